// Round 2
// baseline (1516.644 us; speedup 1.0000x reference)
//
#include <hip/hip_runtime.h>
#include <hip/hip_bf16.h>
#include <math.h>

typedef __hip_bfloat16 bf16;

__device__ __forceinline__ float ldf(const float* p){ return *p; }
__device__ __forceinline__ float ldf(const bf16* p){ return __bfloat162float(*p); }
__device__ __forceinline__ void stf(float* p, float v){ *p = v; }
__device__ __forceinline__ void stf(bf16* p, float v){ *p = __float2bfloat16(v); }

#define LN2F 0.69314718055994531f

// C[m][n] = scale * (sum_k A[m][k]*B[n][k] + bias[n])
// A: MxK row-major, B: NxK row-major (torch Linear weight), bias: N
template<typename TA, typename TB, typename TO>
__global__ __launch_bounds__(256)
void gemm_nt(const TA* __restrict__ A, const TB* __restrict__ B,
             const TB* __restrict__ bias, TO* __restrict__ C,
             int M, int N, int K, float scale)
{
    __shared__ float As[16][132];
    __shared__ float Bs[16][132];
    const int tid = threadIdx.x;
    const int m0 = blockIdx.y * 128;
    const int n0 = blockIdx.x * 128;
    const int tx = tid & 15, ty = tid >> 4;
    float acc[8][8];
    #pragma unroll
    for (int i=0;i<8;++i)
        #pragma unroll
        for (int j=0;j<8;++j) acc[i][j] = 0.f;

    for (int k0 = 0; k0 < K; k0 += 16) {
        #pragma unroll
        for (int l=0;l<8;++l) {
            int idx = tid + l*256;
            int mm = idx >> 4, kk = idx & 15;
            float va = 0.f;
            if (m0 + mm < M) va = ldf(A + (size_t)(m0+mm)*K + (k0+kk));
            As[kk][mm] = va;
        }
        #pragma unroll
        for (int l=0;l<8;++l) {
            int idx = tid + l*256;
            int nn = idx >> 4, kk = idx & 15;
            Bs[kk][nn] = ldf(B + (size_t)(n0+nn)*K + (k0+kk));
        }
        __syncthreads();
        #pragma unroll
        for (int kk=0;kk<16;++kk) {
            float a[8], bb[8];
            #pragma unroll
            for (int i=0;i<8;++i) a[i] = As[kk][ty*8+i];
            #pragma unroll
            for (int j=0;j<8;++j) bb[j] = Bs[kk][tx*8+j];
            #pragma unroll
            for (int i=0;i<8;++i)
                #pragma unroll
                for (int j=0;j<8;++j) acc[i][j] += a[i]*bb[j];
        }
        __syncthreads();
    }
    #pragma unroll
    for (int i=0;i<8;++i) {
        int m = m0 + ty*8 + i;
        if (m >= M) break;
        #pragma unroll
        for (int j=0;j<8;++j) {
            int n = n0 + tx*8 + j;
            float v = scale * (acc[i][j] + ldf(bias + n));
            stf(C + (size_t)m*N + n, v);
        }
    }
}

// pattn[bh][t][p] = softplus(ln2 * (kp_bh[t] . pq_bh[p])) / ln2
__global__ __launch_bounds__(256)
void pattn_kernel(const float* __restrict__ kp, const float* __restrict__ pq,
                  float* __restrict__ pattn, int T)
{
    const int bh = blockIdx.y;
    const int t0 = blockIdx.x * 64;
    const int b = bh >> 4, h = bh & 15;
    __shared__ float pqs[32][65];
    __shared__ float kps[64][65];
    const int tid = threadIdx.x;
    #pragma unroll
    for (int l=0;l<8;++l) {
        int idx = tid + l*256;
        int p = idx >> 6, d = idx & 63;
        pqs[p][d] = pq[(size_t)(p*2+b)*1024 + h*64 + d];
    }
    #pragma unroll
    for (int l=0;l<16;++l) {
        int idx = tid + l*256;
        int t = idx >> 6, d = idx & 63;
        kps[t][d] = kp[(size_t)((t0+t)*2+b)*1024 + h*64 + d];
    }
    __syncthreads();
    const int p = tid & 31;
    const int tb = tid >> 5;
    #pragma unroll
    for (int l=0;l<8;++l) {
        int t = tb + l*8;
        float dot = 0.f;
        for (int d=0;d<64;++d) dot += kps[t][d]*pqs[p][d];
        float z = LN2F * dot;
        float sp = (fmaxf(z, 0.f) + log1pf(expf(-fabsf(z)))) / LN2F;
        pattn[((size_t)bh*T + t0 + t)*32 + p] = sp;
    }
}

// Per (b,h): exclusive chunk prefix states S[i][j] = sum_{t<c*C} kv[t][i]*pattn[t][j]
__global__ __launch_bounds__(512)
void state_kernel(const float* __restrict__ kv, const float* __restrict__ pattn,
                  float* __restrict__ Sbuf, int T, int C, int nchunks)
{
    const int bh = blockIdx.x;
    const int b = bh >> 4, h = bh & 15;
    __shared__ float kvs[8][64];
    __shared__ float ps[8][33];
    const int tid = threadIdx.x; // 512
    float S[4] = {0.f, 0.f, 0.f, 0.f};
    for (int c=0;c<nchunks;++c) {
        #pragma unroll
        for (int k=0;k<4;++k)
            Sbuf[((size_t)bh*nchunks + c)*2048 + tid + k*512] = S[k];
        for (int tt=0; tt<C; tt+=8) {
            int t = c*C + tt;
            {
                int r = tid >> 6, d = tid & 63;
                kvs[r][d] = kv[(size_t)((t+r)*2+b)*1024 + h*64 + d];
            }
            if (tid < 256) {
                int r = tid >> 5, j = tid & 31;
                ps[r][j] = pattn[((size_t)bh*T + t + r)*32 + j];
            }
            __syncthreads();
            #pragma unroll
            for (int k=0;k<4;++k) {
                int e = tid + k*512;
                int i = e >> 5, j = e & 31;
                float s = S[k];
                #pragma unroll
                for (int r=0;r<8;++r) s += kvs[r][i]*ps[r][j];
                S[k] = s;
            }
            __syncthreads();
        }
    }
}

// Per (bh, chunk): both causal-attention stages + softmax for C=64 timesteps.
__global__ __launch_bounds__(256)
void chunk_attn(const float* __restrict__ qg, const float* __restrict__ kvg,
                const float* __restrict__ pg, const float* __restrict__ Sg,
                float* __restrict__ attn, int T)
{
    const int C = 64, NCH = 32;
    __shared__ float smem[14528];
    float* sQ  = smem;          // [64][65]
    float* sKV = smem + 4160;   // [64][65]
    float* sP  = smem + 8320;   // [64][33]
    float* sQK = smem + 10432;  // [64][64], later reused as AP
    float* sAW = smem;          // overlays sQ after it's dead: [64][33]

    const int bh = blockIdx.y, c = blockIdx.x;
    const int b = bh >> 4, h = bh & 15;
    const int t0 = c * C;
    const int tid = threadIdx.x;
    const float* Sblk = Sg + ((size_t)bh*NCH + c)*2048;

    #pragma unroll
    for (int l=0;l<16;++l) {
        int idx = tid + l*256;
        int t = idx >> 6, d = idx & 63;
        size_t g = (size_t)((t0+t)*2 + b)*1024 + h*64 + d;
        sQ[t*65+d]  = qg[g];
        sKV[t*65+d] = kvg[g];
    }
    #pragma unroll
    for (int l=0;l<8;++l) {
        int idx = tid + l*256;
        int t = idx >> 5, j = idx & 31;
        sP[t*33+j] = pg[((size_t)bh*T + t0 + t)*32 + j];
    }
    __syncthreads();

    // QK[t][s] = q_t . kv_s for s<=t
    #pragma unroll
    for (int l=0;l<16;++l) {
        int idx = tid + l*256;
        int t = idx >> 6, s = idx & 63;
        float v = 0.f;
        if (s <= t) {
            for (int d=0;d<64;++d) v += sQ[t*65+d]*sKV[s*65+d];
        }
        sQK[t*64+s] = v;
    }
    __syncthreads();

    // AW[t][j] = (q_t . S[:,j] + sum_{s<=t} QK[t][s]*P[s][j]) / (t0+t+1)
    float awr[8];
    #pragma unroll
    for (int l=0;l<8;++l) {
        int idx = tid + l*256;
        int t = idx >> 5, j = idx & 31;
        float v = 0.f;
        for (int i=0;i<64;++i) v += sQ[t*65+i]*Sblk[i*32+j];
        for (int s=0;s<=t;++s) v += sQK[t*64+s]*sP[s*33+j];
        awr[l] = v / (float)(t0 + t + 1);
    }
    __syncthreads();  // all reads of sQ done; safe to overlay with sAW
    #pragma unroll
    for (int l=0;l<8;++l) {
        int idx = tid + l*256;
        int t = idx >> 5, j = idx & 31;
        sAW[t*33+j] = awr[l];
    }
    __syncthreads();

    // row softmax over 32
    if (tid < 64) {
        int t = tid;
        float m = -1e30f;
        for (int j=0;j<32;++j) m = fmaxf(m, sAW[t*33+j]);
        float sum = 0.f;
        for (int j=0;j<32;++j) { float e = expf(sAW[t*33+j]-m); sAW[t*33+j]=e; sum+=e; }
        float inv = 1.f/sum;
        for (int j=0;j<32;++j) sAW[t*33+j] *= inv;
    }
    __syncthreads();

    // AP[t][s] = aw_t . p_s for s<=t (overwrites sQK)
    #pragma unroll
    for (int l=0;l<16;++l) {
        int idx = tid + l*256;
        int t = idx >> 6, s = idx & 63;
        float v = 0.f;
        if (s <= t) {
            for (int j=0;j<32;++j) v += sAW[t*33+j]*sP[s*33+j];
        }
        sQK[t*64+s] = v;
    }
    __syncthreads();

    // OUT[t][d] = (aw_t . S[d][:] + sum_{s<=t} AP[t][s]*kv_s[d]) / (t0+t+1)
    #pragma unroll
    for (int l=0;l<16;++l) {
        int idx = tid + l*256;
        int t = idx >> 6, d = idx & 63;
        float v = 0.f;
        for (int j=0;j<32;++j) v += sAW[t*33+j]*Sblk[d*32+j];
        for (int s=0;s<=t;++s) v += sQK[t*64+s]*sKV[s*65+d];
        v /= (float)(t0 + t + 1);
        attn[(size_t)((t0+t)*2 + b)*1024 + h*64 + d] = v;
    }
}

extern "C" void kernel_launch(void* const* d_in, const int* in_sizes, int n_in,
                              void* d_out, int out_size, void* d_ws, size_t ws_size,
                              hipStream_t stream) {
    const float* query  = (const float*)d_in[0];
    const float* pquery = (const float*)d_in[1];
    const float* Wpq = (const float*)d_in[2];
    const float* bpq = (const float*)d_in[3];
    const float* Wq  = (const float*)d_in[4];
    const float* bq  = (const float*)d_in[5];
    const float* Wpc = (const float*)d_in[6];
    const float* bpc = (const float*)d_in[7];
    const float* Wc  = (const float*)d_in[8];
    const float* bc  = (const float*)d_in[9];
    const float* Wo  = (const float*)d_in[10];
    const float* bo  = (const float*)d_in[11];
    float* out = (float*)d_out;

    const int T = 2048, E = 1024, MROWS = 4096; // tgt_len * bsz
    const int C = 64, NCH = 32;
    const float SCALING = 0.125f;

    float* ws = (float*)d_ws;
    float* pq_buf    = ws;                        // 64*1024      = 65536
    float* q_buf     = pq_buf + 65536;            // 4096*1024
    float* kv_buf    = q_buf  + 4194304;          // 4096*1024
    float* kp_buf    = kv_buf + 4194304;          // 4096*1024 (reused as attn)
    float* pattn_buf = kp_buf + 4194304;          // 32*2048*32   = 2097152
    float* S_buf     = pattn_buf + 2097152;       // 32*32*2048   = 2097152
    float* attn_buf  = kp_buf;                    // reuse

    dim3 gemm_grid_big(E/128, MROWS/128);
    dim3 gemm_grid_pq(E/128, 1);

    // 1. pq = (pquery @ Wpq^T + bpq) * SCALING
    gemm_nt<float,float,float><<<gemm_grid_pq, 256, 0, stream>>>(
        pquery, Wpq, bpq, pq_buf, 64, E, E, SCALING);
    // 2. kp = query @ Wpc^T + bpc
    gemm_nt<float,float,float><<<gemm_grid_big, 256, 0, stream>>>(
        query, Wpc, bpc, kp_buf, MROWS, E, E, 1.0f);
    // 3. q = (query @ Wq^T + bq) * SCALING
    gemm_nt<float,float,float><<<gemm_grid_big, 256, 0, stream>>>(
        query, Wq, bq, q_buf, MROWS, E, E, SCALING);
    // 4. kv = query @ Wc^T + bc
    gemm_nt<float,float,float><<<gemm_grid_big, 256, 0, stream>>>(
        query, Wc, bc, kv_buf, MROWS, E, E, 1.0f);
    // 5. pattention
    pattn_kernel<<<dim3(T/64, 32), 256, 0, stream>>>(kp_buf, pq_buf, pattn_buf, T);
    // 6. chunk states (exclusive prefix)
    state_kernel<<<32, 512, 0, stream>>>(kv_buf, pattn_buf, S_buf, T, C, NCH);
    // 7. both causal attention stages + softmax
    chunk_attn<<<dim3(NCH, 32), 256, 0, stream>>>(q_buf, kv_buf, pattn_buf, S_buf, attn_buf, T);
    // 8. out = attn @ Wo^T + bo
    gemm_nt<float,float,float><<<gemm_grid_big, 256, 0, stream>>>(
        attn_buf, Wo, bo, out, MROWS, E, E, 1.0f);
}

// Round 3
// 810.474 us; speedup vs baseline: 1.8713x; 1.8713x over previous
//
#include <hip/hip_runtime.h>
#include <hip/hip_bf16.h>
#include <math.h>

typedef __hip_bfloat16 bf16;
typedef __attribute__((ext_vector_type(8))) short bf16x8;
typedef __attribute__((ext_vector_type(4))) float f32x4;

__device__ __forceinline__ float ldf(const float* p){ return *p; }
__device__ __forceinline__ void stf(float* p, float v){ *p = v; }

#define LN2F 0.69314718055994531f

// ---------- fp32 -> bf16 conversion (vectorized), n must be multiple of 4 ----------
__global__ __launch_bounds__(256)
void f2b_kernel(const float* __restrict__ s, bf16* __restrict__ d, int n4)
{
    int i = blockIdx.x * 256 + threadIdx.x;
    if (i < n4) {
        float4 v = ((const float4*)s)[i];
        union { ushort4 u; bf16 b[4]; } o;
        o.b[0] = __float2bfloat16(v.x);
        o.b[1] = __float2bfloat16(v.y);
        o.b[2] = __float2bfloat16(v.z);
        o.b[3] = __float2bfloat16(v.w);
        ((ushort4*)d)[i] = o.u;
    }
}

// ---------- bf16 MFMA GEMM:  C[m][n] = scale*(sum_k A[m][k]*B[n][k] + bias[n]) ----------
// A: MxK bf16 row-major, B: NxK bf16 row-major (torch Linear weight), bias fp32, C fp32.
// M%128==0, N%128==0, K%32==0.
__global__ __launch_bounds__(256)
void gemm_bf16_nt(const bf16* __restrict__ A, const bf16* __restrict__ B,
                  const float* __restrict__ bias, float* __restrict__ C,
                  int M, int N, int K, float scale)
{
    __shared__ short As[128 * 32];   // row-major [128][32], contiguous (m97 layout)
    __shared__ short Bs[128 * 32];

    const int tid  = threadIdx.x;
    const int lane = tid & 63;
    const int wave = tid >> 6;
    const int m0 = blockIdx.y * 128;
    const int n0 = blockIdx.x * 128;
    const int wm = (wave >> 1) * 64;   // wave's 64x64 sub-tile
    const int wn = (wave & 1) * 64;

    f32x4 acc[4][4] = {};

    // staging: 512 chunks of 16B (8 bf16) per tile; thread does chunks tid and tid+256
    const int c0 = tid, c1 = tid + 256;
    const int r0 = c0 >> 2, s0 = c0 & 3;
    const int r1 = c1 >> 2, s1 = c1 & 3;

    const int kb = lane >> 4;        // k-block for fragment read
    const int rr = lane & 15;        // row within 16

    for (int k0 = 0; k0 < K; k0 += 32) {
        uint4 a0 = *(const uint4*)(A + (size_t)(m0 + r0) * K + k0 + s0 * 8);
        uint4 a1 = *(const uint4*)(A + (size_t)(m0 + r1) * K + k0 + s1 * 8);
        uint4 b0 = *(const uint4*)(B + (size_t)(n0 + r0) * K + k0 + s0 * 8);
        uint4 b1 = *(const uint4*)(B + (size_t)(n0 + r1) * K + k0 + s1 * 8);
        __syncthreads();   // previous iteration's LDS reads done
        *(uint4*)(As + c0 * 8) = a0;
        *(uint4*)(As + c1 * 8) = a1;
        *(uint4*)(Bs + c0 * 8) = b0;
        *(uint4*)(Bs + c1 * 8) = b1;
        __syncthreads();

        bf16x8 af[4], bfr[4];
        #pragma unroll
        for (int mi = 0; mi < 4; ++mi)
            af[mi] = *(const bf16x8*)(As + (wm + mi * 16 + rr) * 32 + kb * 8);
        #pragma unroll
        for (int ni = 0; ni < 4; ++ni)
            bfr[ni] = *(const bf16x8*)(Bs + (wn + ni * 16 + rr) * 32 + kb * 8);
        #pragma unroll
        for (int mi = 0; mi < 4; ++mi)
            #pragma unroll
            for (int ni = 0; ni < 4; ++ni)
                acc[mi][ni] = __builtin_amdgcn_mfma_f32_16x16x32_bf16(
                    af[mi], bfr[ni], acc[mi][ni], 0, 0, 0);
    }

    // epilogue: C/D layout col=lane&15, row=(lane>>4)*4+reg  [m89/m91 verified]
    const int col_l = lane & 15;
    const int row_q = lane >> 4;
    #pragma unroll
    for (int ni = 0; ni < 4; ++ni) {
        int col = n0 + wn + ni * 16 + col_l;
        float bb = bias[col];
        #pragma unroll
        for (int mi = 0; mi < 4; ++mi) {
            #pragma unroll
            for (int r = 0; r < 4; ++r) {
                int row = m0 + wm + mi * 16 + row_q * 4 + r;
                C[(size_t)row * N + col] = scale * (acc[mi][ni][r] + bb);
            }
        }
    }
}

// ---------- fp32 tiled GEMM (kept only for the tiny pq projection, M=64) ----------
__global__ __launch_bounds__(256)
void gemm_nt(const float* __restrict__ A, const float* __restrict__ B,
             const float* __restrict__ bias, float* __restrict__ C,
             int M, int N, int K, float scale)
{
    __shared__ float As[16][132];
    __shared__ float Bs[16][132];
    const int tid = threadIdx.x;
    const int m0 = blockIdx.y * 128;
    const int n0 = blockIdx.x * 128;
    const int tx = tid & 15, ty = tid >> 4;
    float acc[8][8];
    #pragma unroll
    for (int i=0;i<8;++i)
        #pragma unroll
        for (int j=0;j<8;++j) acc[i][j] = 0.f;

    for (int k0 = 0; k0 < K; k0 += 16) {
        #pragma unroll
        for (int l=0;l<8;++l) {
            int idx = tid + l*256;
            int mm = idx >> 4, kk = idx & 15;
            float va = 0.f;
            if (m0 + mm < M) va = ldf(A + (size_t)(m0+mm)*K + (k0+kk));
            As[kk][mm] = va;
        }
        #pragma unroll
        for (int l=0;l<8;++l) {
            int idx = tid + l*256;
            int nn = idx >> 4, kk = idx & 15;
            Bs[kk][nn] = ldf(B + (size_t)(n0+nn)*K + (k0+kk));
        }
        __syncthreads();
        #pragma unroll
        for (int kk=0;kk<16;++kk) {
            float a[8], bb[8];
            #pragma unroll
            for (int i=0;i<8;++i) a[i] = As[kk][ty*8+i];
            #pragma unroll
            for (int j=0;j<8;++j) bb[j] = Bs[kk][tx*8+j];
            #pragma unroll
            for (int i=0;i<8;++i)
                #pragma unroll
                for (int j=0;j<8;++j) acc[i][j] += a[i]*bb[j];
        }
        __syncthreads();
    }
    #pragma unroll
    for (int i=0;i<8;++i) {
        int m = m0 + ty*8 + i;
        if (m >= M) break;
        #pragma unroll
        for (int j=0;j<8;++j) {
            int n = n0 + tx*8 + j;
            float v = scale * (acc[i][j] + ldf(bias + n));
            stf(C + (size_t)m*N + n, v);
        }
    }
}

// pattn[bh][t][p] = softplus(ln2 * (kp_bh[t] . pq_bh[p])) / ln2
__global__ __launch_bounds__(256)
void pattn_kernel(const float* __restrict__ kp, const float* __restrict__ pq,
                  float* __restrict__ pattn, int T)
{
    const int bh = blockIdx.y;
    const int t0 = blockIdx.x * 64;
    const int b = bh >> 4, h = bh & 15;
    __shared__ float pqs[32][65];
    __shared__ float kps[64][65];
    const int tid = threadIdx.x;
    #pragma unroll
    for (int l=0;l<8;++l) {
        int idx = tid + l*256;
        int p = idx >> 6, d = idx & 63;
        pqs[p][d] = pq[(size_t)(p*2+b)*1024 + h*64 + d];
    }
    #pragma unroll
    for (int l=0;l<16;++l) {
        int idx = tid + l*256;
        int t = idx >> 6, d = idx & 63;
        kps[t][d] = kp[(size_t)((t0+t)*2+b)*1024 + h*64 + d];
    }
    __syncthreads();
    const int p = tid & 31;
    const int tb = tid >> 5;
    #pragma unroll
    for (int l=0;l<8;++l) {
        int t = tb + l*8;
        float dot = 0.f;
        for (int d=0;d<64;++d) dot += kps[t][d]*pqs[p][d];
        float z = LN2F * dot;
        float sp = (fmaxf(z, 0.f) + log1pf(expf(-fabsf(z)))) / LN2F;
        pattn[((size_t)bh*T + t0 + t)*32 + p] = sp;
    }
}

// Per (b,h): exclusive chunk prefix states S[i][j] = sum_{t<c*C} kv[t][i]*pattn[t][j]
__global__ __launch_bounds__(512)
void state_kernel(const float* __restrict__ kv, const float* __restrict__ pattn,
                  float* __restrict__ Sbuf, int T, int C, int nchunks)
{
    const int bh = blockIdx.x;
    const int b = bh >> 4, h = bh & 15;
    __shared__ float kvs[8][64];
    __shared__ float ps[8][33];
    const int tid = threadIdx.x; // 512
    float S[4] = {0.f, 0.f, 0.f, 0.f};
    for (int c=0;c<nchunks;++c) {
        #pragma unroll
        for (int k=0;k<4;++k)
            Sbuf[((size_t)bh*nchunks + c)*2048 + tid + k*512] = S[k];
        for (int tt=0; tt<C; tt+=8) {
            int t = c*C + tt;
            {
                int r = tid >> 6, d = tid & 63;
                kvs[r][d] = kv[(size_t)((t+r)*2+b)*1024 + h*64 + d];
            }
            if (tid < 256) {
                int r = tid >> 5, j = tid & 31;
                ps[r][j] = pattn[((size_t)bh*T + t + r)*32 + j];
            }
            __syncthreads();
            #pragma unroll
            for (int k=0;k<4;++k) {
                int e = tid + k*512;
                int i = e >> 5, j = e & 31;
                float s = S[k];
                #pragma unroll
                for (int r=0;r<8;++r) s += kvs[r][i]*ps[r][j];
                S[k] = s;
            }
            __syncthreads();
        }
    }
}

// Per (bh, chunk): both causal-attention stages + softmax; writes bf16 attn.
__global__ __launch_bounds__(256)
void chunk_attn(const float* __restrict__ qg, const float* __restrict__ kvg,
                const float* __restrict__ pg, const float* __restrict__ Sg,
                bf16* __restrict__ attn, int T)
{
    const int C = 64, NCH = 32;
    __shared__ float smem[14528];
    float* sQ  = smem;          // [64][65]
    float* sKV = smem + 4160;   // [64][65]
    float* sP  = smem + 8320;   // [64][33]
    float* sQK = smem + 10432;  // [64][64], later reused as AP
    float* sAW = smem;          // overlays sQ after it's dead: [64][33]

    const int bh = blockIdx.y, c = blockIdx.x;
    const int b = bh >> 4, h = bh & 15;
    const int t0 = c * C;
    const int tid = threadIdx.x;
    const float* Sblk = Sg + ((size_t)bh*NCH + c)*2048;

    #pragma unroll
    for (int l=0;l<16;++l) {
        int idx = tid + l*256;
        int t = idx >> 6, d = idx & 63;
        size_t g = (size_t)((t0+t)*2 + b)*1024 + h*64 + d;
        sQ[t*65+d]  = qg[g];
        sKV[t*65+d] = kvg[g];
    }
    #pragma unroll
    for (int l=0;l<8;++l) {
        int idx = tid + l*256;
        int t = idx >> 5, j = idx & 31;
        sP[t*33+j] = pg[((size_t)bh*T + t0 + t)*32 + j];
    }
    __syncthreads();

    // QK[t][s] = q_t . kv_s for s<=t
    #pragma unroll
    for (int l=0;l<16;++l) {
        int idx = tid + l*256;
        int t = idx >> 6, s = idx & 63;
        float v = 0.f;
        if (s <= t) {
            for (int d=0;d<64;++d) v += sQ[t*65+d]*sKV[s*65+d];
        }
        sQK[t*64+s] = v;
    }
    __syncthreads();

    // AW[t][j] = (q_t . S[:,j] + sum_{s<=t} QK[t][s]*P[s][j]) / (t0+t+1)
    float awr[8];
    #pragma unroll
    for (int l=0;l<8;++l) {
        int idx = tid + l*256;
        int t = idx >> 5, j = idx & 31;
        float v = 0.f;
        for (int i=0;i<64;++i) v += sQ[t*65+i]*Sblk[i*32+j];
        for (int s=0;s<=t;++s) v += sQK[t*64+s]*sP[s*33+j];
        awr[l] = v / (float)(t0 + t + 1);
    }
    __syncthreads();  // all reads of sQ done; safe to overlay with sAW
    #pragma unroll
    for (int l=0;l<8;++l) {
        int idx = tid + l*256;
        int t = idx >> 5, j = idx & 31;
        sAW[t*33+j] = awr[l];
    }
    __syncthreads();

    // row softmax over 32
    if (tid < 64) {
        int t = tid;
        float m = -1e30f;
        for (int j=0;j<32;++j) m = fmaxf(m, sAW[t*33+j]);
        float sum = 0.f;
        for (int j=0;j<32;++j) { float e = expf(sAW[t*33+j]-m); sAW[t*33+j]=e; sum+=e; }
        float inv = 1.f/sum;
        for (int j=0;j<32;++j) sAW[t*33+j] *= inv;
    }
    __syncthreads();

    // AP[t][s] = aw_t . p_s for s<=t (overwrites sQK)
    #pragma unroll
    for (int l=0;l<16;++l) {
        int idx = tid + l*256;
        int t = idx >> 6, s = idx & 63;
        float v = 0.f;
        if (s <= t) {
            for (int j=0;j<32;++j) v += sAW[t*33+j]*sP[s*33+j];
        }
        sQK[t*64+s] = v;
    }
    __syncthreads();

    // OUT[t][d] = (aw_t . S[d][:] + sum_{s<=t} AP[t][s]*kv_s[d]) / (t0+t+1)
    #pragma unroll
    for (int l=0;l<16;++l) {
        int idx = tid + l*256;
        int t = idx >> 6, d = idx & 63;
        float v = 0.f;
        for (int j=0;j<32;++j) v += sAW[t*33+j]*Sblk[d*32+j];
        for (int s=0;s<=t;++s) v += sQK[t*64+s]*sKV[s*65+d];
        v /= (float)(t0 + t + 1);
        attn[(size_t)((t0+t)*2 + b)*1024 + h*64 + d] = __float2bfloat16(v);
    }
}

extern "C" void kernel_launch(void* const* d_in, const int* in_sizes, int n_in,
                              void* d_out, int out_size, void* d_ws, size_t ws_size,
                              hipStream_t stream) {
    const float* query  = (const float*)d_in[0];
    const float* pquery = (const float*)d_in[1];
    const float* Wpq = (const float*)d_in[2];
    const float* bpq = (const float*)d_in[3];
    const float* Wq  = (const float*)d_in[4];
    const float* bq  = (const float*)d_in[5];
    const float* Wpc = (const float*)d_in[6];
    const float* bpc = (const float*)d_in[7];
    const float* Wc  = (const float*)d_in[8];
    const float* bc  = (const float*)d_in[9];
    const float* Wo  = (const float*)d_in[10];
    const float* bo  = (const float*)d_in[11];
    float* out = (float*)d_out;

    const int T = 2048, E = 1024, MROWS = 4096; // tgt_len * bsz
    const int C = 64, NCH = 32;
    const float SCALING = 0.125f;

    float* ws = (float*)d_ws;
    float* pq_buf    = ws;                        // 65536
    float* q_buf     = pq_buf + 65536;            // 4096*1024
    float* kv_buf    = q_buf  + 4194304;          // 4096*1024
    float* kp_buf    = kv_buf + 4194304;          // 4096*1024 (later reused as bf16 attn)
    float* pattn_buf = kp_buf + 4194304;          // 2097152
    float* S_buf     = pattn_buf + 2097152;       // 2097152
    bf16*  qbf       = (bf16*)(S_buf + 2097152);  // 4194304 bf16 = 2097152 floats
    bf16*  wq_bf     = (bf16*)(S_buf + 2097152 + 2097152);            // 1M bf16 each
    bf16*  wpc_bf    = wq_bf  + 1048576;
    bf16*  wc_bf     = wpc_bf + 1048576;
    bf16*  wo_bf     = wc_bf  + 1048576;
    bf16*  attn_bf   = (bf16*)kp_buf;             // reuse kp region after pattn

    // --- conversions ---
    f2b_kernel<<<4096, 256, 0, stream>>>(query, qbf, 1048576);
    f2b_kernel<<<1024, 256, 0, stream>>>(Wq,  wq_bf,  262144);
    f2b_kernel<<<1024, 256, 0, stream>>>(Wpc, wpc_bf, 262144);
    f2b_kernel<<<1024, 256, 0, stream>>>(Wc,  wc_bf,  262144);
    f2b_kernel<<<1024, 256, 0, stream>>>(Wo,  wo_bf,  262144);

    dim3 bgrid(E/128, MROWS/128);

    // 1. pq = (pquery @ Wpq^T + bpq) * SCALING   (tiny, fp32 path)
    gemm_nt<<<dim3(E/128, 1), 256, 0, stream>>>(pquery, Wpq, bpq, pq_buf, 64, E, E, SCALING);
    // 2. kp = query @ Wpc^T + bpc
    gemm_bf16_nt<<<bgrid, 256, 0, stream>>>(qbf, wpc_bf, bpc, kp_buf, MROWS, E, E, 1.0f);
    // 3. q = (query @ Wq^T + bq) * SCALING
    gemm_bf16_nt<<<bgrid, 256, 0, stream>>>(qbf, wq_bf, bq, q_buf, MROWS, E, E, SCALING);
    // 4. kv = query @ Wc^T + bc
    gemm_bf16_nt<<<bgrid, 256, 0, stream>>>(qbf, wc_bf, bc, kv_buf, MROWS, E, E, 1.0f);
    // 5. pattention
    pattn_kernel<<<dim3(T/64, 32), 256, 0, stream>>>(kp_buf, pq_buf, pattn_buf, T);
    // 6. chunk states (exclusive prefix)
    state_kernel<<<32, 512, 0, stream>>>(kv_buf, pattn_buf, S_buf, T, C, NCH);
    // 7. both causal attention stages + softmax (writes bf16 attn over kp region)
    chunk_attn<<<dim3(NCH, 32), 256, 0, stream>>>(q_buf, kv_buf, pattn_buf, S_buf, attn_bf, T);
    // 8. out = attn @ Wo^T + bo
    gemm_bf16_nt<<<bgrid, 256, 0, stream>>>(attn_bf, wo_bf, bo, out, MROWS, E, E, 1.0f);
}

// Round 4
// 719.731 us; speedup vs baseline: 2.1072x; 1.1261x over previous
//
#include <hip/hip_runtime.h>
#include <hip/hip_bf16.h>
#include <math.h>

typedef __hip_bfloat16 bf16;
typedef __attribute__((ext_vector_type(8))) short bf16x8;
typedef __attribute__((ext_vector_type(4))) float f32x4;

__device__ __forceinline__ float ldf(const float* p){ return *p; }
__device__ __forceinline__ void stf(float* p, float v){ *p = v; }

#define LN2F 0.69314718055994531f

// ---------- fp32 -> bf16 conversion (vectorized) ----------
__global__ __launch_bounds__(256)
void f2b_kernel(const float* __restrict__ s, bf16* __restrict__ d, int n4)
{
    int i = blockIdx.x * 256 + threadIdx.x;
    if (i < n4) {
        float4 v = ((const float4*)s)[i];
        union { ushort4 u; bf16 b[4]; } o;
        o.b[0] = __float2bfloat16(v.x);
        o.b[1] = __float2bfloat16(v.y);
        o.b[2] = __float2bfloat16(v.z);
        o.b[3] = __float2bfloat16(v.w);
        ((ushort4*)d)[i] = o.u;
    }
}

// ---------- bf16 MFMA GEMM:  C[m][n] = scale*(sum_k A[m][k]*B[n][k] + bias[n]) ----------
__global__ __launch_bounds__(256)
void gemm_bf16_nt(const bf16* __restrict__ A, const bf16* __restrict__ B,
                  const float* __restrict__ bias, float* __restrict__ C,
                  int M, int N, int K, float scale)
{
    __shared__ short As[128 * 32];
    __shared__ short Bs[128 * 32];

    const int tid  = threadIdx.x;
    const int lane = tid & 63;
    const int wave = tid >> 6;
    const int m0 = blockIdx.y * 128;
    const int n0 = blockIdx.x * 128;
    const int wm = (wave >> 1) * 64;
    const int wn = (wave & 1) * 64;

    f32x4 acc[4][4] = {};

    const int c0 = tid, c1 = tid + 256;
    const int r0 = c0 >> 2, s0 = c0 & 3;
    const int r1 = c1 >> 2, s1 = c1 & 3;

    const int kb = lane >> 4;
    const int rr = lane & 15;

    for (int k0 = 0; k0 < K; k0 += 32) {
        uint4 a0 = *(const uint4*)(A + (size_t)(m0 + r0) * K + k0 + s0 * 8);
        uint4 a1 = *(const uint4*)(A + (size_t)(m0 + r1) * K + k0 + s1 * 8);
        uint4 b0 = *(const uint4*)(B + (size_t)(n0 + r0) * K + k0 + s0 * 8);
        uint4 b1 = *(const uint4*)(B + (size_t)(n0 + r1) * K + k0 + s1 * 8);
        __syncthreads();
        *(uint4*)(As + c0 * 8) = a0;
        *(uint4*)(As + c1 * 8) = a1;
        *(uint4*)(Bs + c0 * 8) = b0;
        *(uint4*)(Bs + c1 * 8) = b1;
        __syncthreads();

        bf16x8 af[4], bfr[4];
        #pragma unroll
        for (int mi = 0; mi < 4; ++mi)
            af[mi] = *(const bf16x8*)(As + (wm + mi * 16 + rr) * 32 + kb * 8);
        #pragma unroll
        for (int ni = 0; ni < 4; ++ni)
            bfr[ni] = *(const bf16x8*)(Bs + (wn + ni * 16 + rr) * 32 + kb * 8);
        #pragma unroll
        for (int mi = 0; mi < 4; ++mi)
            #pragma unroll
            for (int ni = 0; ni < 4; ++ni)
                acc[mi][ni] = __builtin_amdgcn_mfma_f32_16x16x32_bf16(
                    af[mi], bfr[ni], acc[mi][ni], 0, 0, 0);
    }

    const int col_l = lane & 15;
    const int row_q = lane >> 4;
    #pragma unroll
    for (int ni = 0; ni < 4; ++ni) {
        int col = n0 + wn + ni * 16 + col_l;
        float bb = bias[col];
        #pragma unroll
        for (int mi = 0; mi < 4; ++mi) {
            #pragma unroll
            for (int r = 0; r < 4; ++r) {
                int row = m0 + wm + mi * 16 + row_q * 4 + r;
                C[(size_t)row * N + col] = scale * (acc[mi][ni][r] + bb);
            }
        }
    }
}

// ---------- fp32 tiled GEMM (tiny pq projection, M=64) ----------
__global__ __launch_bounds__(256)
void gemm_nt(const float* __restrict__ A, const float* __restrict__ B,
             const float* __restrict__ bias, float* __restrict__ C,
             int M, int N, int K, float scale)
{
    __shared__ float As[16][132];
    __shared__ float Bs[16][132];
    const int tid = threadIdx.x;
    const int m0 = blockIdx.y * 128;
    const int n0 = blockIdx.x * 128;
    const int tx = tid & 15, ty = tid >> 4;
    float acc[8][8];
    #pragma unroll
    for (int i=0;i<8;++i)
        #pragma unroll
        for (int j=0;j<8;++j) acc[i][j] = 0.f;

    for (int k0 = 0; k0 < K; k0 += 16) {
        #pragma unroll
        for (int l=0;l<8;++l) {
            int idx = tid + l*256;
            int mm = idx >> 4, kk = idx & 15;
            float va = 0.f;
            if (m0 + mm < M) va = ldf(A + (size_t)(m0+mm)*K + (k0+kk));
            As[kk][mm] = va;
        }
        #pragma unroll
        for (int l=0;l<8;++l) {
            int idx = tid + l*256;
            int nn = idx >> 4, kk = idx & 15;
            Bs[kk][nn] = ldf(B + (size_t)(n0+nn)*K + (k0+kk));
        }
        __syncthreads();
        #pragma unroll
        for (int kk=0;kk<16;++kk) {
            float a[8], bb[8];
            #pragma unroll
            for (int i=0;i<8;++i) a[i] = As[kk][ty*8+i];
            #pragma unroll
            for (int j=0;j<8;++j) bb[j] = Bs[kk][tx*8+j];
            #pragma unroll
            for (int i=0;i<8;++i)
                #pragma unroll
                for (int j=0;j<8;++j) acc[i][j] += a[i]*bb[j];
        }
        __syncthreads();
    }
    #pragma unroll
    for (int i=0;i<8;++i) {
        int m = m0 + ty*8 + i;
        if (m >= M) break;
        #pragma unroll
        for (int j=0;j<8;++j) {
            int n = n0 + tx*8 + j;
            float v = scale * (acc[i][j] + ldf(bias + n));
            stf(C + (size_t)m*N + n, v);
        }
    }
}

// pattn[bh][t][p] = softplus(ln2 * (kp_bh[t] . pq_bh[p])) / ln2
__global__ __launch_bounds__(256)
void pattn_kernel(const float* __restrict__ kp, const float* __restrict__ pq,
                  float* __restrict__ pattn, int T)
{
    const int bh = blockIdx.y;
    const int t0 = blockIdx.x * 64;
    const int b = bh >> 4, h = bh & 15;
    __shared__ float pqs[32][65];
    __shared__ float kps[64][65];
    const int tid = threadIdx.x;
    #pragma unroll
    for (int l=0;l<8;++l) {
        int idx = tid + l*256;
        int p = idx >> 6, d = idx & 63;
        pqs[p][d] = pq[(size_t)(p*2+b)*1024 + h*64 + d];
    }
    #pragma unroll
    for (int l=0;l<16;++l) {
        int idx = tid + l*256;
        int t = idx >> 6, d = idx & 63;
        kps[t][d] = kp[(size_t)((t0+t)*2+b)*1024 + h*64 + d];
    }
    __syncthreads();
    const int p = tid & 31;
    const int tb = tid >> 5;
    #pragma unroll
    for (int l=0;l<8;++l) {
        int t = tb + l*8;
        float dot = 0.f;
        for (int d=0;d<64;++d) dot += kps[t][d]*pqs[p][d];
        float z = LN2F * dot;
        float sp = (fmaxf(z, 0.f) + log1pf(expf(-fabsf(z)))) / LN2F;
        pattn[((size_t)bh*T + t0 + t)*32 + p] = sp;
    }
}

// Chunk-local sums: S[bh][c][i*32+j] = sum_{t in chunk c} kv[t][i]*pattn[t][j]
// grid (c, bh), 256 threads. Later converted in-place to exclusive prefix.
__global__ __launch_bounds__(256)
void chunk_sum_kernel(const float* __restrict__ kv, const float* __restrict__ pattn,
                      float* __restrict__ Sbuf, int T)
{
    const int C = 64, NCH = 32;
    const int c = blockIdx.x, bh = blockIdx.y;
    const int b = bh >> 4, h = bh & 15;
    const int t0 = c * C;
    const int tid = threadIdx.x;
    __shared__ float kvs[64][64];
    __shared__ float ps[64][32];

    #pragma unroll
    for (int l=0;l<16;++l) {
        int idx = tid + l*256;
        int t = idx >> 6, d = idx & 63;
        kvs[t][d] = kv[(size_t)((t0+t)*2+b)*1024 + h*64 + d];
    }
    #pragma unroll
    for (int l=0;l<8;++l) {
        int idx = tid + l*256;
        int t = idx >> 5, j = idx & 31;
        ps[t][j] = pattn[((size_t)bh*T + t0 + t)*32 + j];
    }
    __syncthreads();

    // thread owns elements e = tid + k*256 -> j = tid&31 (fixed), i = (tid>>5)+8k
    const int j = tid & 31;
    const int ib = tid >> 5;
    float acc[8] = {};
    for (int r = 0; r < 64; ++r) {
        float pj = ps[r][j];
        #pragma unroll
        for (int k=0;k<8;++k) acc[k] += kvs[r][ib + 8*k] * pj;
    }
    float* Sdst = Sbuf + ((size_t)bh*NCH + c)*2048;
    #pragma unroll
    for (int k=0;k<8;++k) Sdst[tid + k*256] = acc[k];
}

// In-place exclusive prefix over chunks: thread owns (bh, e), scans c=0..31.
__global__ __launch_bounds__(256)
void prefix_state_kernel(float* __restrict__ Sbuf)
{
    const int NCH = 32;
    int gid = blockIdx.x * 256 + threadIdx.x;   // 65536 threads
    int bh = gid >> 11, e = gid & 2047;
    float* p = Sbuf + (size_t)bh * NCH * 2048 + e;
    float run = 0.f;
    #pragma unroll
    for (int c = 0; c < NCH; ++c) {
        float t = p[c * 2048];
        p[c * 2048] = run;
        run += t;
    }
}

// Per (bh, chunk): both causal-attention stages + softmax; writes bf16 attn.
__global__ __launch_bounds__(256)
void chunk_attn(const float* __restrict__ qg, const float* __restrict__ kvg,
                const float* __restrict__ pg, const float* __restrict__ Sg,
                bf16* __restrict__ attn, int T)
{
    const int C = 64, NCH = 32;
    __shared__ float smem[14528];
    float* sQ  = smem;          // [64][65]
    float* sKV = smem + 4160;   // [64][65]
    float* sP  = smem + 8320;   // [64][33]
    float* sQK = smem + 10432;  // [64][64], later reused as AP
    float* sAW = smem;          // overlays sQ after it's dead: [64][33]

    const int bh = blockIdx.y, c = blockIdx.x;
    const int b = bh >> 4, h = bh & 15;
    const int t0 = c * C;
    const int tid = threadIdx.x;
    const float* Sblk = Sg + ((size_t)bh*NCH + c)*2048;

    #pragma unroll
    for (int l=0;l<16;++l) {
        int idx = tid + l*256;
        int t = idx >> 6, d = idx & 63;
        size_t g = (size_t)((t0+t)*2 + b)*1024 + h*64 + d;
        sQ[t*65+d]  = qg[g];
        sKV[t*65+d] = kvg[g];
    }
    #pragma unroll
    for (int l=0;l<8;++l) {
        int idx = tid + l*256;
        int t = idx >> 5, j = idx & 31;
        sP[t*33+j] = pg[((size_t)bh*T + t0 + t)*32 + j];
    }
    __syncthreads();

    // QK[t][s] = q_t . kv_s for s<=t
    #pragma unroll
    for (int l=0;l<16;++l) {
        int idx = tid + l*256;
        int t = idx >> 6, s = idx & 63;
        float v = 0.f;
        if (s <= t) {
            for (int d=0;d<64;++d) v += sQ[t*65+d]*sKV[s*65+d];
        }
        sQK[t*64+s] = v;
    }
    __syncthreads();

    // AW[t][j] = (q_t . S[:,j] + sum_{s<=t} QK[t][s]*P[s][j]) / (t0+t+1)
    float awr[8];
    #pragma unroll
    for (int l=0;l<8;++l) {
        int idx = tid + l*256;
        int t = idx >> 5, j = idx & 31;
        float v = 0.f;
        for (int i=0;i<64;++i) v += sQ[t*65+i]*Sblk[i*32+j];
        for (int s=0;s<=t;++s) v += sQK[t*64+s]*sP[s*33+j];
        awr[l] = v / (float)(t0 + t + 1);
    }
    __syncthreads();
    #pragma unroll
    for (int l=0;l<8;++l) {
        int idx = tid + l*256;
        int t = idx >> 5, j = idx & 31;
        sAW[t*33+j] = awr[l];
    }
    __syncthreads();

    // row softmax over 32
    if (tid < 64) {
        int t = tid;
        float m = -1e30f;
        for (int j=0;j<32;++j) m = fmaxf(m, sAW[t*33+j]);
        float sum = 0.f;
        for (int j=0;j<32;++j) { float e = expf(sAW[t*33+j]-m); sAW[t*33+j]=e; sum+=e; }
        float inv = 1.f/sum;
        for (int j=0;j<32;++j) sAW[t*33+j] *= inv;
    }
    __syncthreads();

    // AP[t][s] = aw_t . p_s for s<=t (overwrites sQK)
    #pragma unroll
    for (int l=0;l<16;++l) {
        int idx = tid + l*256;
        int t = idx >> 6, s = idx & 63;
        float v = 0.f;
        if (s <= t) {
            for (int j=0;j<32;++j) v += sAW[t*33+j]*sP[s*33+j];
        }
        sQK[t*64+s] = v;
    }
    __syncthreads();

    // OUT[t][d] = (aw_t . S[d][:] + sum_{s<=t} AP[t][s]*kv_s[d]) / (t0+t+1)
    #pragma unroll
    for (int l=0;l<16;++l) {
        int idx = tid + l*256;
        int t = idx >> 6, d = idx & 63;
        float v = 0.f;
        for (int j=0;j<32;++j) v += sAW[t*33+j]*Sblk[d*32+j];
        for (int s=0;s<=t;++s) v += sQK[t*64+s]*sKV[s*65+d];
        v /= (float)(t0 + t + 1);
        attn[(size_t)((t0+t)*2 + b)*1024 + h*64 + d] = __float2bfloat16(v);
    }
}

extern "C" void kernel_launch(void* const* d_in, const int* in_sizes, int n_in,
                              void* d_out, int out_size, void* d_ws, size_t ws_size,
                              hipStream_t stream) {
    const float* query  = (const float*)d_in[0];
    const float* pquery = (const float*)d_in[1];
    const float* Wpq = (const float*)d_in[2];
    const float* bpq = (const float*)d_in[3];
    const float* Wq  = (const float*)d_in[4];
    const float* bq  = (const float*)d_in[5];
    const float* Wpc = (const float*)d_in[6];
    const float* bpc = (const float*)d_in[7];
    const float* Wc  = (const float*)d_in[8];
    const float* bc  = (const float*)d_in[9];
    const float* Wo  = (const float*)d_in[10];
    const float* bo  = (const float*)d_in[11];
    float* out = (float*)d_out;

    const int T = 2048, E = 1024, MROWS = 4096;
    const int NCH = 32;
    const float SCALING = 0.125f;

    float* ws = (float*)d_ws;
    float* pq_buf    = ws;                        // 65536
    float* q_buf     = pq_buf + 65536;            // 4096*1024
    float* kv_buf    = q_buf  + 4194304;          // 4096*1024
    float* kp_buf    = kv_buf + 4194304;          // 4096*1024 (later reused as bf16 attn)
    float* pattn_buf = kp_buf + 4194304;          // 2097152
    float* S_buf     = pattn_buf + 2097152;       // 2097152
    bf16*  qbf       = (bf16*)(S_buf + 2097152);
    bf16*  wq_bf     = (bf16*)(S_buf + 2097152 + 2097152);
    bf16*  wpc_bf    = wq_bf  + 1048576;
    bf16*  wc_bf     = wpc_bf + 1048576;
    bf16*  wo_bf     = wc_bf  + 1048576;
    bf16*  attn_bf   = (bf16*)kp_buf;

    // --- conversions ---
    f2b_kernel<<<4096, 256, 0, stream>>>(query, qbf, 1048576);
    f2b_kernel<<<1024, 256, 0, stream>>>(Wq,  wq_bf,  262144);
    f2b_kernel<<<1024, 256, 0, stream>>>(Wpc, wpc_bf, 262144);
    f2b_kernel<<<1024, 256, 0, stream>>>(Wc,  wc_bf,  262144);
    f2b_kernel<<<1024, 256, 0, stream>>>(Wo,  wo_bf,  262144);

    dim3 bgrid(E/128, MROWS/128);

    // 1. pq = (pquery @ Wpq^T + bpq) * SCALING   (tiny, fp32 path)
    gemm_nt<<<dim3(E/128, 1), 256, 0, stream>>>(pquery, Wpq, bpq, pq_buf, 64, E, E, SCALING);
    // 2. kp = query @ Wpc^T + bpc
    gemm_bf16_nt<<<bgrid, 256, 0, stream>>>(qbf, wpc_bf, bpc, kp_buf, MROWS, E, E, 1.0f);
    // 3. q = (query @ Wq^T + bq) * SCALING
    gemm_bf16_nt<<<bgrid, 256, 0, stream>>>(qbf, wq_bf, bq, q_buf, MROWS, E, E, SCALING);
    // 4. kv = query @ Wc^T + bc
    gemm_bf16_nt<<<bgrid, 256, 0, stream>>>(qbf, wc_bf, bc, kv_buf, MROWS, E, E, 1.0f);
    // 5. pattention
    pattn_kernel<<<dim3(T/64, 32), 256, 0, stream>>>(kp_buf, pq_buf, pattn_buf, T);
    // 6a. chunk-local sums (parallel over bh x chunk)
    chunk_sum_kernel<<<dim3(NCH, 32), 256, 0, stream>>>(kv_buf, pattn_buf, S_buf, T);
    // 6b. in-place exclusive prefix over chunks
    prefix_state_kernel<<<256, 256, 0, stream>>>(S_buf);
    // 7. both causal attention stages + softmax (writes bf16 attn over kp region)
    chunk_attn<<<dim3(NCH, 32), 256, 0, stream>>>(q_buf, kv_buf, pattn_buf, S_buf, attn_bf, T);
    // 8. out = attn @ Wo^T + bo
    gemm_bf16_nt<<<bgrid, 256, 0, stream>>>(attn_bf, wo_bf, bo, out, MROWS, E, E, 1.0f);
}

// Round 5
// 499.316 us; speedup vs baseline: 3.0374x; 1.4414x over previous
//
#include <hip/hip_runtime.h>
#include <hip/hip_bf16.h>
#include <math.h>

typedef __hip_bfloat16 bf16;
typedef __attribute__((ext_vector_type(8))) short bf16x8;
typedef __attribute__((ext_vector_type(4))) float f32x4;

__device__ __forceinline__ float ldf(const float* p){ return *p; }
__device__ __forceinline__ void stf(float* p, float v){ *p = v; }
__device__ __forceinline__ float bfbits(unsigned int u){ union{unsigned int x; float f;} c; c.x = u; return c.f; }

#define LN2F 0.69314718055994531f

// ---------- fp32 -> bf16 conversion (vectorized) ----------
__global__ __launch_bounds__(256)
void f2b_kernel(const float* __restrict__ s, bf16* __restrict__ d, int n4)
{
    int i = blockIdx.x * 256 + threadIdx.x;
    if (i < n4) {
        float4 v = ((const float4*)s)[i];
        union { ushort4 u; bf16 b[4]; } o;
        o.b[0] = __float2bfloat16(v.x);
        o.b[1] = __float2bfloat16(v.y);
        o.b[2] = __float2bfloat16(v.z);
        o.b[3] = __float2bfloat16(v.w);
        ((ushort4*)d)[i] = o.u;
    }
}

// ---------- bf16 MFMA GEMM:  C[m][n] = scale*(sum_k A[m][k]*B[n][k] + bias[n]) ----------
__global__ __launch_bounds__(256)
void gemm_bf16_nt(const bf16* __restrict__ A, const bf16* __restrict__ B,
                  const float* __restrict__ bias, float* __restrict__ C,
                  int M, int N, int K, float scale)
{
    __shared__ short As[128 * 32];
    __shared__ short Bs[128 * 32];

    const int tid  = threadIdx.x;
    const int lane = tid & 63;
    const int wave = tid >> 6;
    const int m0 = blockIdx.y * 128;
    const int n0 = blockIdx.x * 128;
    const int wm = (wave >> 1) * 64;
    const int wn = (wave & 1) * 64;

    f32x4 acc[4][4] = {};

    const int c0 = tid, c1 = tid + 256;
    const int r0 = c0 >> 2, s0 = c0 & 3;
    const int r1 = c1 >> 2, s1 = c1 & 3;

    const int kb = lane >> 4;
    const int rr = lane & 15;

    for (int k0 = 0; k0 < K; k0 += 32) {
        uint4 a0 = *(const uint4*)(A + (size_t)(m0 + r0) * K + k0 + s0 * 8);
        uint4 a1 = *(const uint4*)(A + (size_t)(m0 + r1) * K + k0 + s1 * 8);
        uint4 b0 = *(const uint4*)(B + (size_t)(n0 + r0) * K + k0 + s0 * 8);
        uint4 b1 = *(const uint4*)(B + (size_t)(n0 + r1) * K + k0 + s1 * 8);
        __syncthreads();
        *(uint4*)(As + c0 * 8) = a0;
        *(uint4*)(As + c1 * 8) = a1;
        *(uint4*)(Bs + c0 * 8) = b0;
        *(uint4*)(Bs + c1 * 8) = b1;
        __syncthreads();

        bf16x8 af[4], bfr[4];
        #pragma unroll
        for (int mi = 0; mi < 4; ++mi)
            af[mi] = *(const bf16x8*)(As + (wm + mi * 16 + rr) * 32 + kb * 8);
        #pragma unroll
        for (int ni = 0; ni < 4; ++ni)
            bfr[ni] = *(const bf16x8*)(Bs + (wn + ni * 16 + rr) * 32 + kb * 8);
        #pragma unroll
        for (int mi = 0; mi < 4; ++mi)
            #pragma unroll
            for (int ni = 0; ni < 4; ++ni)
                acc[mi][ni] = __builtin_amdgcn_mfma_f32_16x16x32_bf16(
                    af[mi], bfr[ni], acc[mi][ni], 0, 0, 0);
    }

    const int col_l = lane & 15;
    const int row_q = lane >> 4;
    #pragma unroll
    for (int ni = 0; ni < 4; ++ni) {
        int col = n0 + wn + ni * 16 + col_l;
        float bb = bias[col];
        #pragma unroll
        for (int mi = 0; mi < 4; ++mi) {
            #pragma unroll
            for (int r = 0; r < 4; ++r) {
                int row = m0 + wm + mi * 16 + row_q * 4 + r;
                C[(size_t)row * N + col] = scale * (acc[mi][ni][r] + bb);
            }
        }
    }
}

// ---------- fp32 tiled GEMM (tiny pq projection, M=64) ----------
__global__ __launch_bounds__(256)
void gemm_nt(const float* __restrict__ A, const float* __restrict__ B,
             const float* __restrict__ bias, float* __restrict__ C,
             int M, int N, int K, float scale)
{
    __shared__ float As[16][132];
    __shared__ float Bs[16][132];
    const int tid = threadIdx.x;
    const int m0 = blockIdx.y * 128;
    const int n0 = blockIdx.x * 128;
    const int tx = tid & 15, ty = tid >> 4;
    float acc[8][8];
    #pragma unroll
    for (int i=0;i<8;++i)
        #pragma unroll
        for (int j=0;j<8;++j) acc[i][j] = 0.f;

    for (int k0 = 0; k0 < K; k0 += 16) {
        #pragma unroll
        for (int l=0;l<8;++l) {
            int idx = tid + l*256;
            int mm = idx >> 4, kk = idx & 15;
            float va = 0.f;
            if (m0 + mm < M) va = ldf(A + (size_t)(m0+mm)*K + (k0+kk));
            As[kk][mm] = va;
        }
        #pragma unroll
        for (int l=0;l<8;++l) {
            int idx = tid + l*256;
            int nn = idx >> 4, kk = idx & 15;
            Bs[kk][nn] = ldf(B + (size_t)(n0+nn)*K + (k0+kk));
        }
        __syncthreads();
        #pragma unroll
        for (int kk=0;kk<16;++kk) {
            float a[8], bb[8];
            #pragma unroll
            for (int i=0;i<8;++i) a[i] = As[kk][ty*8+i];
            #pragma unroll
            for (int j=0;j<8;++j) bb[j] = Bs[kk][tx*8+j];
            #pragma unroll
            for (int i=0;i<8;++i)
                #pragma unroll
                for (int j=0;j<8;++j) acc[i][j] += a[i]*bb[j];
        }
        __syncthreads();
    }
    #pragma unroll
    for (int i=0;i<8;++i) {
        int m = m0 + ty*8 + i;
        if (m >= M) break;
        #pragma unroll
        for (int j=0;j<8;++j) {
            int n = n0 + tx*8 + j;
            float v = scale * (acc[i][j] + ldf(bias + n));
            stf(C + (size_t)m*N + n, v);
        }
    }
}

// pattn[bh][t][p] = softplus(ln2 * (kp_bh[t] . pq_bh[p])) / ln2
__global__ __launch_bounds__(256)
void pattn_kernel(const float* __restrict__ kp, const float* __restrict__ pq,
                  float* __restrict__ pattn, int T)
{
    const int bh = blockIdx.y;
    const int t0 = blockIdx.x * 64;
    const int b = bh >> 4, h = bh & 15;
    __shared__ float pqs[32][65];
    __shared__ float kps[64][65];
    const int tid = threadIdx.x;
    #pragma unroll
    for (int l=0;l<8;++l) {
        int idx = tid + l*256;
        int p = idx >> 6, d = idx & 63;
        pqs[p][d] = pq[(size_t)(p*2+b)*1024 + h*64 + d];
    }
    #pragma unroll
    for (int l=0;l<16;++l) {
        int idx = tid + l*256;
        int t = idx >> 6, d = idx & 63;
        kps[t][d] = kp[(size_t)((t0+t)*2+b)*1024 + h*64 + d];
    }
    __syncthreads();
    const int p = tid & 31;
    const int tb = tid >> 5;
    #pragma unroll
    for (int l=0;l<8;++l) {
        int t = tb + l*8;
        float dot = 0.f;
        for (int d=0;d<64;++d) dot += kps[t][d]*pqs[p][d];
        float z = LN2F * dot;
        float sp = (fmaxf(z, 0.f) + log1pf(expf(-fabsf(z)))) / LN2F;
        pattn[((size_t)bh*T + t0 + t)*32 + p] = sp;
    }
}

// Chunk-local sums: S[bh][c][i*32+j] = sum_{t in chunk c} kv[t][i]*pattn[t][j]
__global__ __launch_bounds__(256)
void chunk_sum_kernel(const float* __restrict__ kv, const float* __restrict__ pattn,
                      float* __restrict__ Sbuf, int T)
{
    const int C = 64, NCH = 32;
    const int c = blockIdx.x, bh = blockIdx.y;
    const int b = bh >> 4, h = bh & 15;
    const int t0 = c * C;
    const int tid = threadIdx.x;
    __shared__ float kvs[64][64];
    __shared__ float ps[64][32];

    #pragma unroll
    for (int l=0;l<16;++l) {
        int idx = tid + l*256;
        int t = idx >> 6, d = idx & 63;
        kvs[t][d] = kv[(size_t)((t0+t)*2+b)*1024 + h*64 + d];
    }
    #pragma unroll
    for (int l=0;l<8;++l) {
        int idx = tid + l*256;
        int t = idx >> 5, j = idx & 31;
        ps[t][j] = pattn[((size_t)bh*T + t0 + t)*32 + j];
    }
    __syncthreads();

    const int j = tid & 31;
    const int ib = tid >> 5;
    float acc[8] = {};
    for (int r = 0; r < 64; ++r) {
        float pj = ps[r][j];
        #pragma unroll
        for (int k=0;k<8;++k) acc[k] += kvs[r][ib + 8*k] * pj;
    }
    float* Sdst = Sbuf + ((size_t)bh*NCH + c)*2048;
    #pragma unroll
    for (int k=0;k<8;++k) Sdst[tid + k*256] = acc[k];
}

// In-place exclusive prefix over chunks
__global__ __launch_bounds__(256)
void prefix_state_kernel(float* __restrict__ Sbuf)
{
    const int NCH = 32;
    int gid = blockIdx.x * 256 + threadIdx.x;
    int bh = gid >> 11, e = gid & 2047;
    float* p = Sbuf + (size_t)bh * NCH * 2048 + e;
    float run = 0.f;
    #pragma unroll
    for (int c = 0; c < NCH; ++c) {
        float t = p[c * 2048];
        p[c * 2048] = run;
        run += t;
    }
}

// Per (bh, chunk): both causal-attention stages + softmax; register-tiled fp32.
// LDS layout (floats, total 14976 = 59904 B):
//   sQb  bf16 [64][68]  @0      (8704 B)  -- overlaid by sAW fp32 [64][34]
//   sKV  f32  [64][66]  @2176   (16896 B)
//   sQK  f32  [64][66]  @6400   (16896 B) -- overlaid by sAP
//   sP   f32  [64][34]  @10624  (8704 B)
//   sS   f32  [64][34]  @12800  (8704 B)
__global__ __launch_bounds__(256)
void chunk_attn(const float* __restrict__ qg, const float* __restrict__ kvg,
                const float* __restrict__ pg, const float* __restrict__ Sg,
                bf16* __restrict__ attn, int T)
{
    const int NCH = 32;
    __shared__ float smemf[14976];
    short* sQb = (short*)smemf;
    float* sAW = smemf;
    float* sKV = smemf + 2176;
    float* sQK = smemf + 6400;
    float* sAP = sQK;
    float* sP  = smemf + 10624;
    float* sS  = smemf + 12800;

    const int bh = blockIdx.y, c = blockIdx.x;
    const int b = bh >> 4, h = bh & 15;
    const int t0 = c * 64;
    const int tid = threadIdx.x;
    const float* Sblk = Sg + ((size_t)bh*NCH + c)*2048;

    // ---- stage 1: staging ----
    #pragma unroll
    for (int l = 0; l < 4; ++l) {
        int idx = tid + l * 256;
        int t = idx >> 4, d4 = (idx & 15) * 4;
        size_t g = (size_t)((t0 + t) * 2 + b) * 1024 + h * 64 + d4;
        float4 qv = *(const float4*)(qg + g);
        union { ushort4 u; bf16 bb[4]; } cv;
        cv.bb[0] = __float2bfloat16(qv.x);
        cv.bb[1] = __float2bfloat16(qv.y);
        cv.bb[2] = __float2bfloat16(qv.z);
        cv.bb[3] = __float2bfloat16(qv.w);
        *(ushort4*)(sQb + t * 68 + d4) = cv.u;
        float4 kv = *(const float4*)(kvg + g);
        float* kd = sKV + t * 66 + d4;
        kd[0]=kv.x; kd[1]=kv.y; kd[2]=kv.z; kd[3]=kv.w;
    }
    #pragma unroll
    for (int l = 0; l < 2; ++l) {
        int idx = tid + l * 256;
        int r = idx >> 3, j4 = (idx & 7) * 4;
        float4 pv = *(const float4*)(pg + ((size_t)bh * T + t0 + r) * 32 + j4);
        float* pd = sP + r * 34 + j4;
        pd[0]=pv.x; pd[1]=pv.y; pd[2]=pv.z; pd[3]=pv.w;
        float4 sv = *(const float4*)(Sblk + r * 32 + j4);
        float* sd = sS + r * 34 + j4;
        sd[0]=sv.x; sd[1]=sv.y; sd[2]=sv.z; sd[3]=sv.w;
    }
    __syncthreads();

    // ---- stage 2: QK = Q · KV^T (full 64x64, 4x4 tiles) ----
    {
        const int tB = (tid >> 4) * 4;
        const int sB = (tid & 15) * 4;
        float qk[4][4] = {};
        for (int d4 = 0; d4 < 64; d4 += 4) {
            float qv[4][4], kv[4][4];
            #pragma unroll
            for (int r = 0; r < 4; ++r) {
                uint2 uq = *(const uint2*)(sQb + (tB + r) * 68 + d4);
                qv[r][0] = bfbits(uq.x << 16);
                qv[r][1] = bfbits(uq.x & 0xffff0000u);
                qv[r][2] = bfbits(uq.y << 16);
                qv[r][3] = bfbits(uq.y & 0xffff0000u);
            }
            #pragma unroll
            for (int r = 0; r < 4; ++r) {
                float2 k0 = *(const float2*)(sKV + (sB + r) * 66 + d4);
                float2 k1 = *(const float2*)(sKV + (sB + r) * 66 + d4 + 2);
                kv[r][0]=k0.x; kv[r][1]=k0.y; kv[r][2]=k1.x; kv[r][3]=k1.y;
            }
            #pragma unroll
            for (int i = 0; i < 4; ++i)
                #pragma unroll
                for (int j = 0; j < 4; ++j)
                    qk[i][j] += qv[i][0]*kv[j][0] + qv[i][1]*kv[j][1]
                              + qv[i][2]*kv[j][2] + qv[i][3]*kv[j][3];
        }
        #pragma unroll
        for (int i = 0; i < 4; ++i)
            #pragma unroll
            for (int j = 0; j < 4; ++j)
                sQK[(tB + i) * 66 + sB + j] = qk[i][j];
    }
    __syncthreads();

    // ---- stage 3: AW = (Q·S + causal(QK)·P)/len, softmax over 32 ----
    const int t3 = tid >> 2;
    const int j0 = (tid & 3) * 8;
    float aw[8] = {};
    {
        for (int i = 0; i < 64; ++i) {
            float q = bfbits(((unsigned int)(unsigned short)sQb[t3 * 68 + i]) << 16);
            const float* sr = sS + i * 34 + j0;
            float2 s0 = *(const float2*)(sr);
            float2 s1 = *(const float2*)(sr + 2);
            float2 s2 = *(const float2*)(sr + 4);
            float2 s3 = *(const float2*)(sr + 6);
            aw[0] += q * s0.x; aw[1] += q * s0.y;
            aw[2] += q * s1.x; aw[3] += q * s1.y;
            aw[4] += q * s2.x; aw[5] += q * s2.y;
            aw[6] += q * s3.x; aw[7] += q * s3.y;
        }
        for (int s = 0; s <= t3; ++s) {
            float w = sQK[t3 * 66 + s];
            const float* pr = sP + s * 34 + j0;
            float2 p0 = *(const float2*)(pr);
            float2 p1 = *(const float2*)(pr + 2);
            float2 p2 = *(const float2*)(pr + 4);
            float2 p3 = *(const float2*)(pr + 6);
            aw[0] += w * p0.x; aw[1] += w * p0.y;
            aw[2] += w * p1.x; aw[3] += w * p1.y;
            aw[4] += w * p2.x; aw[5] += w * p2.y;
            aw[6] += w * p3.x; aw[7] += w * p3.y;
        }
        float inv_len = 1.0f / (float)(t0 + t3 + 1);
        #pragma unroll
        for (int k = 0; k < 8; ++k) aw[k] *= inv_len;
        float m = aw[0];
        #pragma unroll
        for (int k = 1; k < 8; ++k) m = fmaxf(m, aw[k]);
        m = fmaxf(m, __shfl_xor(m, 1));
        m = fmaxf(m, __shfl_xor(m, 2));
        float sum = 0.f;
        #pragma unroll
        for (int k = 0; k < 8; ++k) { aw[k] = __expf(aw[k] - m); sum += aw[k]; }
        sum += __shfl_xor(sum, 1);
        sum += __shfl_xor(sum, 2);
        float rs = 1.0f / sum;
        #pragma unroll
        for (int k = 0; k < 8; ++k) aw[k] *= rs;
    }
    __syncthreads();   // all reads of sQb/sQK complete
    {
        float* dst = sAW + t3 * 34 + j0;
        #pragma unroll
        for (int k = 0; k < 8; k += 2) {
            float2 v; v.x = aw[k]; v.y = aw[k+1];
            *(float2*)(dst + k) = v;
        }
    }
    __syncthreads();

    // ---- stage 4: AP = causal(AW · P^T), masked store over sQK ----
    {
        const int tB = (tid >> 4) * 4;
        const int sB = (tid & 15) * 4;
        float ap[4][4] = {};
        for (int j4 = 0; j4 < 32; j4 += 4) {
            float a[4][4], p[4][4];
            #pragma unroll
            for (int r = 0; r < 4; ++r) {
                const float* ar = sAW + (tB + r) * 34 + j4;
                float2 a0 = *(const float2*)(ar);
                float2 a1 = *(const float2*)(ar + 2);
                a[r][0]=a0.x; a[r][1]=a0.y; a[r][2]=a1.x; a[r][3]=a1.y;
                const float* pr = sP + (sB + r) * 34 + j4;
                float2 p0 = *(const float2*)(pr);
                float2 p1 = *(const float2*)(pr + 2);
                p[r][0]=p0.x; p[r][1]=p0.y; p[r][2]=p1.x; p[r][3]=p1.y;
            }
            #pragma unroll
            for (int i = 0; i < 4; ++i)
                #pragma unroll
                for (int j = 0; j < 4; ++j)
                    ap[i][j] += a[i][0]*p[j][0] + a[i][1]*p[j][1]
                              + a[i][2]*p[j][2] + a[i][3]*p[j][3];
        }
        #pragma unroll
        for (int i = 0; i < 4; ++i)
            #pragma unroll
            for (int j = 0; j < 4; ++j)
                sAP[(tB + i) * 66 + sB + j] = (sB + j <= tB + i) ? ap[i][j] : 0.f;
    }
    __syncthreads();

    // ---- stage 5: OUT = (AW·S^T + AP·KV)/len -> bf16 global ----
    {
        const int tyw = tid >> 4;
        const int tB = tyw * 4;
        const int dB = (tid & 15) * 4;
        float o[4][4] = {};
        for (int j4 = 0; j4 < 32; j4 += 4) {
            float a[4][4], s[4][4];
            #pragma unroll
            for (int r = 0; r < 4; ++r) {
                const float* ar = sAW + (tB + r) * 34 + j4;
                float2 a0 = *(const float2*)(ar);
                float2 a1 = *(const float2*)(ar + 2);
                a[r][0]=a0.x; a[r][1]=a0.y; a[r][2]=a1.x; a[r][3]=a1.y;
                const float* sr = sS + (dB + r) * 34 + j4;
                float2 s0 = *(const float2*)(sr);
                float2 s1 = *(const float2*)(sr + 2);
                s[r][0]=s0.x; s[r][1]=s0.y; s[r][2]=s1.x; s[r][3]=s1.y;
            }
            #pragma unroll
            for (int i = 0; i < 4; ++i)
                #pragma unroll
                for (int j = 0; j < 4; ++j)
                    o[i][j] += a[i][0]*s[j][0] + a[i][1]*s[j][1]
                             + a[i][2]*s[j][2] + a[i][3]*s[j][3];
        }
        for (int cc = 0; cc <= tyw; ++cc) {
            int s4 = cc * 4;
            float a[4][4], k[4][4];
            #pragma unroll
            for (int r = 0; r < 4; ++r) {
                const float* ar = sAP + (tB + r) * 66 + s4;
                float2 a0 = *(const float2*)(ar);
                float2 a1 = *(const float2*)(ar + 2);
                a[r][0]=a0.x; a[r][1]=a0.y; a[r][2]=a1.x; a[r][3]=a1.y;
                const float* kr = sKV + (s4 + r) * 66 + dB;
                float2 k0 = *(const float2*)(kr);
                float2 k1 = *(const float2*)(kr + 2);
                k[r][0]=k0.x; k[r][1]=k0.y; k[r][2]=k1.x; k[r][3]=k1.y;
            }
            #pragma unroll
            for (int i = 0; i < 4; ++i)
                #pragma unroll
                for (int j = 0; j < 4; ++j)
                    o[i][j] += a[i][0]*k[0][j] + a[i][1]*k[1][j]
                             + a[i][2]*k[2][j] + a[i][3]*k[3][j];
        }
        #pragma unroll
        for (int i = 0; i < 4; ++i) {
            int tt = t0 + tB + i;
            float inv = 1.0f / (float)(tt + 1);
            union { ushort4 u; bf16 bb[4]; } st;
            #pragma unroll
            for (int j = 0; j < 4; ++j) st.bb[j] = __float2bfloat16(o[i][j] * inv);
            *(ushort4*)((unsigned short*)attn + ((size_t)(tt * 2 + b)) * 1024 + h * 64 + dB) = st.u;
        }
    }
}

extern "C" void kernel_launch(void* const* d_in, const int* in_sizes, int n_in,
                              void* d_out, int out_size, void* d_ws, size_t ws_size,
                              hipStream_t stream) {
    const float* query  = (const float*)d_in[0];
    const float* pquery = (const float*)d_in[1];
    const float* Wpq = (const float*)d_in[2];
    const float* bpq = (const float*)d_in[3];
    const float* Wq  = (const float*)d_in[4];
    const float* bq  = (const float*)d_in[5];
    const float* Wpc = (const float*)d_in[6];
    const float* bpc = (const float*)d_in[7];
    const float* Wc  = (const float*)d_in[8];
    const float* bc  = (const float*)d_in[9];
    const float* Wo  = (const float*)d_in[10];
    const float* bo  = (const float*)d_in[11];
    float* out = (float*)d_out;

    const int T = 2048, E = 1024, MROWS = 4096;
    const int NCH = 32;
    const float SCALING = 0.125f;

    float* ws = (float*)d_ws;
    float* pq_buf    = ws;
    float* q_buf     = pq_buf + 65536;
    float* kv_buf    = q_buf  + 4194304;
    float* kp_buf    = kv_buf + 4194304;
    float* pattn_buf = kp_buf + 4194304;
    float* S_buf     = pattn_buf + 2097152;
    bf16*  qbf       = (bf16*)(S_buf + 2097152);
    bf16*  wq_bf     = (bf16*)(S_buf + 2097152 + 2097152);
    bf16*  wpc_bf    = wq_bf  + 1048576;
    bf16*  wc_bf     = wpc_bf + 1048576;
    bf16*  wo_bf     = wc_bf  + 1048576;
    bf16*  attn_bf   = (bf16*)kp_buf;

    f2b_kernel<<<4096, 256, 0, stream>>>(query, qbf, 1048576);
    f2b_kernel<<<1024, 256, 0, stream>>>(Wq,  wq_bf,  262144);
    f2b_kernel<<<1024, 256, 0, stream>>>(Wpc, wpc_bf, 262144);
    f2b_kernel<<<1024, 256, 0, stream>>>(Wc,  wc_bf,  262144);
    f2b_kernel<<<1024, 256, 0, stream>>>(Wo,  wo_bf,  262144);

    dim3 bgrid(E/128, MROWS/128);

    gemm_nt<<<dim3(E/128, 1), 256, 0, stream>>>(pquery, Wpq, bpq, pq_buf, 64, E, E, SCALING);
    gemm_bf16_nt<<<bgrid, 256, 0, stream>>>(qbf, wpc_bf, bpc, kp_buf, MROWS, E, E, 1.0f);
    gemm_bf16_nt<<<bgrid, 256, 0, stream>>>(qbf, wq_bf, bq, q_buf, MROWS, E, E, SCALING);
    gemm_bf16_nt<<<bgrid, 256, 0, stream>>>(qbf, wc_bf, bc, kv_buf, MROWS, E, E, 1.0f);
    pattn_kernel<<<dim3(T/64, 32), 256, 0, stream>>>(kp_buf, pq_buf, pattn_buf, T);
    chunk_sum_kernel<<<dim3(NCH, 32), 256, 0, stream>>>(kv_buf, pattn_buf, S_buf, T);
    prefix_state_kernel<<<256, 256, 0, stream>>>(S_buf);
    chunk_attn<<<dim3(NCH, 32), 256, 0, stream>>>(q_buf, kv_buf, pattn_buf, S_buf, attn_bf, T);
    gemm_bf16_nt<<<bgrid, 256, 0, stream>>>(attn_bf, wo_bf, bo, out, MROWS, E, E, 1.0f);
}

// Round 6
// 295.796 us; speedup vs baseline: 5.1273x; 1.6880x over previous
//
#include <hip/hip_runtime.h>
#include <hip/hip_bf16.h>
#include <math.h>

typedef __hip_bfloat16 bf16;
typedef __attribute__((ext_vector_type(8))) short bf16x8;
typedef __attribute__((ext_vector_type(4))) float f32x4;

__device__ __forceinline__ float bfbits(unsigned int u){ union{unsigned int x; float f;} c; c.x = u; return c.f; }

#define LN2F 0.69314718055994531f

// ---------- fp32 -> bf16 conversion (vectorized) ----------
__global__ __launch_bounds__(256)
void f2b_kernel(const float* __restrict__ s, bf16* __restrict__ d, int n4)
{
    int i = blockIdx.x * 256 + threadIdx.x;
    if (i < n4) {
        float4 v = ((const float4*)s)[i];
        union { ushort4 u; bf16 b[4]; } o;
        o.b[0] = __float2bfloat16(v.x);
        o.b[1] = __float2bfloat16(v.y);
        o.b[2] = __float2bfloat16(v.z);
        o.b[3] = __float2bfloat16(v.w);
        ((ushort4*)d)[i] = o.u;
    }
}

// concat 3 bias vectors of 1024 into 3072
__global__ __launch_bounds__(256)
void bias_cat_kernel(const float* __restrict__ a, const float* __restrict__ b,
                     const float* __restrict__ c, float* __restrict__ o)
{
    int i = blockIdx.x * 256 + threadIdx.x;  // 3072
    float v = (i < 1024) ? a[i] : ((i < 2048) ? b[i - 1024] : c[i - 2048]);
    o[i] = v;
}

// ---------- bf16 MFMA GEMM:  C[m][n] = sc(n)*(sum_k A[m][k]*B[n][k] + bias[n]) ----------
// sc(n) = scale_mid if (n>>10)==1 else scale_all  (handles fused q-scaling)
__global__ __launch_bounds__(256)
void gemm_bf16_nt(const bf16* __restrict__ A, const bf16* __restrict__ B,
                  const float* __restrict__ bias, float* __restrict__ C,
                  int M, int N, int K, float scale_all, float scale_mid)
{
    __shared__ short As[128 * 32];
    __shared__ short Bs[128 * 32];

    const int tid  = threadIdx.x;
    const int lane = tid & 63;
    const int wave = tid >> 6;
    const int m0 = blockIdx.y * 128;
    const int n0 = blockIdx.x * 128;
    const int wm = (wave >> 1) * 64;
    const int wn = (wave & 1) * 64;

    f32x4 acc[4][4] = {};

    const int c0 = tid, c1 = tid + 256;
    const int r0 = c0 >> 2, s0 = c0 & 3;
    const int r1 = c1 >> 2, s1 = c1 & 3;

    const int kb = lane >> 4;
    const int rr = lane & 15;

    for (int k0 = 0; k0 < K; k0 += 32) {
        uint4 a0 = *(const uint4*)(A + (size_t)(m0 + r0) * K + k0 + s0 * 8);
        uint4 a1 = *(const uint4*)(A + (size_t)(m0 + r1) * K + k0 + s1 * 8);
        uint4 b0 = *(const uint4*)(B + (size_t)(n0 + r0) * K + k0 + s0 * 8);
        uint4 b1 = *(const uint4*)(B + (size_t)(n0 + r1) * K + k0 + s1 * 8);
        __syncthreads();
        *(uint4*)(As + c0 * 8) = a0;
        *(uint4*)(As + c1 * 8) = a1;
        *(uint4*)(Bs + c0 * 8) = b0;
        *(uint4*)(Bs + c1 * 8) = b1;
        __syncthreads();

        bf16x8 af[4], bfr[4];
        #pragma unroll
        for (int mi = 0; mi < 4; ++mi)
            af[mi] = *(const bf16x8*)(As + (wm + mi * 16 + rr) * 32 + kb * 8);
        #pragma unroll
        for (int ni = 0; ni < 4; ++ni)
            bfr[ni] = *(const bf16x8*)(Bs + (wn + ni * 16 + rr) * 32 + kb * 8);
        #pragma unroll
        for (int mi = 0; mi < 4; ++mi)
            #pragma unroll
            for (int ni = 0; ni < 4; ++ni)
                acc[mi][ni] = __builtin_amdgcn_mfma_f32_16x16x32_bf16(
                    af[mi], bfr[ni], acc[mi][ni], 0, 0, 0);
    }

    const int col_l = lane & 15;
    const int row_q = lane >> 4;
    #pragma unroll
    for (int ni = 0; ni < 4; ++ni) {
        int col = n0 + wn + ni * 16 + col_l;
        float bb = bias[col];
        float sc = ((col >> 10) == 1) ? scale_mid : scale_all;
        #pragma unroll
        for (int mi = 0; mi < 4; ++mi) {
            #pragma unroll
            for (int r = 0; r < 4; ++r) {
                int row = m0 + wm + mi * 16 + row_q * 4 + r;
                C[(size_t)row * N + col] = sc * (acc[mi][ni][r] + bb);
            }
        }
    }
}

// ---------- pq projection: M=64, K-split MFMA partials ----------
// part[kslice][64][1024] += A(64xK) . B(1024xK)^T over K slice of 128
__global__ __launch_bounds__(256)
void gemm_pq_partial(const bf16* __restrict__ A, const bf16* __restrict__ B,
                     float* __restrict__ part)
{
    __shared__ short As[64 * 32];
    __shared__ short Bs[128 * 32];

    const int tid  = threadIdx.x;
    const int lane = tid & 63;
    const int wave = tid >> 6;
    const int n0 = blockIdx.x * 128;
    const int kslice = blockIdx.y;
    const int kbase = kslice * 128;

    f32x4 acc[4][2] = {};

    const int ra = tid >> 2, sa = tid & 3;       // A chunk
    const int c0 = tid, c1 = tid + 256;          // B chunks
    const int rb0 = c0 >> 2, sb0 = c0 & 3;
    const int rb1 = c1 >> 2, sb1 = c1 & 3;

    const int kb = lane >> 4;
    const int rr = lane & 15;

    for (int k0 = kbase; k0 < kbase + 128; k0 += 32) {
        uint4 av = *(const uint4*)(A + (size_t)ra * 1024 + k0 + sa * 8);
        uint4 b0 = *(const uint4*)(B + (size_t)(n0 + rb0) * 1024 + k0 + sb0 * 8);
        uint4 b1 = *(const uint4*)(B + (size_t)(n0 + rb1) * 1024 + k0 + sb1 * 8);
        __syncthreads();
        *(uint4*)(As + tid * 8) = av;
        *(uint4*)(Bs + c0 * 8) = b0;
        *(uint4*)(Bs + c1 * 8) = b1;
        __syncthreads();

        bf16x8 af[4], bfr[2];
        #pragma unroll
        for (int mi = 0; mi < 4; ++mi)
            af[mi] = *(const bf16x8*)(As + (mi * 16 + rr) * 32 + kb * 8);
        #pragma unroll
        for (int ni = 0; ni < 2; ++ni)
            bfr[ni] = *(const bf16x8*)(Bs + (wave * 32 + ni * 16 + rr) * 32 + kb * 8);
        #pragma unroll
        for (int mi = 0; mi < 4; ++mi)
            #pragma unroll
            for (int ni = 0; ni < 2; ++ni)
                acc[mi][ni] = __builtin_amdgcn_mfma_f32_16x16x32_bf16(
                    af[mi], bfr[ni], acc[mi][ni], 0, 0, 0);
    }

    const int col_l = lane & 15;
    const int row_q = lane >> 4;
    float* dst = part + (size_t)kslice * 65536;
    #pragma unroll
    for (int ni = 0; ni < 2; ++ni) {
        int col = n0 + wave * 32 + ni * 16 + col_l;
        #pragma unroll
        for (int mi = 0; mi < 4; ++mi) {
            #pragma unroll
            for (int r = 0; r < 4; ++r) {
                int row = mi * 16 + row_q * 4 + r;
                dst[(size_t)row * 1024 + col] = acc[mi][ni][r];
            }
        }
    }
}

// pq[m][n] = 0.125*(sum_s part[s][m][n] + bias[n])
__global__ __launch_bounds__(256)
void pq_reduce(const float* __restrict__ part, const float* __restrict__ bias,
               float* __restrict__ pq)
{
    int gid = blockIdx.x * 256 + threadIdx.x;   // 65536
    int n = gid & 1023;
    float s = bias[n];
    #pragma unroll
    for (int k = 0; k < 8; ++k) s += part[(size_t)k * 65536 + gid];
    pq[gid] = 0.125f * s;
}

// pattn[bh][t][p] = softplus(ln2 * (kp_bh[t] . pq_bh[p])) / ln2 ; kp has row stride ld
__global__ __launch_bounds__(256)
void pattn_kernel(const float* __restrict__ kp, const float* __restrict__ pq,
                  float* __restrict__ pattn, int T, int ld)
{
    const int bh = blockIdx.y;
    const int t0 = blockIdx.x * 64;
    const int b = bh >> 4, h = bh & 15;
    __shared__ float pqs[32][65];
    __shared__ float kps[64][65];
    const int tid = threadIdx.x;
    #pragma unroll
    for (int l=0;l<8;++l) {
        int idx = tid + l*256;
        int p = idx >> 6, d = idx & 63;
        pqs[p][d] = pq[(size_t)(p*2+b)*1024 + h*64 + d];
    }
    #pragma unroll
    for (int l=0;l<16;++l) {
        int idx = tid + l*256;
        int t = idx >> 6, d = idx & 63;
        kps[t][d] = kp[(size_t)((t0+t)*2+b)*ld + h*64 + d];
    }
    __syncthreads();
    const int p = tid & 31;
    const int tb = tid >> 5;
    #pragma unroll
    for (int l=0;l<8;++l) {
        int t = tb + l*8;
        float dot = 0.f;
        for (int d=0;d<64;++d) dot += kps[t][d]*pqs[p][d];
        float z = LN2F * dot;
        float sp = (fmaxf(z, 0.f) + log1pf(expf(-fabsf(z)))) / LN2F;
        pattn[((size_t)bh*T + t0 + t)*32 + p] = sp;
    }
}

// Chunk-local sums: S[bh][c][i*32+j] = sum_{t in chunk c} kv[t][i]*pattn[t][j]
__global__ __launch_bounds__(256)
void chunk_sum_kernel(const float* __restrict__ kv, const float* __restrict__ pattn,
                      float* __restrict__ Sbuf, int T, int ld)
{
    const int C = 64, NCH = 32;
    const int c = blockIdx.x, bh = blockIdx.y;
    const int b = bh >> 4, h = bh & 15;
    const int t0 = c * C;
    const int tid = threadIdx.x;
    __shared__ float kvs[64][64];
    __shared__ float ps[64][32];

    #pragma unroll
    for (int l=0;l<16;++l) {
        int idx = tid + l*256;
        int t = idx >> 6, d = idx & 63;
        kvs[t][d] = kv[(size_t)((t0+t)*2+b)*ld + h*64 + d];
    }
    #pragma unroll
    for (int l=0;l<8;++l) {
        int idx = tid + l*256;
        int t = idx >> 5, j = idx & 31;
        ps[t][j] = pattn[((size_t)bh*T + t0 + t)*32 + j];
    }
    __syncthreads();

    const int j = tid & 31;
    const int ib = tid >> 5;
    float acc[8] = {};
    for (int r = 0; r < 64; ++r) {
        float pj = ps[r][j];
        #pragma unroll
        for (int k=0;k<8;++k) acc[k] += kvs[r][ib + 8*k] * pj;
    }
    float* Sdst = Sbuf + ((size_t)bh*NCH + c)*2048;
    #pragma unroll
    for (int k=0;k<8;++k) Sdst[tid + k*256] = acc[k];
}

// In-place exclusive prefix over chunks
__global__ __launch_bounds__(256)
void prefix_state_kernel(float* __restrict__ Sbuf)
{
    const int NCH = 32;
    int gid = blockIdx.x * 256 + threadIdx.x;
    int bh = gid >> 11, e = gid & 2047;
    float* p = Sbuf + (size_t)bh * NCH * 2048 + e;
    float run = 0.f;
    #pragma unroll
    for (int c = 0; c < NCH; ++c) {
        float t = p[c * 2048];
        p[c * 2048] = run;
        run += t;
    }
}

// Per (bh, chunk): both causal-attention stages + softmax; register-tiled fp32.
__global__ __launch_bounds__(256)
void chunk_attn(const float* __restrict__ qg, const float* __restrict__ kvg,
                const float* __restrict__ pg, const float* __restrict__ Sg,
                bf16* __restrict__ attn, int T, int ld)
{
    const int NCH = 32;
    __shared__ float smemf[14976];
    short* sQb = (short*)smemf;
    float* sAW = smemf;
    float* sKV = smemf + 2176;
    float* sQK = smemf + 6400;
    float* sAP = sQK;
    float* sP  = smemf + 10624;
    float* sS  = smemf + 12800;

    const int bh = blockIdx.y, c = blockIdx.x;
    const int b = bh >> 4, h = bh & 15;
    const int t0 = c * 64;
    const int tid = threadIdx.x;
    const float* Sblk = Sg + ((size_t)bh*NCH + c)*2048;

    // ---- stage 1: staging ----
    #pragma unroll
    for (int l = 0; l < 4; ++l) {
        int idx = tid + l * 256;
        int t = idx >> 4, d4 = (idx & 15) * 4;
        size_t g = (size_t)((t0 + t) * 2 + b) * ld + h * 64 + d4;
        float4 qv = *(const float4*)(qg + g);
        union { ushort4 u; bf16 bb[4]; } cv;
        cv.bb[0] = __float2bfloat16(qv.x);
        cv.bb[1] = __float2bfloat16(qv.y);
        cv.bb[2] = __float2bfloat16(qv.z);
        cv.bb[3] = __float2bfloat16(qv.w);
        *(ushort4*)(sQb + t * 68 + d4) = cv.u;
        float4 kv = *(const float4*)(kvg + g);
        float* kd = sKV + t * 66 + d4;
        kd[0]=kv.x; kd[1]=kv.y; kd[2]=kv.z; kd[3]=kv.w;
    }
    #pragma unroll
    for (int l = 0; l < 2; ++l) {
        int idx = tid + l * 256;
        int r = idx >> 3, j4 = (idx & 7) * 4;
        float4 pv = *(const float4*)(pg + ((size_t)bh * T + t0 + r) * 32 + j4);
        float* pd = sP + r * 34 + j4;
        pd[0]=pv.x; pd[1]=pv.y; pd[2]=pv.z; pd[3]=pv.w;
        float4 sv = *(const float4*)(Sblk + r * 32 + j4);
        float* sd = sS + r * 34 + j4;
        sd[0]=sv.x; sd[1]=sv.y; sd[2]=sv.z; sd[3]=sv.w;
    }
    __syncthreads();

    // ---- stage 2: QK = Q · KV^T ----
    {
        const int tB = (tid >> 4) * 4;
        const int sB = (tid & 15) * 4;
        float qk[4][4] = {};
        for (int d4 = 0; d4 < 64; d4 += 4) {
            float qv[4][4], kv[4][4];
            #pragma unroll
            for (int r = 0; r < 4; ++r) {
                uint2 uq = *(const uint2*)(sQb + (tB + r) * 68 + d4);
                qv[r][0] = bfbits(uq.x << 16);
                qv[r][1] = bfbits(uq.x & 0xffff0000u);
                qv[r][2] = bfbits(uq.y << 16);
                qv[r][3] = bfbits(uq.y & 0xffff0000u);
            }
            #pragma unroll
            for (int r = 0; r < 4; ++r) {
                float2 k0 = *(const float2*)(sKV + (sB + r) * 66 + d4);
                float2 k1 = *(const float2*)(sKV + (sB + r) * 66 + d4 + 2);
                kv[r][0]=k0.x; kv[r][1]=k0.y; kv[r][2]=k1.x; kv[r][3]=k1.y;
            }
            #pragma unroll
            for (int i = 0; i < 4; ++i)
                #pragma unroll
                for (int j = 0; j < 4; ++j)
                    qk[i][j] += qv[i][0]*kv[j][0] + qv[i][1]*kv[j][1]
                              + qv[i][2]*kv[j][2] + qv[i][3]*kv[j][3];
        }
        #pragma unroll
        for (int i = 0; i < 4; ++i)
            #pragma unroll
            for (int j = 0; j < 4; ++j)
                sQK[(tB + i) * 66 + sB + j] = qk[i][j];
    }
    __syncthreads();

    // ---- stage 3: AW = (Q·S + causal(QK)·P)/len, softmax over 32 ----
    const int t3 = tid >> 2;
    const int j0 = (tid & 3) * 8;
    float aw[8] = {};
    {
        for (int i = 0; i < 64; ++i) {
            float q = bfbits(((unsigned int)(unsigned short)sQb[t3 * 68 + i]) << 16);
            const float* sr = sS + i * 34 + j0;
            float2 s0 = *(const float2*)(sr);
            float2 s1 = *(const float2*)(sr + 2);
            float2 s2 = *(const float2*)(sr + 4);
            float2 s3 = *(const float2*)(sr + 6);
            aw[0] += q * s0.x; aw[1] += q * s0.y;
            aw[2] += q * s1.x; aw[3] += q * s1.y;
            aw[4] += q * s2.x; aw[5] += q * s2.y;
            aw[6] += q * s3.x; aw[7] += q * s3.y;
        }
        for (int s = 0; s <= t3; ++s) {
            float w = sQK[t3 * 66 + s];
            const float* pr = sP + s * 34 + j0;
            float2 p0 = *(const float2*)(pr);
            float2 p1 = *(const float2*)(pr + 2);
            float2 p2 = *(const float2*)(pr + 4);
            float2 p3 = *(const float2*)(pr + 6);
            aw[0] += w * p0.x; aw[1] += w * p0.y;
            aw[2] += w * p1.x; aw[3] += w * p1.y;
            aw[4] += w * p2.x; aw[5] += w * p2.y;
            aw[6] += w * p3.x; aw[7] += w * p3.y;
        }
        float inv_len = 1.0f / (float)(t0 + t3 + 1);
        #pragma unroll
        for (int k = 0; k < 8; ++k) aw[k] *= inv_len;
        float m = aw[0];
        #pragma unroll
        for (int k = 1; k < 8; ++k) m = fmaxf(m, aw[k]);
        m = fmaxf(m, __shfl_xor(m, 1));
        m = fmaxf(m, __shfl_xor(m, 2));
        float sum = 0.f;
        #pragma unroll
        for (int k = 0; k < 8; ++k) { aw[k] = __expf(aw[k] - m); sum += aw[k]; }
        sum += __shfl_xor(sum, 1);
        sum += __shfl_xor(sum, 2);
        float rs = 1.0f / sum;
        #pragma unroll
        for (int k = 0; k < 8; ++k) aw[k] *= rs;
    }
    __syncthreads();
    {
        float* dst = sAW + t3 * 34 + j0;
        #pragma unroll
        for (int k = 0; k < 8; k += 2) {
            float2 v; v.x = aw[k]; v.y = aw[k+1];
            *(float2*)(dst + k) = v;
        }
    }
    __syncthreads();

    // ---- stage 4: AP = causal(AW · P^T) ----
    {
        const int tB = (tid >> 4) * 4;
        const int sB = (tid & 15) * 4;
        float ap[4][4] = {};
        for (int j4 = 0; j4 < 32; j4 += 4) {
            float a[4][4], p[4][4];
            #pragma unroll
            for (int r = 0; r < 4; ++r) {
                const float* ar = sAW + (tB + r) * 34 + j4;
                float2 a0 = *(const float2*)(ar);
                float2 a1 = *(const float2*)(ar + 2);
                a[r][0]=a0.x; a[r][1]=a0.y; a[r][2]=a1.x; a[r][3]=a1.y;
                const float* pr = sP + (sB + r) * 34 + j4;
                float2 p0 = *(const float2*)(pr);
                float2 p1 = *(const float2*)(pr + 2);
                p[r][0]=p0.x; p[r][1]=p0.y; p[r][2]=p1.x; p[r][3]=p1.y;
            }
            #pragma unroll
            for (int i = 0; i < 4; ++i)
                #pragma unroll
                for (int j = 0; j < 4; ++j)
                    ap[i][j] += a[i][0]*p[j][0] + a[i][1]*p[j][1]
                              + a[i][2]*p[j][2] + a[i][3]*p[j][3];
        }
        #pragma unroll
        for (int i = 0; i < 4; ++i)
            #pragma unroll
            for (int j = 0; j < 4; ++j)
                sAP[(tB + i) * 66 + sB + j] = (sB + j <= tB + i) ? ap[i][j] : 0.f;
    }
    __syncthreads();

    // ---- stage 5: OUT = (AW·S^T + AP·KV)/len -> bf16 global ----
    {
        const int tyw = tid >> 4;
        const int tB = tyw * 4;
        const int dB = (tid & 15) * 4;
        float o[4][4] = {};
        for (int j4 = 0; j4 < 32; j4 += 4) {
            float a[4][4], s[4][4];
            #pragma unroll
            for (int r = 0; r < 4; ++r) {
                const float* ar = sAW + (tB + r) * 34 + j4;
                float2 a0 = *(const float2*)(ar);
                float2 a1 = *(const float2*)(ar + 2);
                a[r][0]=a0.x; a[r][1]=a0.y; a[r][2]=a1.x; a[r][3]=a1.y;
                const float* sr = sS + (dB + r) * 34 + j4;
                float2 s0 = *(const float2*)(sr);
                float2 s1 = *(const float2*)(sr + 2);
                s[r][0]=s0.x; s[r][1]=s0.y; s[r][2]=s1.x; s[r][3]=s1.y;
            }
            #pragma unroll
            for (int i = 0; i < 4; ++i)
                #pragma unroll
                for (int j = 0; j < 4; ++j)
                    o[i][j] += a[i][0]*s[j][0] + a[i][1]*s[j][1]
                             + a[i][2]*s[j][2] + a[i][3]*s[j][3];
        }
        for (int cc = 0; cc <= tyw; ++cc) {
            int s4 = cc * 4;
            float a[4][4], k[4][4];
            #pragma unroll
            for (int r = 0; r < 4; ++r) {
                const float* ar = sAP + (tB + r) * 66 + s4;
                float2 a0 = *(const float2*)(ar);
                float2 a1 = *(const float2*)(ar + 2);
                a[r][0]=a0.x; a[r][1]=a0.y; a[r][2]=a1.x; a[r][3]=a1.y;
                const float* kr = sKV + (s4 + r) * 66 + dB;
                float2 k0 = *(const float2*)(kr);
                float2 k1 = *(const float2*)(kr + 2);
                k[r][0]=k0.x; k[r][1]=k0.y; k[r][2]=k1.x; k[r][3]=k1.y;
            }
            #pragma unroll
            for (int i = 0; i < 4; ++i)
                #pragma unroll
                for (int j = 0; j < 4; ++j)
                    o[i][j] += a[i][0]*k[0][j] + a[i][1]*k[1][j]
                             + a[i][2]*k[2][j] + a[i][3]*k[3][j];
        }
        #pragma unroll
        for (int i = 0; i < 4; ++i) {
            int tt = t0 + tB + i;
            float inv = 1.0f / (float)(tt + 1);
            union { ushort4 u; bf16 bb[4]; } st;
            #pragma unroll
            for (int j = 0; j < 4; ++j) st.bb[j] = __float2bfloat16(o[i][j] * inv);
            *(ushort4*)((unsigned short*)attn + ((size_t)(tt * 2 + b)) * 1024 + h * 64 + dB) = st.u;
        }
    }
}

extern "C" void kernel_launch(void* const* d_in, const int* in_sizes, int n_in,
                              void* d_out, int out_size, void* d_ws, size_t ws_size,
                              hipStream_t stream) {
    const float* query  = (const float*)d_in[0];
    const float* pquery = (const float*)d_in[1];
    const float* Wpq = (const float*)d_in[2];
    const float* bpq = (const float*)d_in[3];
    const float* Wq  = (const float*)d_in[4];
    const float* bq  = (const float*)d_in[5];
    const float* Wpc = (const float*)d_in[6];
    const float* bpc = (const float*)d_in[7];
    const float* Wc  = (const float*)d_in[8];
    const float* bc  = (const float*)d_in[9];
    const float* Wo  = (const float*)d_in[10];
    const float* bo  = (const float*)d_in[11];
    float* out = (float*)d_out;

    const int T = 2048, E = 1024, MROWS = 4096;
    const int NCH = 32;

    // workspace layout (floats) — total 21,037,056 (= round-5 proven footprint)
    float* ws = (float*)d_ws;
    float* pq_buf    = ws;                         // 65536
    float* Cbig      = pq_buf + 65536;             // 4096*3072 = 12582912 (kp|q|kv)
    float* pattn_buf = Cbig + 12582912;            // 2097152
    float* S_buf     = pattn_buf + 2097152;        // 2097152 (first 524288 reused as pq partials)
    float* qbf_f     = S_buf + 2097152;            // 2097152 f-equiv (bf16 4096x1024; later attn_bf)
    float* wcat_f    = qbf_f + 2097152;            // 1572864 f-equiv (bf16 3072x1024; first part = wpq temp)
    float* wo_f      = wcat_f + 1572864;           // 524288 f-equiv

    bf16* qbf     = (bf16*)qbf_f;
    bf16* wcat    = (bf16*)wcat_f;
    bf16* wpq_bf  = (bf16*)wcat_f;                 // temp overlay, dead before wcat written
    bf16* wo_bf   = (bf16*)wo_f;
    bf16* pqy_bf  = (bf16*)pattn_buf;              // temp overlay (dead before pattn written)
    float* biascat = pattn_buf + 32768;            // 3072 floats, read before pattn written
    float* pq_part = S_buf;                        // 8*65536, consumed before chunk_sum writes S
    bf16* attn_bf = qbf;                           // overlay qbf after fused GEMM

    // --- conversions + pq projection (MFMA, K-split) ---
    f2b_kernel<<<4096, 256, 0, stream>>>(query, qbf, 1048576);
    f2b_kernel<<<64,   256, 0, stream>>>(pquery, pqy_bf, 16384);
    f2b_kernel<<<1024, 256, 0, stream>>>(Wpq, wpq_bf, 262144);
    gemm_pq_partial<<<dim3(8, 8), 256, 0, stream>>>(pqy_bf, wpq_bf, pq_part);
    pq_reduce<<<256, 256, 0, stream>>>(pq_part, bpq, pq_buf);

    // --- fused weight concat (overwrites wpq temp) ---
    f2b_kernel<<<1024, 256, 0, stream>>>(Wpc, wcat,               262144); // cols 0..1023: kp
    f2b_kernel<<<1024, 256, 0, stream>>>(Wq,  wcat + 1048576,     262144); // cols 1024..2047: q
    f2b_kernel<<<1024, 256, 0, stream>>>(Wc,  wcat + 2097152,     262144); // cols 2048..3071: kv
    f2b_kernel<<<1024, 256, 0, stream>>>(Wo,  wo_bf,              262144);
    bias_cat_kernel<<<12, 256, 0, stream>>>(bpc, bq, bc, biascat);

    // --- fused projection GEMM: Cbig[4096][3072] = kp|q|kv ---
    gemm_bf16_nt<<<dim3(3072/128, MROWS/128), 256, 0, stream>>>(
        qbf, wcat, biascat, Cbig, MROWS, 3072, E, 1.0f, 0.125f);

    // --- attention pipeline (stride-3072 reads) ---
    pattn_kernel<<<dim3(T/64, 32), 256, 0, stream>>>(Cbig, pq_buf, pattn_buf, T, 3072);
    chunk_sum_kernel<<<dim3(NCH, 32), 256, 0, stream>>>(Cbig + 2048, pattn_buf, S_buf, T, 3072);
    prefix_state_kernel<<<256, 256, 0, stream>>>(S_buf);
    chunk_attn<<<dim3(NCH, 32), 256, 0, stream>>>(Cbig + 1024, Cbig + 2048, pattn_buf, S_buf, attn_bf, T, 3072);

    // --- output projection ---
    gemm_bf16_nt<<<dim3(E/128, MROWS/128), 256, 0, stream>>>(
        attn_bf, wo_bf, bo, out, MROWS, E, E, 1.0f, 1.0f);
}

// Round 7
// 284.662 us; speedup vs baseline: 5.3279x; 1.0391x over previous
//
#include <hip/hip_runtime.h>
#include <hip/hip_bf16.h>
#include <math.h>

typedef __hip_bfloat16 bf16;
typedef __attribute__((ext_vector_type(8))) short bf16x8;
typedef __attribute__((ext_vector_type(4))) float f32x4;

__device__ __forceinline__ float bfbits(unsigned int u){ union{unsigned int x; float f;} c; c.x = u; return c.f; }

// async global->LDS 16B (m97 pattern: lds dest must be wave-uniform base + lane*16)
__device__ __forceinline__ void gl_lds16(const bf16* g, short* l) {
    __builtin_amdgcn_global_load_lds(
        (const __attribute__((address_space(1))) void*)g,
        (__attribute__((address_space(3))) void*)l, 16, 0, 0);
}

#define LN2F 0.69314718055994531f

__device__ __forceinline__ void cvt_store4(bf16* d, size_t idx, float4 v) {
    union { ushort4 u; bf16 b[4]; } o;
    o.b[0] = __float2bfloat16(v.x);
    o.b[1] = __float2bfloat16(v.y);
    o.b[2] = __float2bfloat16(v.z);
    o.b[3] = __float2bfloat16(v.w);
    ((ushort4*)d)[idx] = o.u;
}

// ---------- conversion batch 1: query, pquery, Wpq ----------
__global__ __launch_bounds__(256)
void conv1_kernel(const float* __restrict__ query, const float* __restrict__ pquery,
                  const float* __restrict__ Wpq, bf16* __restrict__ qbf,
                  bf16* __restrict__ pqy, bf16* __restrict__ wpq)
{
    int blk = blockIdx.x;
    const float* s; bf16* d; int i;
    if (blk < 4096)      { s = query;  d = qbf; i = blk * 256 + threadIdx.x; }
    else if (blk < 4160) { s = pquery; d = pqy; i = (blk - 4096) * 256 + threadIdx.x; }
    else                 { s = Wpq;    d = wpq; i = (blk - 4160) * 256 + threadIdx.x; }
    cvt_store4(d, i, ((const float4*)s)[i]);
}

// ---------- conversion batch 2: Wpc|Wq|Wc -> wcat, Wo -> wo_bf, bias concat ----------
__global__ __launch_bounds__(256)
void conv2_kernel(const float* __restrict__ Wpc, const float* __restrict__ Wq,
                  const float* __restrict__ Wc, const float* __restrict__ Wo,
                  const float* __restrict__ bpc, const float* __restrict__ bq,
                  const float* __restrict__ bc,
                  bf16* __restrict__ wcat, bf16* __restrict__ wo_bf,
                  float* __restrict__ biascat)
{
    int blk = blockIdx.x;
    if (blk < 3072) {
        const float* s = (blk < 1024) ? Wpc : ((blk < 2048) ? Wq : Wc);
        int rel = (blk & 1023) * 256 + threadIdx.x;
        bf16* d = wcat + (size_t)(blk >> 10) * 1048576;
        cvt_store4(d, rel, ((const float4*)s)[rel]);
    } else if (blk < 4096) {
        int rel = (blk - 3072) * 256 + threadIdx.x;
        cvt_store4(wo_bf, rel, ((const float4*)Wo)[rel]);
    } else {
        int i = (blk - 4096) * 256 + threadIdx.x;  // 0..3071
        float v = (i < 1024) ? bpc[i] : ((i < 2048) ? bq[i - 1024] : bc[i - 2048]);
        biascat[i] = v;
    }
}

// ---------- bf16 MFMA GEMM (global_load_lds staging) ----------
__global__ __launch_bounds__(256)
void gemm_bf16_nt(const bf16* __restrict__ A, const bf16* __restrict__ B,
                  const float* __restrict__ bias, float* __restrict__ C,
                  int M, int N, int K, float scale_all, float scale_mid)
{
    __shared__ short As[128 * 32];
    __shared__ short Bs[128 * 32];

    const int tid  = threadIdx.x;
    const int lane = tid & 63;
    const int wave = tid >> 6;
    const int m0 = blockIdx.y * 128;
    const int n0 = blockIdx.x * 128;
    const int wm = (wave >> 1) * 64;
    const int wn = (wave & 1) * 64;

    f32x4 acc[4][4] = {};

    const int c0 = tid, c1 = tid + 256;
    const int r0 = c0 >> 2, s0 = c0 & 3;
    const int r1 = c1 >> 2, s1 = c1 & 3;

    const int kb = lane >> 4;
    const int rr = lane & 15;

    for (int k0 = 0; k0 < K; k0 += 32) {
        __syncthreads();   // previous iteration's LDS reads complete
        gl_lds16(A + (size_t)(m0 + r0) * K + k0 + s0 * 8, As + c0 * 8);
        gl_lds16(A + (size_t)(m0 + r1) * K + k0 + s1 * 8, As + c1 * 8);
        gl_lds16(B + (size_t)(n0 + r0) * K + k0 + s0 * 8, Bs + c0 * 8);
        gl_lds16(B + (size_t)(n0 + r1) * K + k0 + s1 * 8, Bs + c1 * 8);
        __syncthreads();   // barrier drains vmcnt -> LDS valid

        bf16x8 af[4], bfr[4];
        #pragma unroll
        for (int mi = 0; mi < 4; ++mi)
            af[mi] = *(const bf16x8*)(As + (wm + mi * 16 + rr) * 32 + kb * 8);
        #pragma unroll
        for (int ni = 0; ni < 4; ++ni)
            bfr[ni] = *(const bf16x8*)(Bs + (wn + ni * 16 + rr) * 32 + kb * 8);
        #pragma unroll
        for (int mi = 0; mi < 4; ++mi)
            #pragma unroll
            for (int ni = 0; ni < 4; ++ni)
                acc[mi][ni] = __builtin_amdgcn_mfma_f32_16x16x32_bf16(
                    af[mi], bfr[ni], acc[mi][ni], 0, 0, 0);
    }

    const int col_l = lane & 15;
    const int row_q = lane >> 4;
    #pragma unroll
    for (int ni = 0; ni < 4; ++ni) {
        int col = n0 + wn + ni * 16 + col_l;
        float bb = bias[col];
        float sc = ((col >> 10) == 1) ? scale_mid : scale_all;
        #pragma unroll
        for (int mi = 0; mi < 4; ++mi) {
            #pragma unroll
            for (int r = 0; r < 4; ++r) {
                int row = m0 + wm + mi * 16 + row_q * 4 + r;
                C[(size_t)row * N + col] = sc * (acc[mi][ni][r] + bb);
            }
        }
    }
}

// ---------- pq projection: M=64, K-split MFMA partials ----------
__global__ __launch_bounds__(256)
void gemm_pq_partial(const bf16* __restrict__ A, const bf16* __restrict__ B,
                     float* __restrict__ part)
{
    __shared__ short As[64 * 32];
    __shared__ short Bs[128 * 32];

    const int tid  = threadIdx.x;
    const int lane = tid & 63;
    const int wave = tid >> 6;
    const int n0 = blockIdx.x * 128;
    const int kslice = blockIdx.y;
    const int kbase = kslice * 128;

    f32x4 acc[4][2] = {};

    const int ra = tid >> 2, sa = tid & 3;
    const int c0 = tid, c1 = tid + 256;
    const int rb0 = c0 >> 2, sb0 = c0 & 3;
    const int rb1 = c1 >> 2, sb1 = c1 & 3;

    const int kb = lane >> 4;
    const int rr = lane & 15;

    for (int k0 = kbase; k0 < kbase + 128; k0 += 32) {
        __syncthreads();
        gl_lds16(A + (size_t)ra * 1024 + k0 + sa * 8, As + tid * 8);
        gl_lds16(B + (size_t)(n0 + rb0) * 1024 + k0 + sb0 * 8, Bs + c0 * 8);
        gl_lds16(B + (size_t)(n0 + rb1) * 1024 + k0 + sb1 * 8, Bs + c1 * 8);
        __syncthreads();

        bf16x8 af[4], bfr[2];
        #pragma unroll
        for (int mi = 0; mi < 4; ++mi)
            af[mi] = *(const bf16x8*)(As + (mi * 16 + rr) * 32 + kb * 8);
        #pragma unroll
        for (int ni = 0; ni < 2; ++ni)
            bfr[ni] = *(const bf16x8*)(Bs + (wave * 32 + ni * 16 + rr) * 32 + kb * 8);
        #pragma unroll
        for (int mi = 0; mi < 4; ++mi)
            #pragma unroll
            for (int ni = 0; ni < 2; ++ni)
                acc[mi][ni] = __builtin_amdgcn_mfma_f32_16x16x32_bf16(
                    af[mi], bfr[ni], acc[mi][ni], 0, 0, 0);
    }

    const int col_l = lane & 15;
    const int row_q = lane >> 4;
    float* dst = part + (size_t)kslice * 65536;
    #pragma unroll
    for (int ni = 0; ni < 2; ++ni) {
        int col = n0 + wave * 32 + ni * 16 + col_l;
        #pragma unroll
        for (int mi = 0; mi < 4; ++mi) {
            #pragma unroll
            for (int r = 0; r < 4; ++r) {
                int row = mi * 16 + row_q * 4 + r;
                dst[(size_t)row * 1024 + col] = acc[mi][ni][r];
            }
        }
    }
}

__global__ __launch_bounds__(256)
void pq_reduce(const float* __restrict__ part, const float* __restrict__ bias,
               float* __restrict__ pq)
{
    int gid = blockIdx.x * 256 + threadIdx.x;   // 65536
    int n = gid & 1023;
    float s = bias[n];
    #pragma unroll
    for (int k = 0; k < 8; ++k) s += part[(size_t)k * 65536 + gid];
    pq[gid] = 0.125f * s;
}

// ---------- fused pattn + chunk-local state sum ----------
// grid (chunk, bh). Computes pattn for the chunk (written to global for chunk_attn)
// and the chunk-local S sum.
__global__ __launch_bounds__(256)
void pattn_sum_kernel(const float* __restrict__ kp, const float* __restrict__ kv,
                      const float* __restrict__ pq, float* __restrict__ pattn,
                      float* __restrict__ Sbuf, int T, int ld)
{
    const int NCH = 32;
    const int c = blockIdx.x, bh = blockIdx.y;
    const int b = bh >> 4, h = bh & 15;
    const int t0 = c * 64;
    const int tid = threadIdx.x;
    __shared__ float pqs[32][65];
    __shared__ float kps[64][65];   // overlaid by kvs[64][64] after pattn
    __shared__ float ps[64][33];
    float* kvs = &kps[0][0];

    #pragma unroll
    for (int l = 0; l < 8; ++l) {
        int idx = tid + l * 256;
        int p = idx >> 6, d = idx & 63;
        pqs[p][d] = pq[(size_t)(p * 2 + b) * 1024 + h * 64 + d];
    }
    #pragma unroll
    for (int l = 0; l < 16; ++l) {
        int idx = tid + l * 256;
        int t = idx >> 6, d = idx & 63;
        kps[t][d] = kp[(size_t)((t0 + t) * 2 + b) * ld + h * 64 + d];
    }
    __syncthreads();

    const int p = tid & 31, tb = tid >> 5;
    float spv[8];
    #pragma unroll
    for (int l = 0; l < 8; ++l) {
        int t = tb + l * 8;
        float dot = 0.f;
        for (int d = 0; d < 64; ++d) dot += kps[t][d] * pqs[p][d];
        float z = LN2F * dot;
        spv[l] = (fmaxf(z, 0.f) + log1pf(expf(-fabsf(z)))) / LN2F;
    }
    __syncthreads();   // kps reads done; safe to overlay with kvs

    #pragma unroll
    for (int l = 0; l < 8; ++l) {
        int t = tb + l * 8;
        ps[t][p] = spv[l];
        pattn[((size_t)bh * T + t0 + t) * 32 + p] = spv[l];
    }
    #pragma unroll
    for (int l = 0; l < 16; ++l) {
        int idx = tid + l * 256;
        int t = idx >> 6, d = idx & 63;
        kvs[t * 64 + d] = kv[(size_t)((t0 + t) * 2 + b) * ld + h * 64 + d];
    }
    __syncthreads();

    const int j = tid & 31;
    const int ib = tid >> 5;
    float acc[8] = {};
    for (int r = 0; r < 64; ++r) {
        float pj = ps[r][j];
        #pragma unroll
        for (int k = 0; k < 8; ++k) acc[k] += kvs[r * 64 + ib + 8 * k] * pj;
    }
    float* Sdst = Sbuf + ((size_t)bh * NCH + c) * 2048;
    #pragma unroll
    for (int k = 0; k < 8; ++k) Sdst[tid + k * 256] = acc[k];
}

// In-place exclusive prefix over chunks
__global__ __launch_bounds__(256)
void prefix_state_kernel(float* __restrict__ Sbuf)
{
    const int NCH = 32;
    int gid = blockIdx.x * 256 + threadIdx.x;
    int bh = gid >> 11, e = gid & 2047;
    float* p = Sbuf + (size_t)bh * NCH * 2048 + e;
    float run = 0.f;
    #pragma unroll
    for (int c = 0; c < NCH; ++c) {
        float t = p[c * 2048];
        p[c * 2048] = run;
        run += t;
    }
}

// Per (bh, chunk): both causal-attention stages + softmax.
// LDS (floats, 12928 total = 51712 B -> 3 blocks/CU):
//   sQb  bf16 [64][68] @0      (overlaid by sAW f32 [64][34])
//   sKVb bf16 [64][68] @2176
//   sQK  f32  [64][66] @4352   (overlaid by sAP)
//   sP   f32  [64][34] @8576
//   sS   f32  [64][34] @10752
__global__ __launch_bounds__(256)
void chunk_attn(const float* __restrict__ qg, const float* __restrict__ kvg,
                const float* __restrict__ pg, const float* __restrict__ Sg,
                bf16* __restrict__ attn, int T, int ld)
{
    const int NCH = 32;
    __shared__ float smemf[12928];
    short* sQb  = (short*)smemf;
    float* sAW  = smemf;
    short* sKVb = (short*)(smemf + 2176);
    float* sQK  = smemf + 4352;
    float* sAP  = sQK;
    float* sP   = smemf + 8576;
    float* sS   = smemf + 10752;

    const int bh = blockIdx.y, c = blockIdx.x;
    const int b = bh >> 4, h = bh & 15;
    const int t0 = c * 64;
    const int tid = threadIdx.x;
    const float* Sblk = Sg + ((size_t)bh * NCH + c) * 2048;

    // ---- stage 1: staging (q, kv -> bf16 LDS; p, S -> f32 LDS) ----
    #pragma unroll
    for (int l = 0; l < 4; ++l) {
        int idx = tid + l * 256;
        int t = idx >> 4, d4 = (idx & 15) * 4;
        size_t g = (size_t)((t0 + t) * 2 + b) * ld + h * 64 + d4;
        float4 qv = *(const float4*)(qg + g);
        union { ushort4 u; bf16 bb[4]; } cq;
        cq.bb[0] = __float2bfloat16(qv.x);
        cq.bb[1] = __float2bfloat16(qv.y);
        cq.bb[2] = __float2bfloat16(qv.z);
        cq.bb[3] = __float2bfloat16(qv.w);
        *(ushort4*)(sQb + t * 68 + d4) = cq.u;
        float4 kvv = *(const float4*)(kvg + g);
        union { ushort4 u; bf16 bb[4]; } ck;
        ck.bb[0] = __float2bfloat16(kvv.x);
        ck.bb[1] = __float2bfloat16(kvv.y);
        ck.bb[2] = __float2bfloat16(kvv.z);
        ck.bb[3] = __float2bfloat16(kvv.w);
        *(ushort4*)(sKVb + t * 68 + d4) = ck.u;
    }
    #pragma unroll
    for (int l = 0; l < 2; ++l) {
        int idx = tid + l * 256;
        int r = idx >> 3, j4 = (idx & 7) * 4;
        float4 pv = *(const float4*)(pg + ((size_t)bh * T + t0 + r) * 32 + j4);
        float* pd = sP + r * 34 + j4;
        pd[0] = pv.x; pd[1] = pv.y; pd[2] = pv.z; pd[3] = pv.w;
        float4 sv = *(const float4*)(Sblk + r * 32 + j4);
        float* sd = sS + r * 34 + j4;
        sd[0] = sv.x; sd[1] = sv.y; sd[2] = sv.z; sd[3] = sv.w;
    }
    __syncthreads();

    // ---- stage 2: QK = Q · KV^T (rows blocked, cols interleaved by 16) ----
    {
        const int tB = (tid >> 4) * 4;
        const int sC = tid & 15;
        float qk[4][4] = {};
        for (int d4 = 0; d4 < 64; d4 += 4) {
            float qv[4][4], kv[4][4];
            #pragma unroll
            for (int r = 0; r < 4; ++r) {
                uint2 uq = *(const uint2*)(sQb + (tB + r) * 68 + d4);
                qv[r][0] = bfbits(uq.x << 16);
                qv[r][1] = bfbits(uq.x & 0xffff0000u);
                qv[r][2] = bfbits(uq.y << 16);
                qv[r][3] = bfbits(uq.y & 0xffff0000u);
            }
            #pragma unroll
            for (int j = 0; j < 4; ++j) {
                uint2 uk = *(const uint2*)(sKVb + (sC + 16 * j) * 68 + d4);
                kv[j][0] = bfbits(uk.x << 16);
                kv[j][1] = bfbits(uk.x & 0xffff0000u);
                kv[j][2] = bfbits(uk.y << 16);
                kv[j][3] = bfbits(uk.y & 0xffff0000u);
            }
            #pragma unroll
            for (int i = 0; i < 4; ++i)
                #pragma unroll
                for (int j = 0; j < 4; ++j)
                    qk[i][j] += qv[i][0] * kv[j][0] + qv[i][1] * kv[j][1]
                              + qv[i][2] * kv[j][2] + qv[i][3] * kv[j][3];
        }
        #pragma unroll
        for (int i = 0; i < 4; ++i)
            #pragma unroll
            for (int j = 0; j < 4; ++j)
                sQK[(tB + i) * 66 + sC + 16 * j] = qk[i][j];
    }
    __syncthreads();

    // ---- stage 3: AW = (Q·S + causal(QK)·P)/len, softmax over 32 ----
    const int t3 = tid >> 2;
    const int j0 = (tid & 3) * 8;
    float aw[8] = {};
    {
        for (int i = 0; i < 64; ++i) {
            float q = bfbits(((unsigned int)(unsigned short)sQb[t3 * 68 + i]) << 16);
            const float* sr = sS + i * 34 + j0;
            float2 s0 = *(const float2*)(sr);
            float2 s1 = *(const float2*)(sr + 2);
            float2 s2 = *(const float2*)(sr + 4);
            float2 s3 = *(const float2*)(sr + 6);
            aw[0] += q * s0.x; aw[1] += q * s0.y;
            aw[2] += q * s1.x; aw[3] += q * s1.y;
            aw[4] += q * s2.x; aw[5] += q * s2.y;
            aw[6] += q * s3.x; aw[7] += q * s3.y;
        }
        for (int s = 0; s <= t3; ++s) {
            float w = sQK[t3 * 66 + s];
            const float* pr = sP + s * 34 + j0;
            float2 p0 = *(const float2*)(pr);
            float2 p1 = *(const float2*)(pr + 2);
            float2 p2 = *(const float2*)(pr + 4);
            float2 p3 = *(const float2*)(pr + 6);
            aw[0] += w * p0.x; aw[1] += w * p0.y;
            aw[2] += w * p1.x; aw[3] += w * p1.y;
            aw[4] += w * p2.x; aw[5] += w * p2.y;
            aw[6] += w * p3.x; aw[7] += w * p3.y;
        }
        float inv_len = 1.0f / (float)(t0 + t3 + 1);
        #pragma unroll
        for (int k = 0; k < 8; ++k) aw[k] *= inv_len;
        float m = aw[0];
        #pragma unroll
        for (int k = 1; k < 8; ++k) m = fmaxf(m, aw[k]);
        m = fmaxf(m, __shfl_xor(m, 1));
        m = fmaxf(m, __shfl_xor(m, 2));
        float sum = 0.f;
        #pragma unroll
        for (int k = 0; k < 8; ++k) { aw[k] = __expf(aw[k] - m); sum += aw[k]; }
        sum += __shfl_xor(sum, 1);
        sum += __shfl_xor(sum, 2);
        float rs = 1.0f / sum;
        #pragma unroll
        for (int k = 0; k < 8; ++k) aw[k] *= rs;
    }
    __syncthreads();   // sQb/sQK reads complete before overlays written
    {
        float* dst = sAW + t3 * 34 + j0;
        #pragma unroll
        for (int k = 0; k < 8; k += 2) {
            float2 v; v.x = aw[k]; v.y = aw[k + 1];
            *(float2*)(dst + k) = v;
        }
    }
    __syncthreads();

    // ---- stage 4: AP = causal(AW · P^T), interleaved cols ----
    {
        const int tB = (tid >> 4) * 4;
        const int sC = tid & 15;
        float ap[4][4] = {};
        for (int j4 = 0; j4 < 32; j4 += 4) {
            float a[4][4], p[4][4];
            #pragma unroll
            for (int r = 0; r < 4; ++r) {
                const float* ar = sAW + (tB + r) * 34 + j4;
                float2 a0 = *(const float2*)(ar);
                float2 a1 = *(const float2*)(ar + 2);
                a[r][0] = a0.x; a[r][1] = a0.y; a[r][2] = a1.x; a[r][3] = a1.y;
                const float* pr = sP + (sC + 16 * r) * 34 + j4;
                float2 p0 = *(const float2*)(pr);
                float2 p1 = *(const float2*)(pr + 2);
                p[r][0] = p0.x; p[r][1] = p0.y; p[r][2] = p1.x; p[r][3] = p1.y;
            }
            #pragma unroll
            for (int i = 0; i < 4; ++i)
                #pragma unroll
                for (int j = 0; j < 4; ++j)
                    ap[i][j] += a[i][0] * p[j][0] + a[i][1] * p[j][1]
                              + a[i][2] * p[j][2] + a[i][3] * p[j][3];
        }
        #pragma unroll
        for (int i = 0; i < 4; ++i)
            #pragma unroll
            for (int j = 0; j < 4; ++j) {
                int col = sC + 16 * j;
                sAP[(tB + i) * 66 + col] = (col <= tB + i) ? ap[i][j] : 0.f;
            }
    }
    __syncthreads();

    // ---- stage 5: OUT = (AW·S^T + AP·KV)/len -> bf16 global ----
    {
        const int tyw = tid >> 4;
        const int tB = tyw * 4;
        const int dB = (tid & 15) * 4;
        float o[4][4] = {};
        for (int j4 = 0; j4 < 32; j4 += 4) {
            float a[4][4], s[4][4];
            #pragma unroll
            for (int r = 0; r < 4; ++r) {
                const float* ar = sAW + (tB + r) * 34 + j4;
                float2 a0 = *(const float2*)(ar);
                float2 a1 = *(const float2*)(ar + 2);
                a[r][0] = a0.x; a[r][1] = a0.y; a[r][2] = a1.x; a[r][3] = a1.y;
                const float* sr = sS + (dB + r) * 34 + j4;
                float2 s0 = *(const float2*)(sr);
                float2 s1 = *(const float2*)(sr + 2);
                s[r][0] = s0.x; s[r][1] = s0.y; s[r][2] = s1.x; s[r][3] = s1.y;
            }
            #pragma unroll
            for (int i = 0; i < 4; ++i)
                #pragma unroll
                for (int j = 0; j < 4; ++j)
                    o[i][j] += a[i][0] * s[j][0] + a[i][1] * s[j][1]
                             + a[i][2] * s[j][2] + a[i][3] * s[j][3];
        }
        for (int cc = 0; cc <= tyw; ++cc) {
            int s4 = cc * 4;
            float a[4][4], k[4][4];
            #pragma unroll
            for (int r = 0; r < 4; ++r) {
                const float* ar = sAP + (tB + r) * 66 + s4;
                float2 a0 = *(const float2*)(ar);
                float2 a1 = *(const float2*)(ar + 2);
                a[r][0] = a0.x; a[r][1] = a0.y; a[r][2] = a1.x; a[r][3] = a1.y;
                uint2 uk = *(const uint2*)(sKVb + (s4 + r) * 68 + dB);
                k[r][0] = bfbits(uk.x << 16);
                k[r][1] = bfbits(uk.x & 0xffff0000u);
                k[r][2] = bfbits(uk.y << 16);
                k[r][3] = bfbits(uk.y & 0xffff0000u);
            }
            #pragma unroll
            for (int i = 0; i < 4; ++i)
                #pragma unroll
                for (int j = 0; j < 4; ++j)
                    o[i][j] += a[i][0] * k[0][j] + a[i][1] * k[1][j]
                             + a[i][2] * k[2][j] + a[i][3] * k[3][j];
        }
        #pragma unroll
        for (int i = 0; i < 4; ++i) {
            int tt = t0 + tB + i;
            float inv = 1.0f / (float)(tt + 1);
            union { ushort4 u; bf16 bb[4]; } st;
            #pragma unroll
            for (int j = 0; j < 4; ++j) st.bb[j] = __float2bfloat16(o[i][j] * inv);
            *(ushort4*)((unsigned short*)attn + ((size_t)(tt * 2 + b)) * 1024 + h * 64 + dB) = st.u;
        }
    }
}

extern "C" void kernel_launch(void* const* d_in, const int* in_sizes, int n_in,
                              void* d_out, int out_size, void* d_ws, size_t ws_size,
                              hipStream_t stream) {
    const float* query  = (const float*)d_in[0];
    const float* pquery = (const float*)d_in[1];
    const float* Wpq = (const float*)d_in[2];
    const float* bpq = (const float*)d_in[3];
    const float* Wq  = (const float*)d_in[4];
    const float* bq  = (const float*)d_in[5];
    const float* Wpc = (const float*)d_in[6];
    const float* bpc = (const float*)d_in[7];
    const float* Wc  = (const float*)d_in[8];
    const float* bc  = (const float*)d_in[9];
    const float* Wo  = (const float*)d_in[10];
    const float* bo  = (const float*)d_in[11];
    float* out = (float*)d_out;

    const int T = 2048, E = 1024, MROWS = 4096;
    const int NCH = 32;

    // workspace layout (floats) — proven round-6 footprint
    float* ws = (float*)d_ws;
    float* pq_buf    = ws;                         // 65536
    float* Cbig      = pq_buf + 65536;             // 4096*3072 (kp|q|kv)
    float* pattn_buf = Cbig + 12582912;            // 2097152
    float* S_buf     = pattn_buf + 2097152;        // 2097152 (first 524288 reused as pq partials)
    float* qbf_f     = S_buf + 2097152;            // bf16 4096x1024 (later attn_bf)
    float* wcat_f    = qbf_f + 2097152;            // bf16 3072x1024 (first third = wpq temp)
    float* wo_f      = wcat_f + 1572864;           // bf16 1024x1024

    bf16* qbf     = (bf16*)qbf_f;
    bf16* wcat    = (bf16*)wcat_f;
    bf16* wpq_bf  = (bf16*)wcat_f;                 // overlay, consumed before wcat written
    bf16* wo_bf   = (bf16*)wo_f;
    bf16* pqy_bf  = (bf16*)pattn_buf;              // overlay, consumed before pattn written
    float* biascat = pattn_buf + 32768;            // consumed by GEMM before pattn written
    float* pq_part = S_buf;                        // consumed before pattn_sum writes S
    bf16* attn_bf = qbf;                           // overlay qbf after fused GEMM

    // 1. conversions batch 1 + pq projection pipeline
    conv1_kernel<<<5184, 256, 0, stream>>>(query, pquery, Wpq, qbf, pqy_bf, wpq_bf);
    gemm_pq_partial<<<dim3(8, 8), 256, 0, stream>>>(pqy_bf, wpq_bf, pq_part);
    pq_reduce<<<256, 256, 0, stream>>>(pq_part, bpq, pq_buf);

    // 2. conversions batch 2 (overwrites wpq overlay)
    conv2_kernel<<<4108, 256, 0, stream>>>(Wpc, Wq, Wc, Wo, bpc, bq, bc, wcat, wo_bf, biascat);

    // 3. fused projection GEMM: Cbig[4096][3072] = kp|q|kv
    gemm_bf16_nt<<<dim3(24, 32), 256, 0, stream>>>(
        qbf, wcat, biascat, Cbig, MROWS, 3072, E, 1.0f, 0.125f);

    // 4. fused pattn + chunk-local sums
    pattn_sum_kernel<<<dim3(NCH, 32), 256, 0, stream>>>(
        Cbig, Cbig + 2048, pq_buf, pattn_buf, S_buf, T, 3072);
    // 5. exclusive prefix over chunks
    prefix_state_kernel<<<256, 256, 0, stream>>>(S_buf);
    // 6. both causal attention stages + softmax
    chunk_attn<<<dim3(NCH, 32), 256, 0, stream>>>(
        Cbig + 1024, Cbig + 2048, pattn_buf, S_buf, attn_bf, T, 3072);
    // 7. output projection
    gemm_bf16_nt<<<dim3(8, 32), 256, 0, stream>>>(
        attn_bf, wo_bf, bo, out, MROWS, E, E, 1.0f, 1.0f);
}

// Round 8
// 228.706 us; speedup vs baseline: 6.6314x; 1.2447x over previous
//
#include <hip/hip_runtime.h>
#include <hip/hip_bf16.h>
#include <math.h>

typedef __hip_bfloat16 bf16;
typedef __attribute__((ext_vector_type(8))) short bf16x8;
typedef __attribute__((ext_vector_type(4))) float f32x4;

__device__ __forceinline__ float bfbits(unsigned int u){ union{unsigned int x; float f;} c; c.x = u; return c.f; }
__device__ __forceinline__ short f2bf_s(float v){ union{ bf16 b; short s;} u; u.b = __float2bfloat16(v); return u.s; }

// async global->LDS 16B (m97 pattern)
__device__ __forceinline__ void gl_lds16(const bf16* g, short* l) {
    __builtin_amdgcn_global_load_lds(
        (const __attribute__((address_space(1))) void*)g,
        (__attribute__((address_space(3))) void*)l, 16, 0, 0);
}

#define LN2F 0.69314718055994531f

__device__ __forceinline__ void cvt_store4(bf16* d, size_t idx, float4 v) {
    union { ushort4 u; bf16 b[4]; } o;
    o.b[0] = __float2bfloat16(v.x);
    o.b[1] = __float2bfloat16(v.y);
    o.b[2] = __float2bfloat16(v.z);
    o.b[3] = __float2bfloat16(v.w);
    ((ushort4*)d)[idx] = o.u;
}

// ---------- conversion batch 1: query, pquery, Wpq ----------
__global__ __launch_bounds__(256)
void conv1_kernel(const float* __restrict__ query, const float* __restrict__ pquery,
                  const float* __restrict__ Wpq, bf16* __restrict__ qbf,
                  bf16* __restrict__ pqy, bf16* __restrict__ wpq)
{
    int blk = blockIdx.x;
    const float* s; bf16* d; int i;
    if (blk < 4096)      { s = query;  d = qbf; i = blk * 256 + threadIdx.x; }
    else if (blk < 4160) { s = pquery; d = pqy; i = (blk - 4096) * 256 + threadIdx.x; }
    else                 { s = Wpq;    d = wpq; i = (blk - 4160) * 256 + threadIdx.x; }
    cvt_store4(d, i, ((const float4*)s)[i]);
}

// ---------- conversion batch 2 ----------
__global__ __launch_bounds__(256)
void conv2_kernel(const float* __restrict__ Wpc, const float* __restrict__ Wq,
                  const float* __restrict__ Wc, const float* __restrict__ Wo,
                  const float* __restrict__ bpc, const float* __restrict__ bq,
                  const float* __restrict__ bc,
                  bf16* __restrict__ wcat, bf16* __restrict__ wo_bf,
                  float* __restrict__ biascat)
{
    int blk = blockIdx.x;
    if (blk < 3072) {
        const float* s = (blk < 1024) ? Wpc : ((blk < 2048) ? Wq : Wc);
        int rel = (blk & 1023) * 256 + threadIdx.x;
        bf16* d = wcat + (size_t)(blk >> 10) * 1048576;
        cvt_store4(d, rel, ((const float4*)s)[rel]);
    } else if (blk < 4096) {
        int rel = (blk - 3072) * 256 + threadIdx.x;
        cvt_store4(wo_bf, rel, ((const float4*)Wo)[rel]);
    } else {
        int i = (blk - 4096) * 256 + threadIdx.x;
        float v = (i < 1024) ? bpc[i] : ((i < 2048) ? bq[i - 1024] : bc[i - 2048]);
        biascat[i] = v;
    }
}

// ---------- bf16 MFMA GEMM (global_load_lds staging) ----------
__global__ __launch_bounds__(256)
void gemm_bf16_nt(const bf16* __restrict__ A, const bf16* __restrict__ B,
                  const float* __restrict__ bias, float* __restrict__ C,
                  int M, int N, int K, float scale_all, float scale_mid)
{
    __shared__ short As[128 * 32];
    __shared__ short Bs[128 * 32];

    const int tid  = threadIdx.x;
    const int lane = tid & 63;
    const int wave = tid >> 6;
    const int m0 = blockIdx.y * 128;
    const int n0 = blockIdx.x * 128;
    const int wm = (wave >> 1) * 64;
    const int wn = (wave & 1) * 64;

    f32x4 acc[4][4] = {};

    const int c0 = tid, c1 = tid + 256;
    const int r0 = c0 >> 2, s0 = c0 & 3;
    const int r1 = c1 >> 2, s1 = c1 & 3;

    const int kb = lane >> 4;
    const int rr = lane & 15;

    for (int k0 = 0; k0 < K; k0 += 32) {
        __syncthreads();
        gl_lds16(A + (size_t)(m0 + r0) * K + k0 + s0 * 8, As + c0 * 8);
        gl_lds16(A + (size_t)(m0 + r1) * K + k0 + s1 * 8, As + c1 * 8);
        gl_lds16(B + (size_t)(n0 + r0) * K + k0 + s0 * 8, Bs + c0 * 8);
        gl_lds16(B + (size_t)(n0 + r1) * K + k0 + s1 * 8, Bs + c1 * 8);
        __syncthreads();

        bf16x8 af[4], bfr[4];
        #pragma unroll
        for (int mi = 0; mi < 4; ++mi)
            af[mi] = *(const bf16x8*)(As + (wm + mi * 16 + rr) * 32 + kb * 8);
        #pragma unroll
        for (int ni = 0; ni < 4; ++ni)
            bfr[ni] = *(const bf16x8*)(Bs + (wn + ni * 16 + rr) * 32 + kb * 8);
        #pragma unroll
        for (int mi = 0; mi < 4; ++mi)
            #pragma unroll
            for (int ni = 0; ni < 4; ++ni)
                acc[mi][ni] = __builtin_amdgcn_mfma_f32_16x16x32_bf16(
                    af[mi], bfr[ni], acc[mi][ni], 0, 0, 0);
    }

    const int col_l = lane & 15;
    const int row_q = lane >> 4;
    #pragma unroll
    for (int ni = 0; ni < 4; ++ni) {
        int col = n0 + wn + ni * 16 + col_l;
        float bb = bias[col];
        float sc = ((col >> 10) == 1) ? scale_mid : scale_all;
        #pragma unroll
        for (int mi = 0; mi < 4; ++mi) {
            #pragma unroll
            for (int r = 0; r < 4; ++r) {
                int row = m0 + wm + mi * 16 + row_q * 4 + r;
                C[(size_t)row * N + col] = sc * (acc[mi][ni][r] + bb);
            }
        }
    }
}

// ---------- pq projection: M=64, K-split MFMA partials ----------
__global__ __launch_bounds__(256)
void gemm_pq_partial(const bf16* __restrict__ A, const bf16* __restrict__ B,
                     float* __restrict__ part)
{
    __shared__ short As[64 * 32];
    __shared__ short Bs[128 * 32];

    const int tid  = threadIdx.x;
    const int lane = tid & 63;
    const int wave = tid >> 6;
    const int n0 = blockIdx.x * 128;
    const int kslice = blockIdx.y;
    const int kbase = kslice * 128;

    f32x4 acc[4][2] = {};

    const int ra = tid >> 2, sa = tid & 3;
    const int c0 = tid, c1 = tid + 256;
    const int rb0 = c0 >> 2, sb0 = c0 & 3;
    const int rb1 = c1 >> 2, sb1 = c1 & 3;

    const int kb = lane >> 4;
    const int rr = lane & 15;

    for (int k0 = kbase; k0 < kbase + 128; k0 += 32) {
        __syncthreads();
        gl_lds16(A + (size_t)ra * 1024 + k0 + sa * 8, As + tid * 8);
        gl_lds16(B + (size_t)(n0 + rb0) * 1024 + k0 + sb0 * 8, Bs + c0 * 8);
        gl_lds16(B + (size_t)(n0 + rb1) * 1024 + k0 + sb1 * 8, Bs + c1 * 8);
        __syncthreads();

        bf16x8 af[4], bfr[2];
        #pragma unroll
        for (int mi = 0; mi < 4; ++mi)
            af[mi] = *(const bf16x8*)(As + (mi * 16 + rr) * 32 + kb * 8);
        #pragma unroll
        for (int ni = 0; ni < 2; ++ni)
            bfr[ni] = *(const bf16x8*)(Bs + (wave * 32 + ni * 16 + rr) * 32 + kb * 8);
        #pragma unroll
        for (int mi = 0; mi < 4; ++mi)
            #pragma unroll
            for (int ni = 0; ni < 2; ++ni)
                acc[mi][ni] = __builtin_amdgcn_mfma_f32_16x16x32_bf16(
                    af[mi], bfr[ni], acc[mi][ni], 0, 0, 0);
    }

    const int col_l = lane & 15;
    const int row_q = lane >> 4;
    float* dst = part + (size_t)kslice * 65536;
    #pragma unroll
    for (int ni = 0; ni < 2; ++ni) {
        int col = n0 + wave * 32 + ni * 16 + col_l;
        #pragma unroll
        for (int mi = 0; mi < 4; ++mi) {
            #pragma unroll
            for (int r = 0; r < 4; ++r) {
                int row = mi * 16 + row_q * 4 + r;
                dst[(size_t)row * 1024 + col] = acc[mi][ni][r];
            }
        }
    }
}

__global__ __launch_bounds__(256)
void pq_reduce(const float* __restrict__ part, const float* __restrict__ bias,
               float* __restrict__ pq)
{
    int gid = blockIdx.x * 256 + threadIdx.x;
    int n = gid & 1023;
    float s = bias[n];
    #pragma unroll
    for (int k = 0; k < 8; ++k) s += part[(size_t)k * 65536 + gid];
    pq[gid] = 0.125f * s;
}

// ---------- fused pattn + chunk-local state sum ----------
__global__ __launch_bounds__(256)
void pattn_sum_kernel(const float* __restrict__ kp, const float* __restrict__ kv,
                      const float* __restrict__ pq, float* __restrict__ pattn,
                      float* __restrict__ Sbuf, int T, int ld)
{
    const int NCH = 32;
    const int c = blockIdx.x, bh = blockIdx.y;
    const int b = bh >> 4, h = bh & 15;
    const int t0 = c * 64;
    const int tid = threadIdx.x;
    __shared__ float pqs[32][65];
    __shared__ float kps[64][65];
    __shared__ float ps[64][33];
    float* kvs = &kps[0][0];

    #pragma unroll
    for (int l = 0; l < 8; ++l) {
        int idx = tid + l * 256;
        int p = idx >> 6, d = idx & 63;
        pqs[p][d] = pq[(size_t)(p * 2 + b) * 1024 + h * 64 + d];
    }
    #pragma unroll
    for (int l = 0; l < 16; ++l) {
        int idx = tid + l * 256;
        int t = idx >> 6, d = idx & 63;
        kps[t][d] = kp[(size_t)((t0 + t) * 2 + b) * ld + h * 64 + d];
    }
    __syncthreads();

    const int p = tid & 31, tb = tid >> 5;
    float spv[8];
    #pragma unroll
    for (int l = 0; l < 8; ++l) {
        int t = tb + l * 8;
        float dot = 0.f;
        for (int d = 0; d < 64; ++d) dot += kps[t][d] * pqs[p][d];
        float z = LN2F * dot;
        spv[l] = (fmaxf(z, 0.f) + log1pf(expf(-fabsf(z)))) / LN2F;
    }
    __syncthreads();

    #pragma unroll
    for (int l = 0; l < 8; ++l) {
        int t = tb + l * 8;
        ps[t][p] = spv[l];
        pattn[((size_t)bh * T + t0 + t) * 32 + p] = spv[l];
    }
    #pragma unroll
    for (int l = 0; l < 16; ++l) {
        int idx = tid + l * 256;
        int t = idx >> 6, d = idx & 63;
        kvs[t * 64 + d] = kv[(size_t)((t0 + t) * 2 + b) * ld + h * 64 + d];
    }
    __syncthreads();

    const int j = tid & 31;
    const int ib = tid >> 5;
    float acc[8] = {};
    for (int r = 0; r < 64; ++r) {
        float pj = ps[r][j];
        #pragma unroll
        for (int k = 0; k < 8; ++k) acc[k] += kvs[r * 64 + ib + 8 * k] * pj;
    }
    float* Sdst = Sbuf + ((size_t)bh * NCH + c) * 2048;
    #pragma unroll
    for (int k = 0; k < 8; ++k) Sdst[tid + k * 256] = acc[k];
}

// In-place exclusive prefix over chunks
__global__ __launch_bounds__(256)
void prefix_state_kernel(float* __restrict__ Sbuf)
{
    const int NCH = 32;
    int gid = blockIdx.x * 256 + threadIdx.x;
    int bh = gid >> 11, e = gid & 2047;
    float* p = Sbuf + (size_t)bh * NCH * 2048 + e;
    float run = 0.f;
    #pragma unroll
    for (int c = 0; c < NCH; ++c) {
        float t = p[c * 2048];
        p[c * 2048] = run;
        run += t;
    }
}

// ---------- MFMA chunk_attn ----------
// LDS arenas (shorts; strides 72/40 are 16B multiples):
//   sQ  [64][72] q bf16 (t,k=d)      sKV [64][72] kv (s,k=d)
//   sKVT[64][72] kv^T (d,k=s)        sW  [64][72] QKmasked then AP (t,k=s)
//   sAW [64][40] attn-weights (t,k=j)
//   sS  [64][40] S (d,k=j)           sST [32][72] S^T (j,k=i)
//   sP  [64][40] P (s,k=j)           sPT [32][72] P^T (j,k=s)
// Total 61440 B.
__global__ __launch_bounds__(256)
void chunk_attn(const float* __restrict__ qg, const float* __restrict__ kvg,
                const float* __restrict__ pg, const float* __restrict__ Sg,
                bf16* __restrict__ attn, int T, int ld)
{
    __shared__ short sm[30720];
    short* sQ   = sm;
    short* sKV  = sm + 4608;
    short* sKVT = sm + 9216;
    short* sW   = sm + 13824;
    short* sAW  = sm + 18432;
    short* sS   = sm + 20992;
    short* sST  = sm + 23552;
    short* sP   = sm + 25856;
    short* sPT  = sm + 28416;

    const int bh = blockIdx.y, c = blockIdx.x;
    const int b = bh >> 4, h = bh & 15;
    const int t0 = c * 64;
    const int tid = threadIdx.x;
    const int lane = tid & 63;
    const int wave = tid >> 6;
    const int rr = lane & 15;
    const int kb = lane >> 4;
    const int m0w = wave * 16;
    const float* Sblk = Sg + ((size_t)bh * 32 + c) * 2048;

    // ---- staging ----
    #pragma unroll
    for (int l = 0; l < 4; ++l) {
        int idx = tid + l * 256;
        int t = idx >> 4, d4 = (idx & 15) * 4;
        size_t g = (size_t)((t0 + t) * 2 + b) * ld + h * 64 + d4;
        float4 qv = *(const float4*)(qg + g);
        union { ushort4 u; short s[4]; bf16 bb[4]; } cq;
        cq.bb[0] = __float2bfloat16(qv.x);
        cq.bb[1] = __float2bfloat16(qv.y);
        cq.bb[2] = __float2bfloat16(qv.z);
        cq.bb[3] = __float2bfloat16(qv.w);
        *(ushort4*)(sQ + t * 72 + d4) = cq.u;
        float4 kvv = *(const float4*)(kvg + g);
        union { ushort4 u; short s[4]; bf16 bb[4]; } ck;
        ck.bb[0] = __float2bfloat16(kvv.x);
        ck.bb[1] = __float2bfloat16(kvv.y);
        ck.bb[2] = __float2bfloat16(kvv.z);
        ck.bb[3] = __float2bfloat16(kvv.w);
        *(ushort4*)(sKV + t * 72 + d4) = ck.u;
        #pragma unroll
        for (int i = 0; i < 4; ++i) sKVT[(d4 + i) * 72 + t] = ck.s[i];
    }
    #pragma unroll
    for (int l = 0; l < 2; ++l) {
        int idx = tid + l * 256;
        int i = idx >> 3, j4 = (idx & 7) * 4;
        float4 sv = *(const float4*)(Sblk + i * 32 + j4);
        union { ushort4 u; short s[4]; bf16 bb[4]; } cs;
        cs.bb[0] = __float2bfloat16(sv.x);
        cs.bb[1] = __float2bfloat16(sv.y);
        cs.bb[2] = __float2bfloat16(sv.z);
        cs.bb[3] = __float2bfloat16(sv.w);
        *(ushort4*)(sS + i * 40 + j4) = cs.u;
        #pragma unroll
        for (int k = 0; k < 4; ++k) sST[(j4 + k) * 72 + i] = cs.s[k];
        float4 pv = *(const float4*)(pg + ((size_t)bh * T + t0 + i) * 32 + j4);
        union { ushort4 u; short s[4]; bf16 bb[4]; } cp;
        cp.bb[0] = __float2bfloat16(pv.x);
        cp.bb[1] = __float2bfloat16(pv.y);
        cp.bb[2] = __float2bfloat16(pv.z);
        cp.bb[3] = __float2bfloat16(pv.w);
        *(ushort4*)(sP + i * 40 + j4) = cp.u;
        #pragma unroll
        for (int k = 0; k < 4; ++k) sPT[(j4 + k) * 72 + i] = cp.s[k];
    }
    __syncthreads();

    // ---- stage 2: QKm = causal(Q · KV^T), bf16 -> sW ----
    {
        bf16x8 aq0 = *(const bf16x8*)(sQ + (m0w + rr) * 72 + kb * 8);
        bf16x8 aq1 = *(const bf16x8*)(sQ + (m0w + rr) * 72 + 32 + kb * 8);
        f32x4 acc[4] = {};
        #pragma unroll
        for (int nt = 0; nt < 4; ++nt) {
            bf16x8 b0 = *(const bf16x8*)(sKV + (nt * 16 + rr) * 72 + kb * 8);
            bf16x8 b1 = *(const bf16x8*)(sKV + (nt * 16 + rr) * 72 + 32 + kb * 8);
            acc[nt] = __builtin_amdgcn_mfma_f32_16x16x32_bf16(aq0, b0, acc[nt], 0, 0, 0);
            acc[nt] = __builtin_amdgcn_mfma_f32_16x16x32_bf16(aq1, b1, acc[nt], 0, 0, 0);
        }
        #pragma unroll
        for (int nt = 0; nt < 4; ++nt)
            #pragma unroll
            for (int r = 0; r < 4; ++r) {
                int t = m0w + kb * 4 + r;
                int s = nt * 16 + rr;
                sW[t * 72 + s] = f2bf_s((s <= t) ? acc[nt][r] : 0.f);
            }
    }
    __syncthreads();

    // ---- stage 3: AW = (Q·S + QKm·P)/len, softmax(32) -> sAW bf16 ----
    {
        bf16x8 aq0 = *(const bf16x8*)(sQ + (m0w + rr) * 72 + kb * 8);
        bf16x8 aq1 = *(const bf16x8*)(sQ + (m0w + rr) * 72 + 32 + kb * 8);
        bf16x8 aw0 = *(const bf16x8*)(sW + (m0w + rr) * 72 + kb * 8);
        bf16x8 aw1 = *(const bf16x8*)(sW + (m0w + rr) * 72 + 32 + kb * 8);
        f32x4 acc[2] = {};
        #pragma unroll
        for (int nt = 0; nt < 2; ++nt) {
            bf16x8 bs0 = *(const bf16x8*)(sST + (nt * 16 + rr) * 72 + kb * 8);
            bf16x8 bs1 = *(const bf16x8*)(sST + (nt * 16 + rr) * 72 + 32 + kb * 8);
            bf16x8 bp0 = *(const bf16x8*)(sPT + (nt * 16 + rr) * 72 + kb * 8);
            bf16x8 bp1 = *(const bf16x8*)(sPT + (nt * 16 + rr) * 72 + 32 + kb * 8);
            acc[nt] = __builtin_amdgcn_mfma_f32_16x16x32_bf16(aq0, bs0, acc[nt], 0, 0, 0);
            acc[nt] = __builtin_amdgcn_mfma_f32_16x16x32_bf16(aq1, bs1, acc[nt], 0, 0, 0);
            acc[nt] = __builtin_amdgcn_mfma_f32_16x16x32_bf16(aw0, bp0, acc[nt], 0, 0, 0);
            acc[nt] = __builtin_amdgcn_mfma_f32_16x16x32_bf16(aw1, bp1, acc[nt], 0, 0, 0);
        }
        #pragma unroll
        for (int r = 0; r < 4; ++r) {
            int t = m0w + kb * 4 + r;
            float inv_len = 1.0f / (float)(t0 + t + 1);
            float v0 = acc[0][r] * inv_len;
            float v1 = acc[1][r] * inv_len;
            float m = fmaxf(v0, v1);
            m = fmaxf(m, __shfl_xor(m, 1));
            m = fmaxf(m, __shfl_xor(m, 2));
            m = fmaxf(m, __shfl_xor(m, 4));
            m = fmaxf(m, __shfl_xor(m, 8));
            float e0 = __expf(v0 - m), e1 = __expf(v1 - m);
            float s = e0 + e1;
            s += __shfl_xor(s, 1);
            s += __shfl_xor(s, 2);
            s += __shfl_xor(s, 4);
            s += __shfl_xor(s, 8);
            float rs = 1.0f / s;
            sAW[t * 40 + rr]      = f2bf_s(e0 * rs);
            sAW[t * 40 + 16 + rr] = f2bf_s(e1 * rs);
        }
    }
    __syncthreads();

    // ---- stage 4: AP = causal(AW · P^T), bf16 -> sW (overwrites QKm) ----
    {
        bf16x8 aa = *(const bf16x8*)(sAW + (m0w + rr) * 40 + kb * 8);
        f32x4 acc[4] = {};
        #pragma unroll
        for (int nt = 0; nt < 4; ++nt) {
            bf16x8 bp = *(const bf16x8*)(sP + (nt * 16 + rr) * 40 + kb * 8);
            acc[nt] = __builtin_amdgcn_mfma_f32_16x16x32_bf16(aa, bp, acc[nt], 0, 0, 0);
        }
        __syncthreads();   // ensure all stage-3 consumers of sW done (they were; barrier above) & stage-5 readers not yet -- protect QKm overwrite ordering across waves
        #pragma unroll
        for (int nt = 0; nt < 4; ++nt)
            #pragma unroll
            for (int r = 0; r < 4; ++r) {
                int t = m0w + kb * 4 + r;
                int s = nt * 16 + rr;
                sW[t * 72 + s] = f2bf_s((s <= t) ? acc[nt][r] : 0.f);
            }
    }
    __syncthreads();

    // ---- stage 5: OUT = (AW·S^T + AP·KV)/len -> bf16 global ----
    {
        bf16x8 aa  = *(const bf16x8*)(sAW + (m0w + rr) * 40 + kb * 8);
        bf16x8 ap0 = *(const bf16x8*)(sW + (m0w + rr) * 72 + kb * 8);
        bf16x8 ap1 = *(const bf16x8*)(sW + (m0w + rr) * 72 + 32 + kb * 8);
        f32x4 acc[4] = {};
        #pragma unroll
        for (int nt = 0; nt < 4; ++nt) {
            bf16x8 bs = *(const bf16x8*)(sS + (nt * 16 + rr) * 40 + kb * 8);
            bf16x8 bk0 = *(const bf16x8*)(sKVT + (nt * 16 + rr) * 72 + kb * 8);
            bf16x8 bk1 = *(const bf16x8*)(sKVT + (nt * 16 + rr) * 72 + 32 + kb * 8);
            acc[nt] = __builtin_amdgcn_mfma_f32_16x16x32_bf16(aa,  bs,  acc[nt], 0, 0, 0);
            acc[nt] = __builtin_amdgcn_mfma_f32_16x16x32_bf16(ap0, bk0, acc[nt], 0, 0, 0);
            acc[nt] = __builtin_amdgcn_mfma_f32_16x16x32_bf16(ap1, bk1, acc[nt], 0, 0, 0);
        }
        #pragma unroll
        for (int nt = 0; nt < 4; ++nt)
            #pragma unroll
            for (int r = 0; r < 4; ++r) {
                int t = m0w + kb * 4 + r;
                int d = nt * 16 + rr;
                float v = acc[nt][r] / (float)(t0 + t + 1);
                ((unsigned short*)attn)[((size_t)((t0 + t) * 2 + b)) * 1024 + h * 64 + d] =
                    (unsigned short)f2bf_s(v);
            }
    }
}

extern "C" void kernel_launch(void* const* d_in, const int* in_sizes, int n_in,
                              void* d_out, int out_size, void* d_ws, size_t ws_size,
                              hipStream_t stream) {
    const float* query  = (const float*)d_in[0];
    const float* pquery = (const float*)d_in[1];
    const float* Wpq = (const float*)d_in[2];
    const float* bpq = (const float*)d_in[3];
    const float* Wq  = (const float*)d_in[4];
    const float* bq  = (const float*)d_in[5];
    const float* Wpc = (const float*)d_in[6];
    const float* bpc = (const float*)d_in[7];
    const float* Wc  = (const float*)d_in[8];
    const float* bc  = (const float*)d_in[9];
    const float* Wo  = (const float*)d_in[10];
    const float* bo  = (const float*)d_in[11];
    float* out = (float*)d_out;

    const int T = 2048, E = 1024, MROWS = 4096;
    const int NCH = 32;

    float* ws = (float*)d_ws;
    float* pq_buf    = ws;
    float* Cbig      = pq_buf + 65536;
    float* pattn_buf = Cbig + 12582912;
    float* S_buf     = pattn_buf + 2097152;
    float* qbf_f     = S_buf + 2097152;
    float* wcat_f    = qbf_f + 2097152;
    float* wo_f      = wcat_f + 1572864;

    bf16* qbf     = (bf16*)qbf_f;
    bf16* wcat    = (bf16*)wcat_f;
    bf16* wpq_bf  = (bf16*)wcat_f;
    bf16* wo_bf   = (bf16*)wo_f;
    bf16* pqy_bf  = (bf16*)pattn_buf;
    float* biascat = pattn_buf + 32768;
    float* pq_part = S_buf;
    bf16* attn_bf = qbf;

    conv1_kernel<<<5184, 256, 0, stream>>>(query, pquery, Wpq, qbf, pqy_bf, wpq_bf);
    gemm_pq_partial<<<dim3(8, 8), 256, 0, stream>>>(pqy_bf, wpq_bf, pq_part);
    pq_reduce<<<256, 256, 0, stream>>>(pq_part, bpq, pq_buf);

    conv2_kernel<<<4108, 256, 0, stream>>>(Wpc, Wq, Wc, Wo, bpc, bq, bc, wcat, wo_bf, biascat);

    gemm_bf16_nt<<<dim3(24, 32), 256, 0, stream>>>(
        qbf, wcat, biascat, Cbig, MROWS, 3072, E, 1.0f, 0.125f);

    pattn_sum_kernel<<<dim3(NCH, 32), 256, 0, stream>>>(
        Cbig, Cbig + 2048, pq_buf, pattn_buf, S_buf, T, 3072);
    prefix_state_kernel<<<256, 256, 0, stream>>>(S_buf);
    chunk_attn<<<dim3(NCH, 32), 256, 0, stream>>>(
        Cbig + 1024, Cbig + 2048, pattn_buf, S_buf, attn_bf, T, 3072);
    gemm_bf16_nt<<<dim3(8, 32), 256, 0, stream>>>(
        attn_bf, wo_bf, bo, out, MROWS, E, E, 1.0f, 1.0f);
}

// Round 9
// 198.775 us; speedup vs baseline: 7.6299x; 1.1506x over previous
//
#include <hip/hip_runtime.h>
#include <hip/hip_bf16.h>
#include <math.h>

typedef __hip_bfloat16 bf16;
typedef __attribute__((ext_vector_type(8))) short bf16x8;
typedef __attribute__((ext_vector_type(4))) float f32x4;

__device__ __forceinline__ short f2bf_s(float v){ union{ bf16 b; short s;} u; u.b = __float2bfloat16(v); return u.s; }

// async global->LDS 16B (m97 pattern)
__device__ __forceinline__ void gl_lds16(const bf16* g, short* l) {
    __builtin_amdgcn_global_load_lds(
        (const __attribute__((address_space(1))) void*)g,
        (__attribute__((address_space(3))) void*)l, 16, 0, 0);
}

#define LN2F 0.69314718055994531f

__device__ __forceinline__ void cvt_store4(bf16* d, size_t idx, float4 v) {
    union { ushort4 u; bf16 b[4]; } o;
    o.b[0] = __float2bfloat16(v.x);
    o.b[1] = __float2bfloat16(v.y);
    o.b[2] = __float2bfloat16(v.z);
    o.b[3] = __float2bfloat16(v.w);
    ((ushort4*)d)[idx] = o.u;
}

__device__ __forceinline__ void st_out(float* p, float v){ *p = v; }
__device__ __forceinline__ void st_out(bf16* p, float v){ *p = __float2bfloat16(v); }

// ---------- conversion batch 1: query, pquery, Wpq ----------
__global__ __launch_bounds__(256)
void conv1_kernel(const float* __restrict__ query, const float* __restrict__ pquery,
                  const float* __restrict__ Wpq, bf16* __restrict__ qbf,
                  bf16* __restrict__ pqy, bf16* __restrict__ wpq)
{
    int blk = blockIdx.x;
    const float* s; bf16* d; int i;
    if (blk < 4096)      { s = query;  d = qbf; i = blk * 256 + threadIdx.x; }
    else if (blk < 4160) { s = pquery; d = pqy; i = (blk - 4096) * 256 + threadIdx.x; }
    else                 { s = Wpq;    d = wpq; i = (blk - 4160) * 256 + threadIdx.x; }
    cvt_store4(d, i, ((const float4*)s)[i]);
}

// ---------- conversion batch 2 ----------
__global__ __launch_bounds__(256)
void conv2_kernel(const float* __restrict__ Wpc, const float* __restrict__ Wq,
                  const float* __restrict__ Wc, const float* __restrict__ Wo,
                  const float* __restrict__ bpc, const float* __restrict__ bq,
                  const float* __restrict__ bc,
                  bf16* __restrict__ wcat, bf16* __restrict__ wo_bf,
                  float* __restrict__ biascat)
{
    int blk = blockIdx.x;
    if (blk < 3072) {
        const float* s = (blk < 1024) ? Wpc : ((blk < 2048) ? Wq : Wc);
        int rel = (blk & 1023) * 256 + threadIdx.x;
        bf16* d = wcat + (size_t)(blk >> 10) * 1048576;
        cvt_store4(d, rel, ((const float4*)s)[rel]);
    } else if (blk < 4096) {
        int rel = (blk - 3072) * 256 + threadIdx.x;
        cvt_store4(wo_bf, rel, ((const float4*)Wo)[rel]);
    } else {
        int i = (blk - 4096) * 256 + threadIdx.x;
        float v = (i < 1024) ? bpc[i] : ((i < 2048) ? bq[i - 1024] : bc[i - 2048]);
        biascat[i] = v;
    }
}

// ---------- bf16 MFMA GEMM (global_load_lds staging), templated output ----------
template<typename TO>
__global__ __launch_bounds__(256)
void gemm_bf16_nt(const bf16* __restrict__ A, const bf16* __restrict__ B,
                  const float* __restrict__ bias, TO* __restrict__ C,
                  int M, int N, int K, float scale_all, float scale_mid)
{
    __shared__ short As[128 * 32];
    __shared__ short Bs[128 * 32];

    const int tid  = threadIdx.x;
    const int lane = tid & 63;
    const int wave = tid >> 6;
    const int m0 = blockIdx.y * 128;
    const int n0 = blockIdx.x * 128;
    const int wm = (wave >> 1) * 64;
    const int wn = (wave & 1) * 64;

    f32x4 acc[4][4] = {};

    const int c0 = tid, c1 = tid + 256;
    const int r0 = c0 >> 2, s0 = c0 & 3;
    const int r1 = c1 >> 2, s1 = c1 & 3;

    const int kb = lane >> 4;
    const int rr = lane & 15;

    for (int k0 = 0; k0 < K; k0 += 32) {
        __syncthreads();
        gl_lds16(A + (size_t)(m0 + r0) * K + k0 + s0 * 8, As + c0 * 8);
        gl_lds16(A + (size_t)(m0 + r1) * K + k0 + s1 * 8, As + c1 * 8);
        gl_lds16(B + (size_t)(n0 + r0) * K + k0 + s0 * 8, Bs + c0 * 8);
        gl_lds16(B + (size_t)(n0 + r1) * K + k0 + s1 * 8, Bs + c1 * 8);
        __syncthreads();

        bf16x8 af[4], bfr[4];
        #pragma unroll
        for (int mi = 0; mi < 4; ++mi)
            af[mi] = *(const bf16x8*)(As + (wm + mi * 16 + rr) * 32 + kb * 8);
        #pragma unroll
        for (int ni = 0; ni < 4; ++ni)
            bfr[ni] = *(const bf16x8*)(Bs + (wn + ni * 16 + rr) * 32 + kb * 8);
        #pragma unroll
        for (int mi = 0; mi < 4; ++mi)
            #pragma unroll
            for (int ni = 0; ni < 4; ++ni)
                acc[mi][ni] = __builtin_amdgcn_mfma_f32_16x16x32_bf16(
                    af[mi], bfr[ni], acc[mi][ni], 0, 0, 0);
    }

    const int col_l = lane & 15;
    const int row_q = lane >> 4;
    #pragma unroll
    for (int ni = 0; ni < 4; ++ni) {
        int col = n0 + wn + ni * 16 + col_l;
        float bb = bias[col];
        float sc = ((col >> 10) == 1) ? scale_mid : scale_all;
        #pragma unroll
        for (int mi = 0; mi < 4; ++mi) {
            #pragma unroll
            for (int r = 0; r < 4; ++r) {
                int row = m0 + wm + mi * 16 + row_q * 4 + r;
                st_out(C + (size_t)row * N + col, sc * (acc[mi][ni][r] + bb));
            }
        }
    }
}

// ---------- pq projection: M=64, K-split MFMA partials ----------
__global__ __launch_bounds__(256)
void gemm_pq_partial(const bf16* __restrict__ A, const bf16* __restrict__ B,
                     float* __restrict__ part)
{
    __shared__ short As[64 * 32];
    __shared__ short Bs[128 * 32];

    const int tid  = threadIdx.x;
    const int lane = tid & 63;
    const int wave = tid >> 6;
    const int n0 = blockIdx.x * 128;
    const int kslice = blockIdx.y;
    const int kbase = kslice * 128;

    f32x4 acc[4][2] = {};

    const int ra = tid >> 2, sa = tid & 3;
    const int c0 = tid, c1 = tid + 256;
    const int rb0 = c0 >> 2, sb0 = c0 & 3;
    const int rb1 = c1 >> 2, sb1 = c1 & 3;

    const int kb = lane >> 4;
    const int rr = lane & 15;

    for (int k0 = kbase; k0 < kbase + 128; k0 += 32) {
        __syncthreads();
        gl_lds16(A + (size_t)ra * 1024 + k0 + sa * 8, As + tid * 8);
        gl_lds16(B + (size_t)(n0 + rb0) * 1024 + k0 + sb0 * 8, Bs + c0 * 8);
        gl_lds16(B + (size_t)(n0 + rb1) * 1024 + k0 + sb1 * 8, Bs + c1 * 8);
        __syncthreads();

        bf16x8 af[4], bfr[2];
        #pragma unroll
        for (int mi = 0; mi < 4; ++mi)
            af[mi] = *(const bf16x8*)(As + (mi * 16 + rr) * 32 + kb * 8);
        #pragma unroll
        for (int ni = 0; ni < 2; ++ni)
            bfr[ni] = *(const bf16x8*)(Bs + (wave * 32 + ni * 16 + rr) * 32 + kb * 8);
        #pragma unroll
        for (int mi = 0; mi < 4; ++mi)
            #pragma unroll
            for (int ni = 0; ni < 2; ++ni)
                acc[mi][ni] = __builtin_amdgcn_mfma_f32_16x16x32_bf16(
                    af[mi], bfr[ni], acc[mi][ni], 0, 0, 0);
    }

    const int col_l = lane & 15;
    const int row_q = lane >> 4;
    float* dst = part + (size_t)kslice * 65536;
    #pragma unroll
    for (int ni = 0; ni < 2; ++ni) {
        int col = n0 + wave * 32 + ni * 16 + col_l;
        #pragma unroll
        for (int mi = 0; mi < 4; ++mi) {
            #pragma unroll
            for (int r = 0; r < 4; ++r) {
                int row = mi * 16 + row_q * 4 + r;
                dst[(size_t)row * 1024 + col] = acc[mi][ni][r];
            }
        }
    }
}

// pq (bf16 out) = 0.125*(sum_s part + bias)
__global__ __launch_bounds__(256)
void pq_reduce(const float* __restrict__ part, const float* __restrict__ bias,
               bf16* __restrict__ pq)
{
    int gid = blockIdx.x * 256 + threadIdx.x;
    int n = gid & 1023;
    float s = bias[n];
    #pragma unroll
    for (int k = 0; k < 8; ++k) s += part[(size_t)k * 65536 + gid];
    pq[gid] = __float2bfloat16(0.125f * s);
}

// ---------- MFMA pattn + chunk-local state sum ----------
// LDS: sKP [64][72] (t,k=d); sKVT [64][72] (d,k=t); sPQ [32][72] (p,k=d); sPT [32][72] (j,k=t)
__global__ __launch_bounds__(256)
void pattn_sum_kernel(const bf16* __restrict__ kp, const bf16* __restrict__ kv,
                      const bf16* __restrict__ pqb, bf16* __restrict__ pattn,
                      float* __restrict__ Sbuf, int T, int ld)
{
    __shared__ short sKP[64 * 72];
    __shared__ short sKVT[64 * 72];
    __shared__ short sPQ[32 * 72];
    __shared__ short sPT[32 * 72];

    const int c = blockIdx.x, bh = blockIdx.y;
    const int b = bh >> 4, h = bh & 15;
    const int t0 = c * 64;
    const int tid = threadIdx.x;
    const int lane = tid & 63, wave = tid >> 6;
    const int rr = lane & 15, kb = lane >> 4;
    const int m0w = wave * 16;

    #pragma unroll
    for (int l = 0; l < 2; ++l) {
        int idx = tid + l * 256;
        int t = idx >> 3, d8 = (idx & 7) * 8;
        size_t g = (size_t)((t0 + t) * 2 + b) * ld + h * 64 + d8;
        uint4 vk = *(const uint4*)(kp + g);
        *(uint4*)(sKP + t * 72 + d8) = vk;
        uint4 vv = *(const uint4*)(kv + g + 2048);
        union { uint4 u; short s[8]; } cw; cw.u = vv;
        #pragma unroll
        for (int i = 0; i < 8; ++i) sKVT[(d8 + i) * 72 + t] = cw.s[i];
    }
    {
        int p = tid >> 3, d8 = (tid & 7) * 8;
        uint4 v = *(const uint4*)(pqb + (size_t)(p * 2 + b) * 1024 + h * 64 + d8);
        *(uint4*)(sPQ + p * 72 + d8) = v;
    }
    __syncthreads();

    // pattn: C[t][p] = softplus(ln2 * kp.pq)/ln2
    {
        bf16x8 a0 = *(const bf16x8*)(sKP + (m0w + rr) * 72 + kb * 8);
        bf16x8 a1 = *(const bf16x8*)(sKP + (m0w + rr) * 72 + 32 + kb * 8);
        f32x4 acc[2] = {};
        #pragma unroll
        for (int nt = 0; nt < 2; ++nt) {
            bf16x8 b0 = *(const bf16x8*)(sPQ + (nt * 16 + rr) * 72 + kb * 8);
            bf16x8 b1 = *(const bf16x8*)(sPQ + (nt * 16 + rr) * 72 + 32 + kb * 8);
            acc[nt] = __builtin_amdgcn_mfma_f32_16x16x32_bf16(a0, b0, acc[nt], 0, 0, 0);
            acc[nt] = __builtin_amdgcn_mfma_f32_16x16x32_bf16(a1, b1, acc[nt], 0, 0, 0);
        }
        #pragma unroll
        for (int nt = 0; nt < 2; ++nt)
            #pragma unroll
            for (int r = 0; r < 4; ++r) {
                int t = m0w + kb * 4 + r;
                int p = nt * 16 + rr;
                float z = LN2F * acc[nt][r];
                float sp = (fmaxf(z, 0.f) + log1pf(__expf(-fabsf(z)))) / LN2F;
                short sb = f2bf_s(sp);
                sPT[p * 72 + t] = sb;
                ((unsigned short*)pattn)[((size_t)bh * T + t0 + t) * 32 + p] = (unsigned short)sb;
            }
    }
    __syncthreads();

    // S[i][j] = sum_t kv[t][i]*p[t][j]
    {
        bf16x8 a0 = *(const bf16x8*)(sKVT + (m0w + rr) * 72 + kb * 8);
        bf16x8 a1 = *(const bf16x8*)(sKVT + (m0w + rr) * 72 + 32 + kb * 8);
        f32x4 acc[2] = {};
        #pragma unroll
        for (int nt = 0; nt < 2; ++nt) {
            bf16x8 b0 = *(const bf16x8*)(sPT + (nt * 16 + rr) * 72 + kb * 8);
            bf16x8 b1 = *(const bf16x8*)(sPT + (nt * 16 + rr) * 72 + 32 + kb * 8);
            acc[nt] = __builtin_amdgcn_mfma_f32_16x16x32_bf16(a0, b0, acc[nt], 0, 0, 0);
            acc[nt] = __builtin_amdgcn_mfma_f32_16x16x32_bf16(a1, b1, acc[nt], 0, 0, 0);
        }
        float* Sdst = Sbuf + ((size_t)bh * 32 + c) * 2048;
        #pragma unroll
        for (int nt = 0; nt < 2; ++nt)
            #pragma unroll
            for (int r = 0; r < 4; ++r) {
                int i = m0w + kb * 4 + r;
                int j = nt * 16 + rr;
                Sdst[i * 32 + j] = acc[nt][r];
            }
    }
}

// In-place exclusive prefix over chunks
__global__ __launch_bounds__(256)
void prefix_state_kernel(float* __restrict__ Sbuf)
{
    const int NCH = 32;
    int gid = blockIdx.x * 256 + threadIdx.x;
    int bh = gid >> 11, e = gid & 2047;
    float* p = Sbuf + (size_t)bh * NCH * 2048 + e;
    float run = 0.f;
    #pragma unroll
    for (int c = 0; c < NCH; ++c) {
        float t = p[c * 2048];
        p[c * 2048] = run;
        run += t;
    }
}

// ---------- MFMA chunk_attn (bf16 inputs) ----------
__global__ __launch_bounds__(256)
void chunk_attn(const bf16* __restrict__ qg, const bf16* __restrict__ kvg,
                const bf16* __restrict__ pg, const float* __restrict__ Sg,
                bf16* __restrict__ attn, int T, int ld)
{
    __shared__ short sm[30720];
    short* sQ   = sm;
    short* sKV  = sm + 4608;
    short* sKVT = sm + 9216;
    short* sW   = sm + 13824;
    short* sAW  = sm + 18432;
    short* sS   = sm + 20992;
    short* sST  = sm + 23552;
    short* sP   = sm + 25856;
    short* sPT  = sm + 28416;

    const int bh = blockIdx.y, c = blockIdx.x;
    const int b = bh >> 4, h = bh & 15;
    const int t0 = c * 64;
    const int tid = threadIdx.x;
    const int lane = tid & 63;
    const int wave = tid >> 6;
    const int rr = lane & 15;
    const int kb = lane >> 4;
    const int m0w = wave * 16;
    const float* Sblk = Sg + ((size_t)bh * 32 + c) * 2048;

    // ---- staging (all-bf16 sources except S) ----
    #pragma unroll
    for (int l = 0; l < 2; ++l) {
        int idx = tid + l * 256;
        int t = idx >> 3, d8 = (idx & 7) * 8;
        size_t g = (size_t)((t0 + t) * 2 + b) * ld + h * 64 + d8;
        uint4 qv = *(const uint4*)(qg + g);
        *(uint4*)(sQ + t * 72 + d8) = qv;
        uint4 kvv = *(const uint4*)(kvg + g);
        *(uint4*)(sKV + t * 72 + d8) = kvv;
        union { uint4 u; short s[8]; } ck; ck.u = kvv;
        #pragma unroll
        for (int i = 0; i < 8; ++i) sKVT[(d8 + i) * 72 + t] = ck.s[i];
    }
    {
        int t = tid >> 2, j8 = (tid & 3) * 8;
        uint4 pv = *(const uint4*)(pg + ((size_t)bh * T + t0 + t) * 32 + j8);
        *(uint4*)(sP + t * 40 + j8) = pv;
        union { uint4 u; short s[8]; } cp; cp.u = pv;
        #pragma unroll
        for (int i = 0; i < 8; ++i) sPT[(j8 + i) * 72 + t] = cp.s[i];

        float4 s0 = *(const float4*)(Sblk + t * 32 + j8);
        float4 s1 = *(const float4*)(Sblk + t * 32 + j8 + 4);
        union { ushort4 u; short s[4]; bf16 bb[4]; } c0, c1;
        c0.bb[0] = __float2bfloat16(s0.x);
        c0.bb[1] = __float2bfloat16(s0.y);
        c0.bb[2] = __float2bfloat16(s0.z);
        c0.bb[3] = __float2bfloat16(s0.w);
        c1.bb[0] = __float2bfloat16(s1.x);
        c1.bb[1] = __float2bfloat16(s1.y);
        c1.bb[2] = __float2bfloat16(s1.z);
        c1.bb[3] = __float2bfloat16(s1.w);
        *(ushort4*)(sS + t * 40 + j8) = c0.u;
        *(ushort4*)(sS + t * 40 + j8 + 4) = c1.u;
        #pragma unroll
        for (int i = 0; i < 4; ++i) sST[(j8 + i) * 72 + t] = c0.s[i];
        #pragma unroll
        for (int i = 0; i < 4; ++i) sST[(j8 + 4 + i) * 72 + t] = c1.s[i];
    }
    __syncthreads();

    // ---- stage 2: QKm = causal(Q · KV^T) -> sW bf16 ----
    {
        bf16x8 aq0 = *(const bf16x8*)(sQ + (m0w + rr) * 72 + kb * 8);
        bf16x8 aq1 = *(const bf16x8*)(sQ + (m0w + rr) * 72 + 32 + kb * 8);
        f32x4 acc[4] = {};
        #pragma unroll
        for (int nt = 0; nt < 4; ++nt) {
            bf16x8 b0 = *(const bf16x8*)(sKV + (nt * 16 + rr) * 72 + kb * 8);
            bf16x8 b1 = *(const bf16x8*)(sKV + (nt * 16 + rr) * 72 + 32 + kb * 8);
            acc[nt] = __builtin_amdgcn_mfma_f32_16x16x32_bf16(aq0, b0, acc[nt], 0, 0, 0);
            acc[nt] = __builtin_amdgcn_mfma_f32_16x16x32_bf16(aq1, b1, acc[nt], 0, 0, 0);
        }
        #pragma unroll
        for (int nt = 0; nt < 4; ++nt)
            #pragma unroll
            for (int r = 0; r < 4; ++r) {
                int t = m0w + kb * 4 + r;
                int s = nt * 16 + rr;
                sW[t * 72 + s] = f2bf_s((s <= t) ? acc[nt][r] : 0.f);
            }
    }
    __syncthreads();

    // ---- stage 3: AW = (Q·S + QKm·P)/len, softmax(32) -> sAW bf16 ----
    {
        bf16x8 aq0 = *(const bf16x8*)(sQ + (m0w + rr) * 72 + kb * 8);
        bf16x8 aq1 = *(const bf16x8*)(sQ + (m0w + rr) * 72 + 32 + kb * 8);
        bf16x8 aw0 = *(const bf16x8*)(sW + (m0w + rr) * 72 + kb * 8);
        bf16x8 aw1 = *(const bf16x8*)(sW + (m0w + rr) * 72 + 32 + kb * 8);
        f32x4 acc[2] = {};
        #pragma unroll
        for (int nt = 0; nt < 2; ++nt) {
            bf16x8 bs0 = *(const bf16x8*)(sST + (nt * 16 + rr) * 72 + kb * 8);
            bf16x8 bs1 = *(const bf16x8*)(sST + (nt * 16 + rr) * 72 + 32 + kb * 8);
            bf16x8 bp0 = *(const bf16x8*)(sPT + (nt * 16 + rr) * 72 + kb * 8);
            bf16x8 bp1 = *(const bf16x8*)(sPT + (nt * 16 + rr) * 72 + 32 + kb * 8);
            acc[nt] = __builtin_amdgcn_mfma_f32_16x16x32_bf16(aq0, bs0, acc[nt], 0, 0, 0);
            acc[nt] = __builtin_amdgcn_mfma_f32_16x16x32_bf16(aq1, bs1, acc[nt], 0, 0, 0);
            acc[nt] = __builtin_amdgcn_mfma_f32_16x16x32_bf16(aw0, bp0, acc[nt], 0, 0, 0);
            acc[nt] = __builtin_amdgcn_mfma_f32_16x16x32_bf16(aw1, bp1, acc[nt], 0, 0, 0);
        }
        #pragma unroll
        for (int r = 0; r < 4; ++r) {
            int t = m0w + kb * 4 + r;
            float inv_len = 1.0f / (float)(t0 + t + 1);
            float v0 = acc[0][r] * inv_len;
            float v1 = acc[1][r] * inv_len;
            float m = fmaxf(v0, v1);
            m = fmaxf(m, __shfl_xor(m, 1));
            m = fmaxf(m, __shfl_xor(m, 2));
            m = fmaxf(m, __shfl_xor(m, 4));
            m = fmaxf(m, __shfl_xor(m, 8));
            float e0 = __expf(v0 - m), e1 = __expf(v1 - m);
            float s = e0 + e1;
            s += __shfl_xor(s, 1);
            s += __shfl_xor(s, 2);
            s += __shfl_xor(s, 4);
            s += __shfl_xor(s, 8);
            float rs = 1.0f / s;
            sAW[t * 40 + rr]      = f2bf_s(e0 * rs);
            sAW[t * 40 + 16 + rr] = f2bf_s(e1 * rs);
        }
    }
    __syncthreads();

    // ---- stage 4: AP = causal(AW · P^T) -> sW (overwrites QKm) ----
    {
        bf16x8 aa = *(const bf16x8*)(sAW + (m0w + rr) * 40 + kb * 8);
        f32x4 acc[4] = {};
        #pragma unroll
        for (int nt = 0; nt < 4; ++nt) {
            bf16x8 bp = *(const bf16x8*)(sP + (nt * 16 + rr) * 40 + kb * 8);
            acc[nt] = __builtin_amdgcn_mfma_f32_16x16x32_bf16(aa, bp, acc[nt], 0, 0, 0);
        }
        __syncthreads();
        #pragma unroll
        for (int nt = 0; nt < 4; ++nt)
            #pragma unroll
            for (int r = 0; r < 4; ++r) {
                int t = m0w + kb * 4 + r;
                int s = nt * 16 + rr;
                sW[t * 72 + s] = f2bf_s((s <= t) ? acc[nt][r] : 0.f);
            }
    }
    __syncthreads();

    // ---- stage 5: OUT = (AW·S^T + AP·KV)/len -> bf16 global ----
    {
        bf16x8 aa  = *(const bf16x8*)(sAW + (m0w + rr) * 40 + kb * 8);
        bf16x8 ap0 = *(const bf16x8*)(sW + (m0w + rr) * 72 + kb * 8);
        bf16x8 ap1 = *(const bf16x8*)(sW + (m0w + rr) * 72 + 32 + kb * 8);
        f32x4 acc[4] = {};
        #pragma unroll
        for (int nt = 0; nt < 4; ++nt) {
            bf16x8 bs = *(const bf16x8*)(sS + (nt * 16 + rr) * 40 + kb * 8);
            bf16x8 bk0 = *(const bf16x8*)(sKVT + (nt * 16 + rr) * 72 + kb * 8);
            bf16x8 bk1 = *(const bf16x8*)(sKVT + (nt * 16 + rr) * 72 + 32 + kb * 8);
            acc[nt] = __builtin_amdgcn_mfma_f32_16x16x32_bf16(aa,  bs,  acc[nt], 0, 0, 0);
            acc[nt] = __builtin_amdgcn_mfma_f32_16x16x32_bf16(ap0, bk0, acc[nt], 0, 0, 0);
            acc[nt] = __builtin_amdgcn_mfma_f32_16x16x32_bf16(ap1, bk1, acc[nt], 0, 0, 0);
        }
        #pragma unroll
        for (int nt = 0; nt < 4; ++nt)
            #pragma unroll
            for (int r = 0; r < 4; ++r) {
                int t = m0w + kb * 4 + r;
                int d = nt * 16 + rr;
                float v = acc[nt][r] / (float)(t0 + t + 1);
                ((unsigned short*)attn)[((size_t)((t0 + t) * 2 + b)) * 1024 + h * 64 + d] =
                    (unsigned short)f2bf_s(v);
            }
    }
}

extern "C" void kernel_launch(void* const* d_in, const int* in_sizes, int n_in,
                              void* d_out, int out_size, void* d_ws, size_t ws_size,
                              hipStream_t stream) {
    const float* query  = (const float*)d_in[0];
    const float* pquery = (const float*)d_in[1];
    const float* Wpq = (const float*)d_in[2];
    const float* bpq = (const float*)d_in[3];
    const float* Wq  = (const float*)d_in[4];
    const float* bq  = (const float*)d_in[5];
    const float* Wpc = (const float*)d_in[6];
    const float* bpc = (const float*)d_in[7];
    const float* Wc  = (const float*)d_in[8];
    const float* bc  = (const float*)d_in[9];
    const float* Wo  = (const float*)d_in[10];
    const float* bo  = (const float*)d_in[11];
    float* out = (float*)d_out;

    const int T = 2048, E = 1024, MROWS = 4096;
    const int NCH = 32;

    // workspace layout (floats)
    float* ws = (float*)d_ws;
    float* pq_f      = ws;                         // 65536 region: pq bf16 (64x1024)
    float* Cbig_f    = pq_f + 65536;               // 6291456: Cbig bf16 (4096x3072)
    float* pattn_f   = Cbig_f + 6291456;           // 1048576: pattn bf16 (2M elems)
    float* S_buf     = pattn_f + 1048576;          // 2097152 fp32
    float* qbf_f     = S_buf + 2097152;            // 2097152: qbf bf16 (4096x1024)
    float* wcat_f    = qbf_f + 2097152;            // 1572864: wcat bf16 (3072x1024)
    float* wo_f      = wcat_f + 1572864;           // 524288: wo bf16

    bf16* pq_bf   = (bf16*)pq_f;
    bf16* Cbig    = (bf16*)Cbig_f;
    bf16* pattn_bf= (bf16*)pattn_f;
    bf16* qbf     = (bf16*)qbf_f;
    bf16* wcat    = (bf16*)wcat_f;
    bf16* wpq_bf  = (bf16*)wcat_f;                 // overlay, consumed before wcat written
    bf16* wo_bf   = (bf16*)wo_f;
    bf16* pqy_bf  = (bf16*)pattn_f;                // overlay, consumed before pattn written
    float* biascat = pattn_f + 32768;              // overlay, consumed by GEMM before pattn written
    float* pq_part = S_buf;                        // overlay, consumed before pattn_sum writes S
    bf16* attn_bf = qbf;                           // overlay qbf after fused GEMM

    conv1_kernel<<<5184, 256, 0, stream>>>(query, pquery, Wpq, qbf, pqy_bf, wpq_bf);
    gemm_pq_partial<<<dim3(8, 8), 256, 0, stream>>>(pqy_bf, wpq_bf, pq_part);
    pq_reduce<<<256, 256, 0, stream>>>(pq_part, bpq, pq_bf);

    conv2_kernel<<<4108, 256, 0, stream>>>(Wpc, Wq, Wc, Wo, bpc, bq, bc, wcat, wo_bf, biascat);

    // fused projection GEMM -> bf16 Cbig (kp|q|kv)
    gemm_bf16_nt<bf16><<<dim3(24, 32), 256, 0, stream>>>(
        qbf, wcat, biascat, Cbig, MROWS, 3072, E, 1.0f, 0.125f);

    // MFMA pattn + chunk sums
    pattn_sum_kernel<<<dim3(NCH, 32), 256, 0, stream>>>(
        Cbig, Cbig, pq_bf, pattn_bf, S_buf, T, 3072);
    prefix_state_kernel<<<256, 256, 0, stream>>>(S_buf);
    chunk_attn<<<dim3(NCH, 32), 256, 0, stream>>>(
        Cbig + 1024, Cbig + 2048, pattn_bf, S_buf, attn_bf, T, 3072);
    // output projection -> fp32 out
    gemm_bf16_nt<float><<<dim3(8, 32), 256, 0, stream>>>(
        attn_bf, wo_bf, bo, out, MROWS, E, E, 1.0f, 1.0f);
}

// Round 10
// 190.920 us; speedup vs baseline: 7.9439x; 1.0411x over previous
//
#include <hip/hip_runtime.h>
#include <hip/hip_bf16.h>
#include <math.h>

typedef __hip_bfloat16 bf16;
typedef __attribute__((ext_vector_type(8))) short bf16x8;
typedef __attribute__((ext_vector_type(4))) float f32x4;

__device__ __forceinline__ short f2bf_s(float v){ union{ bf16 b; short s;} u; u.b = __float2bfloat16(v); return u.s; }

// async global->LDS 16B (m97 pattern)
__device__ __forceinline__ void gl_lds16(const bf16* g, short* l) {
    __builtin_amdgcn_global_load_lds(
        (const __attribute__((address_space(1))) void*)g,
        (__attribute__((address_space(3))) void*)l, 16, 0, 0);
}

#define LN2F 0.69314718055994531f

__device__ __forceinline__ void cvt_store4(bf16* d, size_t idx, float4 v) {
    union { ushort4 u; bf16 b[4]; } o;
    o.b[0] = __float2bfloat16(v.x);
    o.b[1] = __float2bfloat16(v.y);
    o.b[2] = __float2bfloat16(v.z);
    o.b[3] = __float2bfloat16(v.w);
    ((ushort4*)d)[idx] = o.u;
}

__device__ __forceinline__ void st_out(float* p, float v){ *p = v; }
__device__ __forceinline__ void st_out(bf16* p, float v){ *p = __float2bfloat16(v); }

// ---------- single merged conversion kernel ----------
__global__ __launch_bounds__(256)
void conv_all(const float* __restrict__ query, const float* __restrict__ pquery,
              const float* __restrict__ Wpq, const float* __restrict__ Wpc,
              const float* __restrict__ Wq, const float* __restrict__ Wc,
              const float* __restrict__ Wo,
              const float* __restrict__ bpc, const float* __restrict__ bq,
              const float* __restrict__ bc,
              bf16* __restrict__ qbf, bf16* __restrict__ pqy, bf16* __restrict__ wpq,
              bf16* __restrict__ wcat, bf16* __restrict__ wo_bf,
              float* __restrict__ biascat)
{
    int blk = blockIdx.x;
    if (blk < 4096) {
        int i = blk * 256 + threadIdx.x;
        cvt_store4(qbf, i, ((const float4*)query)[i]);
    } else if (blk < 4160) {
        int i = (blk - 4096) * 256 + threadIdx.x;
        cvt_store4(pqy, i, ((const float4*)pquery)[i]);
    } else if (blk < 5184) {
        int i = (blk - 4160) * 256 + threadIdx.x;
        cvt_store4(wpq, i, ((const float4*)Wpq)[i]);
    } else if (blk < 8256) {
        int rel = blk - 5184;
        const float* s = (rel < 1024) ? Wpc : ((rel < 2048) ? Wq : Wc);
        int i = (rel & 1023) * 256 + threadIdx.x;
        cvt_store4(wcat + (size_t)(rel >> 10) * 1048576, i, ((const float4*)s)[i]);
    } else if (blk < 9280) {
        int i = (blk - 8256) * 256 + threadIdx.x;
        cvt_store4(wo_bf, i, ((const float4*)Wo)[i]);
    } else {
        int i = (blk - 9280) * 256 + threadIdx.x;
        if (i < 3072) {
            float v = (i < 1024) ? bpc[i] : ((i < 2048) ? bq[i - 1024] : bc[i - 2048]);
            biascat[i] = v;
        }
    }
}

// ---------- bf16 MFMA GEMM 128x128 (global_load_lds staging), templated output ----------
template<typename TO>
__global__ __launch_bounds__(256)
void gemm_bf16_nt(const bf16* __restrict__ A, const bf16* __restrict__ B,
                  const float* __restrict__ bias, TO* __restrict__ C,
                  int M, int N, int K, float scale_all, float scale_mid)
{
    __shared__ short As[128 * 32];
    __shared__ short Bs[128 * 32];

    const int tid  = threadIdx.x;
    const int lane = tid & 63;
    const int wave = tid >> 6;
    const int m0 = blockIdx.y * 128;
    const int n0 = blockIdx.x * 128;
    const int wm = (wave >> 1) * 64;
    const int wn = (wave & 1) * 64;

    f32x4 acc[4][4] = {};

    const int c0 = tid, c1 = tid + 256;
    const int r0 = c0 >> 2, s0 = c0 & 3;
    const int r1 = c1 >> 2, s1 = c1 & 3;

    const int kb = lane >> 4;
    const int rr = lane & 15;

    for (int k0 = 0; k0 < K; k0 += 32) {
        __syncthreads();
        gl_lds16(A + (size_t)(m0 + r0) * K + k0 + s0 * 8, As + c0 * 8);
        gl_lds16(A + (size_t)(m0 + r1) * K + k0 + s1 * 8, As + c1 * 8);
        gl_lds16(B + (size_t)(n0 + r0) * K + k0 + s0 * 8, Bs + c0 * 8);
        gl_lds16(B + (size_t)(n0 + r1) * K + k0 + s1 * 8, Bs + c1 * 8);
        __syncthreads();

        bf16x8 af[4], bfr[4];
        #pragma unroll
        for (int mi = 0; mi < 4; ++mi)
            af[mi] = *(const bf16x8*)(As + (wm + mi * 16 + rr) * 32 + kb * 8);
        #pragma unroll
        for (int ni = 0; ni < 4; ++ni)
            bfr[ni] = *(const bf16x8*)(Bs + (wn + ni * 16 + rr) * 32 + kb * 8);
        #pragma unroll
        for (int mi = 0; mi < 4; ++mi)
            #pragma unroll
            for (int ni = 0; ni < 4; ++ni)
                acc[mi][ni] = __builtin_amdgcn_mfma_f32_16x16x32_bf16(
                    af[mi], bfr[ni], acc[mi][ni], 0, 0, 0);
    }

    const int col_l = lane & 15;
    const int row_q = lane >> 4;
    #pragma unroll
    for (int ni = 0; ni < 4; ++ni) {
        int col = n0 + wn + ni * 16 + col_l;
        float bb = bias[col];
        float sc = ((col >> 10) == 1) ? scale_mid : scale_all;
        #pragma unroll
        for (int mi = 0; mi < 4; ++mi) {
            #pragma unroll
            for (int r = 0; r < 4; ++r) {
                int row = m0 + wm + mi * 16 + row_q * 4 + r;
                st_out(C + (size_t)row * N + col, sc * (acc[mi][ni][r] + bb));
            }
        }
    }
}

// ---------- bf16 MFMA GEMM 64x128 tile (2x occupancy for small-grid GEMMs) ----------
__global__ __launch_bounds__(256)
void gemm_bf16_nt64(const bf16* __restrict__ A, const bf16* __restrict__ B,
                    const float* __restrict__ bias, float* __restrict__ C,
                    int M, int N, int K)
{
    __shared__ short As[64 * 32];
    __shared__ short Bs[128 * 32];

    const int tid  = threadIdx.x;
    const int lane = tid & 63;
    const int wave = tid >> 6;
    const int m0 = blockIdx.y * 64;
    const int n0 = blockIdx.x * 128;
    const int wm = (wave >> 1) * 32;
    const int wn = (wave & 1) * 64;

    f32x4 acc[2][4] = {};

    const int ra = tid >> 2, sa = tid & 3;         // A: 256 chunks, 1/thread
    const int c0 = tid, c1 = tid + 256;            // B: 512 chunks, 2/thread
    const int rb0 = c0 >> 2, sb0 = c0 & 3;
    const int rb1 = c1 >> 2, sb1 = c1 & 3;

    const int kb = lane >> 4;
    const int rr = lane & 15;

    for (int k0 = 0; k0 < K; k0 += 32) {
        __syncthreads();
        gl_lds16(A + (size_t)(m0 + ra) * K + k0 + sa * 8, As + tid * 8);
        gl_lds16(B + (size_t)(n0 + rb0) * K + k0 + sb0 * 8, Bs + c0 * 8);
        gl_lds16(B + (size_t)(n0 + rb1) * K + k0 + sb1 * 8, Bs + c1 * 8);
        __syncthreads();

        bf16x8 af[2], bfr[4];
        #pragma unroll
        for (int mi = 0; mi < 2; ++mi)
            af[mi] = *(const bf16x8*)(As + (wm + mi * 16 + rr) * 32 + kb * 8);
        #pragma unroll
        for (int ni = 0; ni < 4; ++ni)
            bfr[ni] = *(const bf16x8*)(Bs + (wn + ni * 16 + rr) * 32 + kb * 8);
        #pragma unroll
        for (int mi = 0; mi < 2; ++mi)
            #pragma unroll
            for (int ni = 0; ni < 4; ++ni)
                acc[mi][ni] = __builtin_amdgcn_mfma_f32_16x16x32_bf16(
                    af[mi], bfr[ni], acc[mi][ni], 0, 0, 0);
    }

    const int col_l = lane & 15;
    const int row_q = lane >> 4;
    #pragma unroll
    for (int ni = 0; ni < 4; ++ni) {
        int col = n0 + wn + ni * 16 + col_l;
        float bb = bias[col];
        #pragma unroll
        for (int mi = 0; mi < 2; ++mi) {
            #pragma unroll
            for (int r = 0; r < 4; ++r) {
                int row = m0 + wm + mi * 16 + row_q * 4 + r;
                C[(size_t)row * N + col] = acc[mi][ni][r] + bb;
            }
        }
    }
}

// ---------- pq projection: M=64, K-split MFMA partials ----------
__global__ __launch_bounds__(256)
void gemm_pq_partial(const bf16* __restrict__ A, const bf16* __restrict__ B,
                     float* __restrict__ part)
{
    __shared__ short As[64 * 32];
    __shared__ short Bs[128 * 32];

    const int tid  = threadIdx.x;
    const int lane = tid & 63;
    const int wave = tid >> 6;
    const int n0 = blockIdx.x * 128;
    const int kslice = blockIdx.y;
    const int kbase = kslice * 128;

    f32x4 acc[4][2] = {};

    const int ra = tid >> 2, sa = tid & 3;
    const int c0 = tid, c1 = tid + 256;
    const int rb0 = c0 >> 2, sb0 = c0 & 3;
    const int rb1 = c1 >> 2, sb1 = c1 & 3;

    const int kb = lane >> 4;
    const int rr = lane & 15;

    for (int k0 = kbase; k0 < kbase + 128; k0 += 32) {
        __syncthreads();
        gl_lds16(A + (size_t)ra * 1024 + k0 + sa * 8, As + tid * 8);
        gl_lds16(B + (size_t)(n0 + rb0) * 1024 + k0 + sb0 * 8, Bs + c0 * 8);
        gl_lds16(B + (size_t)(n0 + rb1) * 1024 + k0 + sb1 * 8, Bs + c1 * 8);
        __syncthreads();

        bf16x8 af[4], bfr[2];
        #pragma unroll
        for (int mi = 0; mi < 4; ++mi)
            af[mi] = *(const bf16x8*)(As + (mi * 16 + rr) * 32 + kb * 8);
        #pragma unroll
        for (int ni = 0; ni < 2; ++ni)
            bfr[ni] = *(const bf16x8*)(Bs + (wave * 32 + ni * 16 + rr) * 32 + kb * 8);
        #pragma unroll
        for (int mi = 0; mi < 4; ++mi)
            #pragma unroll
            for (int ni = 0; ni < 2; ++ni)
                acc[mi][ni] = __builtin_amdgcn_mfma_f32_16x16x32_bf16(
                    af[mi], bfr[ni], acc[mi][ni], 0, 0, 0);
    }

    const int col_l = lane & 15;
    const int row_q = lane >> 4;
    float* dst = part + (size_t)kslice * 65536;
    #pragma unroll
    for (int ni = 0; ni < 2; ++ni) {
        int col = n0 + wave * 32 + ni * 16 + col_l;
        #pragma unroll
        for (int mi = 0; mi < 4; ++mi) {
            #pragma unroll
            for (int r = 0; r < 4; ++r) {
                int row = mi * 16 + row_q * 4 + r;
                dst[(size_t)row * 1024 + col] = acc[mi][ni][r];
            }
        }
    }
}

// pq (bf16 out) = 0.125*(sum_s part + bias)
__global__ __launch_bounds__(256)
void pq_reduce(const float* __restrict__ part, const float* __restrict__ bias,
               bf16* __restrict__ pq)
{
    int gid = blockIdx.x * 256 + threadIdx.x;
    int n = gid & 1023;
    float s = bias[n];
    #pragma unroll
    for (int k = 0; k < 8; ++k) s += part[(size_t)k * 65536 + gid];
    pq[gid] = __float2bfloat16(0.125f * s);
}

// ---------- MFMA pattn + chunk-local state sum ----------
__global__ __launch_bounds__(256)
void pattn_sum_kernel(const bf16* __restrict__ kp, const bf16* __restrict__ kv,
                      const bf16* __restrict__ pqb, bf16* __restrict__ pattn,
                      float* __restrict__ Sbuf, int T, int ld)
{
    __shared__ short sKP[64 * 72];
    __shared__ short sKVT[64 * 72];
    __shared__ short sPQ[32 * 72];
    __shared__ short sPT[32 * 72];

    const int c = blockIdx.x, bh = blockIdx.y;
    const int b = bh >> 4, h = bh & 15;
    const int t0 = c * 64;
    const int tid = threadIdx.x;
    const int lane = tid & 63, wave = tid >> 6;
    const int rr = lane & 15, kb = lane >> 4;
    const int m0w = wave * 16;

    #pragma unroll
    for (int l = 0; l < 2; ++l) {
        int idx = tid + l * 256;
        int t = idx >> 3, d8 = (idx & 7) * 8;
        size_t g = (size_t)((t0 + t) * 2 + b) * ld + h * 64 + d8;
        uint4 vk = *(const uint4*)(kp + g);
        *(uint4*)(sKP + t * 72 + d8) = vk;
        uint4 vv = *(const uint4*)(kv + g + 2048);
        union { uint4 u; short s[8]; } cw; cw.u = vv;
        #pragma unroll
        for (int i = 0; i < 8; ++i) sKVT[(d8 + i) * 72 + t] = cw.s[i];
    }
    {
        int p = tid >> 3, d8 = (tid & 7) * 8;
        uint4 v = *(const uint4*)(pqb + (size_t)(p * 2 + b) * 1024 + h * 64 + d8);
        *(uint4*)(sPQ + p * 72 + d8) = v;
    }
    __syncthreads();

    // pattn: C[t][p] = softplus(ln2 * kp.pq)/ln2
    {
        bf16x8 a0 = *(const bf16x8*)(sKP + (m0w + rr) * 72 + kb * 8);
        bf16x8 a1 = *(const bf16x8*)(sKP + (m0w + rr) * 72 + 32 + kb * 8);
        f32x4 acc[2] = {};
        #pragma unroll
        for (int nt = 0; nt < 2; ++nt) {
            bf16x8 b0 = *(const bf16x8*)(sPQ + (nt * 16 + rr) * 72 + kb * 8);
            bf16x8 b1 = *(const bf16x8*)(sPQ + (nt * 16 + rr) * 72 + 32 + kb * 8);
            acc[nt] = __builtin_amdgcn_mfma_f32_16x16x32_bf16(a0, b0, acc[nt], 0, 0, 0);
            acc[nt] = __builtin_amdgcn_mfma_f32_16x16x32_bf16(a1, b1, acc[nt], 0, 0, 0);
        }
        #pragma unroll
        for (int nt = 0; nt < 2; ++nt)
            #pragma unroll
            for (int r = 0; r < 4; ++r) {
                int t = m0w + kb * 4 + r;
                int p = nt * 16 + rr;
                float z = LN2F * acc[nt][r];
                float sp = (fmaxf(z, 0.f) + log1pf(__expf(-fabsf(z)))) / LN2F;
                short sb = f2bf_s(sp);
                sPT[p * 72 + t] = sb;
                ((unsigned short*)pattn)[((size_t)bh * T + t0 + t) * 32 + p] = (unsigned short)sb;
            }
    }
    __syncthreads();

    // S[i][j] = sum_t kv[t][i]*p[t][j]
    {
        bf16x8 a0 = *(const bf16x8*)(sKVT + (m0w + rr) * 72 + kb * 8);
        bf16x8 a1 = *(const bf16x8*)(sKVT + (m0w + rr) * 72 + 32 + kb * 8);
        f32x4 acc[2] = {};
        #pragma unroll
        for (int nt = 0; nt < 2; ++nt) {
            bf16x8 b0 = *(const bf16x8*)(sPT + (nt * 16 + rr) * 72 + kb * 8);
            bf16x8 b1 = *(const bf16x8*)(sPT + (nt * 16 + rr) * 72 + 32 + kb * 8);
            acc[nt] = __builtin_amdgcn_mfma_f32_16x16x32_bf16(a0, b0, acc[nt], 0, 0, 0);
            acc[nt] = __builtin_amdgcn_mfma_f32_16x16x32_bf16(a1, b1, acc[nt], 0, 0, 0);
        }
        float* Sdst = Sbuf + ((size_t)bh * 32 + c) * 2048;
        #pragma unroll
        for (int nt = 0; nt < 2; ++nt)
            #pragma unroll
            for (int r = 0; r < 4; ++r) {
                int i = m0w + kb * 4 + r;
                int j = nt * 16 + rr;
                Sdst[i * 32 + j] = acc[nt][r];
            }
    }
}

// In-place exclusive prefix over chunks
__global__ __launch_bounds__(256)
void prefix_state_kernel(float* __restrict__ Sbuf)
{
    const int NCH = 32;
    int gid = blockIdx.x * 256 + threadIdx.x;
    int bh = gid >> 11, e = gid & 2047;
    float* p = Sbuf + (size_t)bh * NCH * 2048 + e;
    float run = 0.f;
    #pragma unroll
    for (int c = 0; c < NCH; ++c) {
        float t = p[c * 2048];
        p[c * 2048] = run;
        run += t;
    }
}

// ---------- MFMA chunk_attn (bf16 inputs), 52224 B LDS -> 3 blocks/CU ----------
// Arenas (shorts): sQ@0 [64][72] (becomes sKVT after stage 3); sKV@4608 [64][72];
// sW@9216 [64][72]; sAW@13824 [64][40]; sS@16384 [64][40]; sST@18944 [32][72];
// sP@21248 [64][40]; sPT@23808 [32][72]. Total 26112 shorts.
__global__ __launch_bounds__(256)
void chunk_attn(const bf16* __restrict__ qg, const bf16* __restrict__ kvg,
                const bf16* __restrict__ pg, const float* __restrict__ Sg,
                bf16* __restrict__ attn, int T, int ld)
{
    __shared__ short sm[26112];
    short* sQ   = sm;          // overlaid by sKVT after stage 3
    short* sKV  = sm + 4608;
    short* sW   = sm + 9216;
    short* sAW  = sm + 13824;
    short* sS   = sm + 16384;
    short* sST  = sm + 18944;
    short* sP   = sm + 21248;
    short* sPT  = sm + 23808;

    const int bh = blockIdx.y, c = blockIdx.x;
    const int b = bh >> 4, h = bh & 15;
    const int t0 = c * 64;
    const int tid = threadIdx.x;
    const int lane = tid & 63;
    const int wave = tid >> 6;
    const int rr = lane & 15;
    const int kb = lane >> 4;
    const int m0w = wave * 16;
    const float* Sblk = Sg + ((size_t)bh * 32 + c) * 2048;

    // ---- staging ----
    #pragma unroll
    for (int l = 0; l < 2; ++l) {
        int idx = tid + l * 256;
        int t = idx >> 3, d8 = (idx & 7) * 8;
        size_t g = (size_t)((t0 + t) * 2 + b) * ld + h * 64 + d8;
        uint4 qv = *(const uint4*)(qg + g);
        *(uint4*)(sQ + t * 72 + d8) = qv;
        uint4 kvv = *(const uint4*)(kvg + g);
        *(uint4*)(sKV + t * 72 + d8) = kvv;
    }
    {
        int t = tid >> 2, j8 = (tid & 3) * 8;
        uint4 pv = *(const uint4*)(pg + ((size_t)bh * T + t0 + t) * 32 + j8);
        *(uint4*)(sP + t * 40 + j8) = pv;
        union { uint4 u; short s[8]; } cp; cp.u = pv;
        #pragma unroll
        for (int i = 0; i < 8; ++i) sPT[(j8 + i) * 72 + t] = cp.s[i];

        float4 s0 = *(const float4*)(Sblk + t * 32 + j8);
        float4 s1 = *(const float4*)(Sblk + t * 32 + j8 + 4);
        union { ushort4 u; short s[4]; bf16 bb[4]; } c0, c1;
        c0.bb[0] = __float2bfloat16(s0.x);
        c0.bb[1] = __float2bfloat16(s0.y);
        c0.bb[2] = __float2bfloat16(s0.z);
        c0.bb[3] = __float2bfloat16(s0.w);
        c1.bb[0] = __float2bfloat16(s1.x);
        c1.bb[1] = __float2bfloat16(s1.y);
        c1.bb[2] = __float2bfloat16(s1.z);
        c1.bb[3] = __float2bfloat16(s1.w);
        *(ushort4*)(sS + t * 40 + j8) = c0.u;
        *(ushort4*)(sS + t * 40 + j8 + 4) = c1.u;
        #pragma unroll
        for (int i = 0; i < 4; ++i) sST[(j8 + i) * 72 + t] = c0.s[i];
        #pragma unroll
        for (int i = 0; i < 4; ++i) sST[(j8 + 4 + i) * 72 + t] = c1.s[i];
    }
    __syncthreads();

    // ---- stage 2: QKm = causal(Q · KV^T) -> sW bf16 ----
    {
        bf16x8 aq0 = *(const bf16x8*)(sQ + (m0w + rr) * 72 + kb * 8);
        bf16x8 aq1 = *(const bf16x8*)(sQ + (m0w + rr) * 72 + 32 + kb * 8);
        f32x4 acc[4] = {};
        #pragma unroll
        for (int nt = 0; nt < 4; ++nt) {
            bf16x8 b0 = *(const bf16x8*)(sKV + (nt * 16 + rr) * 72 + kb * 8);
            bf16x8 b1 = *(const bf16x8*)(sKV + (nt * 16 + rr) * 72 + 32 + kb * 8);
            acc[nt] = __builtin_amdgcn_mfma_f32_16x16x32_bf16(aq0, b0, acc[nt], 0, 0, 0);
            acc[nt] = __builtin_amdgcn_mfma_f32_16x16x32_bf16(aq1, b1, acc[nt], 0, 0, 0);
        }
        #pragma unroll
        for (int nt = 0; nt < 4; ++nt)
            #pragma unroll
            for (int r = 0; r < 4; ++r) {
                int t = m0w + kb * 4 + r;
                int s = nt * 16 + rr;
                sW[t * 72 + s] = f2bf_s((s <= t) ? acc[nt][r] : 0.f);
            }
    }
    __syncthreads();

    // ---- stage 3: AW = (Q·S + QKm·P)/len, softmax(32) -> sAW bf16 ----
    {
        bf16x8 aq0 = *(const bf16x8*)(sQ + (m0w + rr) * 72 + kb * 8);
        bf16x8 aq1 = *(const bf16x8*)(sQ + (m0w + rr) * 72 + 32 + kb * 8);
        bf16x8 aw0 = *(const bf16x8*)(sW + (m0w + rr) * 72 + kb * 8);
        bf16x8 aw1 = *(const bf16x8*)(sW + (m0w + rr) * 72 + 32 + kb * 8);
        f32x4 acc[2] = {};
        #pragma unroll
        for (int nt = 0; nt < 2; ++nt) {
            bf16x8 bs0 = *(const bf16x8*)(sST + (nt * 16 + rr) * 72 + kb * 8);
            bf16x8 bs1 = *(const bf16x8*)(sST + (nt * 16 + rr) * 72 + 32 + kb * 8);
            bf16x8 bp0 = *(const bf16x8*)(sPT + (nt * 16 + rr) * 72 + kb * 8);
            bf16x8 bp1 = *(const bf16x8*)(sPT + (nt * 16 + rr) * 72 + 32 + kb * 8);
            acc[nt] = __builtin_amdgcn_mfma_f32_16x16x32_bf16(aq0, bs0, acc[nt], 0, 0, 0);
            acc[nt] = __builtin_amdgcn_mfma_f32_16x16x32_bf16(aq1, bs1, acc[nt], 0, 0, 0);
            acc[nt] = __builtin_amdgcn_mfma_f32_16x16x32_bf16(aw0, bp0, acc[nt], 0, 0, 0);
            acc[nt] = __builtin_amdgcn_mfma_f32_16x16x32_bf16(aw1, bp1, acc[nt], 0, 0, 0);
        }
        #pragma unroll
        for (int r = 0; r < 4; ++r) {
            int t = m0w + kb * 4 + r;
            float inv_len = 1.0f / (float)(t0 + t + 1);
            float v0 = acc[0][r] * inv_len;
            float v1 = acc[1][r] * inv_len;
            float m = fmaxf(v0, v1);
            m = fmaxf(m, __shfl_xor(m, 1));
            m = fmaxf(m, __shfl_xor(m, 2));
            m = fmaxf(m, __shfl_xor(m, 4));
            m = fmaxf(m, __shfl_xor(m, 8));
            float e0 = __expf(v0 - m), e1 = __expf(v1 - m);
            float s = e0 + e1;
            s += __shfl_xor(s, 1);
            s += __shfl_xor(s, 2);
            s += __shfl_xor(s, 4);
            s += __shfl_xor(s, 8);
            float rs = 1.0f / s;
            sAW[t * 40 + rr]      = f2bf_s(e0 * rs);
            sAW[t * 40 + 16 + rr] = f2bf_s(e1 * rs);
        }
    }
    __syncthreads();   // sQ now dead; sAW visible

    // ---- stage 4: transpose KV into dead sQ arena + AP = causal(AW · P^T) ----
    short* sKVT = sQ;
    {
        #pragma unroll
        for (int l = 0; l < 2; ++l) {
            int idx = tid + l * 256;
            int t = idx >> 3, d8 = (idx & 7) * 8;
            union { uint4 u; short s[8]; } ck;
            ck.u = *(const uint4*)(sKV + t * 72 + d8);
            #pragma unroll
            for (int i = 0; i < 8; ++i) sKVT[(d8 + i) * 72 + t] = ck.s[i];
        }
        bf16x8 aa = *(const bf16x8*)(sAW + (m0w + rr) * 40 + kb * 8);
        f32x4 acc[4] = {};
        #pragma unroll
        for (int nt = 0; nt < 4; ++nt) {
            bf16x8 bp = *(const bf16x8*)(sP + (nt * 16 + rr) * 40 + kb * 8);
            acc[nt] = __builtin_amdgcn_mfma_f32_16x16x32_bf16(aa, bp, acc[nt], 0, 0, 0);
        }
        __syncthreads();
        #pragma unroll
        for (int nt = 0; nt < 4; ++nt)
            #pragma unroll
            for (int r = 0; r < 4; ++r) {
                int t = m0w + kb * 4 + r;
                int s = nt * 16 + rr;
                sW[t * 72 + s] = f2bf_s((s <= t) ? acc[nt][r] : 0.f);
            }
    }
    __syncthreads();

    // ---- stage 5: OUT = (AW·S^T + AP·KV)/len -> bf16 global ----
    {
        bf16x8 aa  = *(const bf16x8*)(sAW + (m0w + rr) * 40 + kb * 8);
        bf16x8 ap0 = *(const bf16x8*)(sW + (m0w + rr) * 72 + kb * 8);
        bf16x8 ap1 = *(const bf16x8*)(sW + (m0w + rr) * 72 + 32 + kb * 8);
        f32x4 acc[4] = {};
        #pragma unroll
        for (int nt = 0; nt < 4; ++nt) {
            bf16x8 bs = *(const bf16x8*)(sS + (nt * 16 + rr) * 40 + kb * 8);
            bf16x8 bk0 = *(const bf16x8*)(sKVT + (nt * 16 + rr) * 72 + kb * 8);
            bf16x8 bk1 = *(const bf16x8*)(sKVT + (nt * 16 + rr) * 72 + 32 + kb * 8);
            acc[nt] = __builtin_amdgcn_mfma_f32_16x16x32_bf16(aa,  bs,  acc[nt], 0, 0, 0);
            acc[nt] = __builtin_amdgcn_mfma_f32_16x16x32_bf16(ap0, bk0, acc[nt], 0, 0, 0);
            acc[nt] = __builtin_amdgcn_mfma_f32_16x16x32_bf16(ap1, bk1, acc[nt], 0, 0, 0);
        }
        #pragma unroll
        for (int nt = 0; nt < 4; ++nt)
            #pragma unroll
            for (int r = 0; r < 4; ++r) {
                int t = m0w + kb * 4 + r;
                int d = nt * 16 + rr;
                float v = acc[nt][r] / (float)(t0 + t + 1);
                ((unsigned short*)attn)[((size_t)((t0 + t) * 2 + b)) * 1024 + h * 64 + d] =
                    (unsigned short)f2bf_s(v);
            }
    }
}

extern "C" void kernel_launch(void* const* d_in, const int* in_sizes, int n_in,
                              void* d_out, int out_size, void* d_ws, size_t ws_size,
                              hipStream_t stream) {
    const float* query  = (const float*)d_in[0];
    const float* pquery = (const float*)d_in[1];
    const float* Wpq = (const float*)d_in[2];
    const float* bpq = (const float*)d_in[3];
    const float* Wq  = (const float*)d_in[4];
    const float* bq  = (const float*)d_in[5];
    const float* Wpc = (const float*)d_in[6];
    const float* bpc = (const float*)d_in[7];
    const float* Wc  = (const float*)d_in[8];
    const float* bc  = (const float*)d_in[9];
    const float* Wo  = (const float*)d_in[10];
    const float* bo  = (const float*)d_in[11];
    float* out = (float*)d_out;

    const int T = 2048, E = 1024, MROWS = 4096;
    const int NCH = 32;

    // workspace layout (floats)
    float* ws = (float*)d_ws;
    float* pq_f      = ws;                         // pq bf16 (64x1024)
    float* Cbig_f    = pq_f + 65536;               // Cbig bf16 (4096x3072)
    float* pattn_f   = Cbig_f + 6291456;           // pattn bf16
    float* S_buf     = pattn_f + 1048576;          // fp32 states
    float* qbf_f     = S_buf + 2097152;            // qbf bf16 (4096x1024)
    float* wcat_f    = qbf_f + 2097152;            // wcat bf16 (3072x1024)
    float* wo_f      = wcat_f + 1572864;           // wo bf16
    float* wpq_f     = wo_f + 524288;              // wpq bf16 (own region now)

    bf16* pq_bf   = (bf16*)pq_f;
    bf16* Cbig    = (bf16*)Cbig_f;
    bf16* pattn_bf= (bf16*)pattn_f;
    bf16* qbf     = (bf16*)qbf_f;
    bf16* wcat    = (bf16*)wcat_f;
    bf16* wo_bf   = (bf16*)wo_f;
    bf16* wpq_bf  = (bf16*)wpq_f;
    bf16* pqy_bf  = (bf16*)pattn_f;                // overlay, consumed before pattn written
    float* biascat = pattn_f + 32768;              // overlay, consumed by GEMM before pattn written
    float* pq_part = S_buf;                        // overlay, consumed before pattn_sum writes S
    bf16* attn_bf = qbf;                           // overlay qbf after fused GEMM

    // 1. all conversions in one kernel
    conv_all<<<9292, 256, 0, stream>>>(query, pquery, Wpq, Wpc, Wq, Wc, Wo,
                                       bpc, bq, bc, qbf, pqy_bf, wpq_bf,
                                       wcat, wo_bf, biascat);
    // 2. pq projection (K-split MFMA + reduce)
    gemm_pq_partial<<<dim3(8, 8), 256, 0, stream>>>(pqy_bf, wpq_bf, pq_part);
    pq_reduce<<<256, 256, 0, stream>>>(pq_part, bpq, pq_bf);

    // 3. fused projection GEMM -> bf16 Cbig (kp|q|kv)
    gemm_bf16_nt<bf16><<<dim3(24, 32), 256, 0, stream>>>(
        qbf, wcat, biascat, Cbig, MROWS, 3072, E, 1.0f, 0.125f);

    // 4. MFMA pattn + chunk sums
    pattn_sum_kernel<<<dim3(NCH, 32), 256, 0, stream>>>(
        Cbig, Cbig, pq_bf, pattn_bf, S_buf, T, 3072);
    // 5. exclusive prefix
    prefix_state_kernel<<<256, 256, 0, stream>>>(S_buf);
    // 6. attention
    chunk_attn<<<dim3(NCH, 32), 256, 0, stream>>>(
        Cbig + 1024, Cbig + 2048, pattn_bf, S_buf, attn_bf, T, 3072);
    // 7. output projection (64x128 tiles, 512 blocks = 2/CU)
    gemm_bf16_nt64<<<dim3(8, 64), 256, 0, stream>>>(
        attn_bf, wo_bf, bo, out, MROWS, E, E);
}